// Round 3
// baseline (29552.078 us; speedup 1.0000x reference)
//
#include <hip/hip_runtime.h>
#include <math.h>

// Problem constants (B=8, C=64, H=W=128, HEADS=8, ch=8, L=2, P=4)
#define NPIX 16384               // 128*128
#define SBUF 8388608             // 8*64*16384 elements per full tensor

__device__ __forceinline__ float gelu_f(float x){
    return 0.5f*x*(1.0f+erff(x*0.70710678118654752440f));
}
__device__ __forceinline__ float waveReduceSum(float v){
    #pragma unroll
    for(int off=32;off>0;off>>=1) v += __shfl_down(v, off);
    return v;
}

// ---------------- LayerNorm over channel dim (64) ----------------
__global__ __launch_bounds__(256) void ln_kernel(const float* __restrict__ x,
        const float* __restrict__ w, const float* __restrict__ b, float* __restrict__ out){
    int idx = blockIdx.x*256 + threadIdx.x;      // over B*NPIX
    int bb = idx >> 14, n = idx & 16383;
    const float* ip = x + ((size_t)bb<<20) + n;
    float v[64]; float s = 0.f;
    #pragma unroll
    for(int c=0;c<64;c++){ v[c] = ip[(size_t)c<<14]; s += v[c]; }
    float mu = s*(1.f/64.f); float ss = 0.f;
    #pragma unroll
    for(int c=0;c<64;c++){ float d = v[c]-mu; ss += d*d; }
    float r = rsqrtf(ss*(1.f/64.f) + 1e-5f);
    float* op = out + ((size_t)bb<<20) + n;
    #pragma unroll
    for(int c=0;c<64;c++) op[(size_t)c<<14] = (v[c]-mu)*r*w[c] + b[c];
}

// ---------------- 1x1 conv: out[o] = sum_c w[o,c]*in[c] (+bias)(+res) ----------------
__global__ __launch_bounds__(256) void pw_kernel(const float* __restrict__ in,
        const float* __restrict__ w, const float* __restrict__ bias,
        const float* __restrict__ res, float* __restrict__ out, int wPerB){
    __shared__ float wl[4096];                   // transposed: wl[c*64+o]
    int t = threadIdx.x;
    int idx = blockIdx.x*256 + t;
    int b = idx >> 14, n = idx & 16383;
    const float* wp = w + (wPerB ? b*4096 : 0);
    for(int i=t;i<4096;i+=256) wl[(i&63)*64 + (i>>6)] = wp[i];
    __syncthreads();
    float acc[64];
    if(bias){
        #pragma unroll
        for(int o=0;o<64;o++) acc[o] = bias[o];
    } else {
        #pragma unroll
        for(int o=0;o<64;o++) acc[o] = 0.f;
    }
    const float* ip = in + ((size_t)b<<20) + n;
    for(int c=0;c<64;c++){
        float v = ip[(size_t)c<<14];
        const float4* wv = (const float4*)&wl[c*64];
        #pragma unroll
        for(int o4=0;o4<16;o4++){
            float4 w4 = wv[o4];
            acc[o4*4+0] += w4.x*v; acc[o4*4+1] += w4.y*v;
            acc[o4*4+2] += w4.z*v; acc[o4*4+3] += w4.w*v;
        }
    }
    size_t baseo = ((size_t)b<<20) + n;
    if(res){
        #pragma unroll
        for(int o=0;o<64;o++) out[baseo+((size_t)o<<14)] = acc[o] + res[baseo+((size_t)o<<14)];
    } else {
        #pragma unroll
        for(int o=0;o<64;o++) out[baseo+((size_t)o<<14)] = acc[o];
    }
}

// ---------------- depthwise 3x3, zero pad ----------------
__global__ __launch_bounds__(256) void dw3x3_kernel(const float* __restrict__ in,
        const float* __restrict__ wd, float* __restrict__ out){
    int idx = blockIdx.x*256 + threadIdx.x;      // over B*64*NPIX
    int n = idx & 16383; int bc = idx >> 14; int c = bc & 63;
    int y = n >> 7, x = n & 127;
    bool ym=y>0, yp=y<127, xm=x>0, xpv=x<127;
    const float* cp = in + ((size_t)bc<<14) + n;
    const float* wp = wd + c*9;
    float s = cp[0]*wp[4];
    if(ym){ s += cp[-128]*wp[1]; if(xm) s += cp[-129]*wp[0]; if(xpv) s += cp[-127]*wp[2]; }
    if(xm)  s += cp[-1]*wp[3];
    if(xpv) s += cp[1]*wp[5];
    if(yp){ s += cp[128]*wp[7]; if(xm) s += cp[127]*wp[6]; if(xpv) s += cp[129]*wp[8]; }
    out[idx] = s;
}

// ---------------- L2 normalize each (b,c) plane over NPIX ----------------
__global__ __launch_bounds__(256) void l2n_kernel(float* __restrict__ q){
    int bc = blockIdx.x;
    float* p = q + ((size_t)bc<<14);
    int t = threadIdx.x;
    float ss = 0.f;
    for(int n=t;n<NPIX;n+=256){ float v=p[n]; ss += v*v; }
    ss = waveReduceSum(ss);
    __shared__ float red[4];
    __shared__ float scale_s;
    if((t&63)==0) red[t>>6] = ss;
    __syncthreads();
    if(t==0) scale_s = 1.f/fmaxf(sqrtf(red[0]+red[1]+red[2]+red[3]), 1e-12f);
    __syncthreads();
    float sc = scale_s;
    for(int n=t;n<NPIX;n+=256) p[n] *= sc;
}

// ---------------- spectral attention: att[b,h,c,d] = sum_n q[c,n] k[d,n] ----------------
__global__ __launch_bounds__(256) void qk_kernel(const float* __restrict__ Q,
        const float* __restrict__ K, float* __restrict__ att){
    int blk = blockIdx.x;                        // B*HEADS*8 = 512
    int c = blk & 7, bh = blk >> 3;              // bh = b*8+head
    const float* qp = Q + (((size_t)bh*8 + c)<<14);
    const float* kp = K + (((size_t)bh*8)<<14);
    float p[8] = {0,0,0,0,0,0,0,0};
    for(int n=threadIdx.x;n<NPIX;n+=256){
        float qv = qp[n];
        #pragma unroll
        for(int d=0;d<8;d++) p[d] += qv*kp[((size_t)d<<14)+n];
    }
    #pragma unroll
    for(int off=32;off>0;off>>=1){
        #pragma unroll
        for(int d=0;d<8;d++) p[d] += __shfl_down(p[d], off);
    }
    __shared__ float red[4][8];
    int wave = threadIdx.x>>6, lane = threadIdx.x&63;
    if(lane==0){
        #pragma unroll
        for(int d=0;d<8;d++) red[wave][d] = p[d];
    }
    __syncthreads();
    if(threadIdx.x<8){
        float s = red[0][threadIdx.x]+red[1][threadIdx.x]+red[2][threadIdx.x]+red[3][threadIdx.x];
        att[blk*8+threadIdx.x] = s;
    }
}

// ---------------- zero helper ----------------
__global__ void zero512(float* __restrict__ p){
    p[blockIdx.x*256 + threadIdx.x] = 0.f;
}

// ---------------- mask bias v3: thread=pixel, 32 output accs (half of m), low VGPR ----
// svec[b,m] += sum over this block's pixels of relu(conv3x3_full(mask)[b,m,pix])
__global__ __launch_bounds__(256) void mbconv3_kernel(const float* __restrict__ mask,
        const float* __restrict__ w, float* __restrict__ svec){
    __shared__ float wl[4608];                   // 18 KB: [(cc*9+k)*32 + mm], cc in [0,16)
    __shared__ float red[4][32];
    int t = threadIdx.x;
    int b = blockIdx.x >> 7;                     // 8 b x 2 mhalf x 64 pixel-blocks
    int mh = (blockIdx.x >> 6) & 1;
    int n = (blockIdx.x & 63)*256 + t;
    int y = n>>7, x = n&127;
    bool ym=y>0, yp=y<127, xm=x>0, xpv=x<127;
    const float* mp = mask + ((size_t)b<<20) + n;
    float acc[32];
    #pragma unroll
    for(int o=0;o<32;o++) acc[o] = 0.f;
    for(int chunk=0;chunk<4;chunk++){
        __syncthreads();
        // fill: wl[ck*32+mm] = w[(mh*32+mm)*576 + chunk*144 + ck], ck in [0,144)
        const float* wp = w + (size_t)mh*32*576 + chunk*144;
        for(int i=t;i<4608;i+=256){
            int mm = i & 31, ck = i >> 5;
            wl[i] = wp[mm*576 + ck];
        }
        __syncthreads();
        #pragma unroll
        for(int cc=0;cc<16;cc++){
            int c = chunk*16 + cc;
            const float* cp = mp + ((size_t)c<<14);
            float tap[9];
            tap[0] = (ym&&xm)? cp[-129]:0.f;
            tap[1] =  ym?      cp[-128]:0.f;
            tap[2] = (ym&&xpv)?cp[-127]:0.f;
            tap[3] =  xm?      cp[-1]:0.f;
            tap[4] =           cp[0];
            tap[5] =  xpv?     cp[1]:0.f;
            tap[6] = (yp&&xm)? cp[127]:0.f;
            tap[7] =  yp?      cp[128]:0.f;
            tap[8] = (yp&&xpv)?cp[129]:0.f;
            #pragma unroll
            for(int k=0;k<9;k++){
                float tv = tap[k];
                const float4* wv = (const float4*)&wl[(cc*9+k)*32];
                #pragma unroll
                for(int o4=0;o4<8;o4++){
                    float4 w4 = wv[o4];
                    acc[o4*4+0] += w4.x*tv; acc[o4*4+1] += w4.y*tv;
                    acc[o4*4+2] += w4.z*tv; acc[o4*4+3] += w4.w*tv;
                }
            }
        }
    }
    // relu + reduce across the 256 threads, then atomic into svec[b*64+mh*32+mm]
    int wave = t>>6, lane = t&63;
    #pragma unroll
    for(int m=0;m<32;m++){
        float v = waveReduceSum(fmaxf(acc[m], 0.f));
        if(lane==0) red[wave][m] = v;
    }
    __syncthreads();
    if(t<32){
        float s = red[0][t]+red[1][t]+red[2][t]+red[3][t];
        atomicAdd(&svec[b*64 + mh*32 + t], s);
    }
}

// ---------------- spectral: mb projection + scale + bias + softmax over d ----------------
__global__ void spec_softmax_kernel(float* __restrict__ att, const float* __restrict__ svec,
        const float* __restrict__ smp2, const float* __restrict__ resc){
    int b = blockIdx.x, t = threadIdx.x;         // 8 blocks, 64 threads
    __shared__ float mb[64];
    float a = 0.f;
    for(int m=0;m<64;m++) a += smp2[t*64+m]*svec[b*64+m];
    mb[t] = a*(1.f/16384.f);
    __syncthreads();
    int h = t>>3, c = t&7;
    float* ap = att + (size_t)(b*8+h)*64 + c*8;
    float rs = resc[h];
    float v[8]; float mx = -1e30f;
    #pragma unroll
    for(int d=0;d<8;d++){ v[d] = ap[d]*rs + mb[h*8+d] - mb[h*8+c]; mx = fmaxf(mx, v[d]); }
    float s = 0.f;
    #pragma unroll
    for(int d=0;d<8;d++){ v[d] = expf(v[d]-mx); s += v[d]; }
    float inv = 1.f/s;
    #pragma unroll
    for(int d=0;d<8;d++) ap[d] = v[d]*inv;
}

// ---------------- M[b] = sproj @ blockdiag(att[b]) (64x64 per batch) ----------------
__global__ void mmat_kernel(const float* __restrict__ att, const float* __restrict__ sproj,
        float* __restrict__ M){
    int b = blockIdx.x;
    for(int e=threadIdx.x;e<4096;e+=256){
        int o = e>>6, j = e&63;
        int h = j>>3, jj = j&7;
        float s = 0.f;
        #pragma unroll
        for(int cc=0;cc<8;cc++) s += sproj[o*64 + h*8+cc]*att[(size_t)(b*8+h)*64 + cc*8 + jj];
        M[b*4096 + e] = s;
    }
}

// ---------------- FFN2D fused: dw3x3(x4) -> GELU -> 256->64 proj, += residual ----------------
__global__ __launch_bounds__(256) void ffn2d_kernel(const float* __restrict__ A,
        const float* __restrict__ w1, const float* __restrict__ w2, float* __restrict__ xs){
    __shared__ float w2l[16384];                 // transposed: [m*64+o]
    int t = threadIdx.x;
    for(int i=t;i<16384;i+=256){ int o=i>>8, m=i&255; w2l[m*64+o] = w2[i]; }
    __syncthreads();
    int idx = blockIdx.x*256 + t;
    int b = idx>>14, n = idx&16383;
    int y = n>>7, x = n&127;
    bool ym=y>0, yp=y<127, xm=x>0, xpv=x<127;
    const float* ap = A + ((size_t)b<<20) + n;
    float acc[64];
    #pragma unroll
    for(int o=0;o<64;o++) acc[o] = 0.f;
    for(int c=0;c<64;c++){
        const float* cp = ap + ((size_t)c<<14);
        float t00 = (ym&&xm)? cp[-129]:0.f;
        float t01 =  ym?      cp[-128]:0.f;
        float t02 = (ym&&xpv)?cp[-127]:0.f;
        float t10 =  xm?      cp[-1]:0.f;
        float t11 =           cp[0];
        float t12 =  xpv?     cp[1]:0.f;
        float t20 = (yp&&xm)? cp[127]:0.f;
        float t21 =  yp?      cp[128]:0.f;
        float t22 = (yp&&xpv)?cp[129]:0.f;
        const float* w1c = w1 + c*36;
        #pragma unroll
        for(int j=0;j<4;j++){
            const float* wj = w1c + j*9;
            float cv = t00*wj[0]+t01*wj[1]+t02*wj[2]+t10*wj[3]+t11*wj[4]
                      +t12*wj[5]+t20*wj[6]+t21*wj[7]+t22*wj[8];
            float g = gelu_f(cv);
            const float4* wv = (const float4*)&w2l[(c*4+j)*64];
            #pragma unroll
            for(int o4=0;o4<16;o4++){
                float4 w4 = wv[o4];
                acc[o4*4+0] += w4.x*g; acc[o4*4+1] += w4.y*g;
                acc[o4*4+2] += w4.z*g; acc[o4*4+3] += w4.w*g;
            }
        }
    }
    size_t baseo = ((size_t)b<<20) + n;
    #pragma unroll
    for(int o=0;o<64;o++) xs[baseo+((size_t)o<<14)] += acc[o];
}

// ---------------- polar: wbar[c] = mean_o pm2w[o,c]; wbar[64] = mean(pm2b) ----------------
__global__ void wbar_kernel(const float* __restrict__ pm2w, const float* __restrict__ pm2b,
        float* __restrict__ wbar){
    int t = threadIdx.x;                         // 64
    float s = 0.f;
    for(int o=0;o<64;o++) s += pm2w[o*64+t];
    wbar[t] = s*(1.f/64.f);
    if(t==0){
        float sb = 0.f;
        for(int o=0;o<64;o++) sb += pm2b[o];
        wbar[64] = sb*(1.f/64.f);
    }
}

// ---------------- polar mask gate: mg[b,n] = sum_c wbar[c]*gelu(dw3x3(mask)[c]+pm1b[c]) + bbar ----------------
__global__ __launch_bounds__(256) void mg_kernel(const float* __restrict__ mask,
        const float* __restrict__ w1, const float* __restrict__ b1,
        const float* __restrict__ wbar, float* __restrict__ mg){
    int idx = blockIdx.x*256 + threadIdx.x;      // over B*NPIX
    int b = idx>>14, n = idx&16383;
    int y = n>>7, x = n&127;
    bool ym=y>0, yp=y<127, xm=x>0, xpv=x<127;
    const float* ap = mask + ((size_t)b<<20) + n;
    float acc = wbar[64];
    for(int c=0;c<64;c++){
        const float* cp = ap + ((size_t)c<<14);
        const float* wj = w1 + c*9;
        float cv = b1[c] + cp[0]*wj[4];
        if(ym){ cv += cp[-128]*wj[1]; if(xm) cv += cp[-129]*wj[0]; if(xpv) cv += cp[-127]*wj[2]; }
        if(xm)  cv += cp[-1]*wj[3];
        if(xpv) cv += cp[1]*wj[5];
        if(yp){ cv += cp[128]*wj[7]; if(xm) cv += cp[127]*wj[6]; if(xpv) cv += cp[129]*wj[8]; }
        acc += wbar[c]*gelu_f(cv);
    }
    mg[idx] = acc;
}

// ---------------- polar attention (P=4, ch=8 per head), writes O (pre-projection) ----------------
__global__ __launch_bounds__(256) void att_pol_kernel(const float* __restrict__ Q,
        const float* __restrict__ K, const float* __restrict__ V,
        const float* __restrict__ mg, const float* __restrict__ resc, float* __restrict__ O){
    int idx = blockIdx.x*256 + threadIdx.x;      // over BN*NPIX = 32768
    int bn = idx>>14, n = idx&16383;
    float mgv[4];
    #pragma unroll
    for(int p=0;p<4;p++) mgv[p] = mg[(((bn<<2)+p)<<14) + n];
    for(int h=0;h<8;h++){
        size_t base = ((size_t)bn<<22) + ((size_t)h<<17) + n;
        float q[4][8], k[4][8], v[4][8];
        #pragma unroll
        for(int p=0;p<4;p++){
            size_t pb = base + ((size_t)p<<20);
            #pragma unroll
            for(int j=0;j<8;j++){
                size_t o = pb + ((size_t)j<<14);
                q[p][j] = Q[o]; k[p][j] = K[o]; v[p][j] = V[o];
            }
        }
        #pragma unroll
        for(int p=0;p<4;p++){
            float sq=0.f, sk=0.f;
            #pragma unroll
            for(int j=0;j<8;j++){ sq += q[p][j]*q[p][j]; sk += k[p][j]*k[p][j]; }
            float iq = 1.f/fmaxf(sqrtf(sq),1e-12f), ik = 1.f/fmaxf(sqrtf(sk),1e-12f);
            #pragma unroll
            for(int j=0;j<8;j++){ q[p][j]*=iq; k[p][j]*=ik; }
        }
        float rs = resc[h];
        float att[4][4];
        #pragma unroll
        for(int p=0;p<4;p++){
            #pragma unroll
            for(int r=0;r<4;r++){
                float d = 0.f;
                #pragma unroll
                for(int j=0;j<8;j++) d += q[p][j]*k[r][j];
                att[p][r] = rs*d + mgv[r] - mgv[p];
            }
        }
        #pragma unroll
        for(int p=0;p<4;p++){
            float mx = fmaxf(fmaxf(att[p][0],att[p][1]),fmaxf(att[p][2],att[p][3]));
            float s = 0.f;
            #pragma unroll
            for(int r=0;r<4;r++){ att[p][r] = expf(att[p][r]-mx); s += att[p][r]; }
            float inv = 1.f/s;
            #pragma unroll
            for(int r=0;r<4;r++) att[p][r] *= inv;
        }
        #pragma unroll
        for(int p=0;p<4;p++){
            size_t pb = base + ((size_t)p<<20);
            #pragma unroll
            for(int j=0;j<8;j++){
                float o = att[p][0]*v[0][j]+att[p][1]*v[1][j]+att[p][2]*v[2][j]+att[p][3]*v[3][j];
                O[pb + ((size_t)j<<14)] = o;
            }
        }
    }
}

// ---------------- FFN3D fused: 3D dw conv 3x3x3 (x4) -> GELU -> 256->64 proj, += residual ----------------
__global__ __launch_bounds__(256) void ffn3d_kernel(const float* __restrict__ A,
        const float* __restrict__ w1, const float* __restrict__ w2, float* __restrict__ xp){
    __shared__ float w2l[16384];
    int t = threadIdx.x;
    for(int i=t;i<16384;i+=256){ int o=i>>8, m=i&255; w2l[m*64+o] = w2[i]; }
    __syncthreads();
    int idx = blockIdx.x*256 + t;                // over B*NPIX
    int bp = idx>>14, n = idx&16383;
    int bn = bp>>2, p = bp&3;
    int y = n>>7, x = n&127;
    bool ym=y>0, yp=y<127, xm=x>0, xpv=x<127;
    float acc[64];
    #pragma unroll
    for(int o=0;o<64;o++) acc[o] = 0.f;
    for(int c=0;c<64;c++){
        float tap[27];
        #pragma unroll
        for(int dz=0;dz<3;dz++){
            int pp = p + dz - 1;
            if(pp < 0 || pp > 3){
                #pragma unroll
                for(int k9=0;k9<9;k9++) tap[dz*9+k9] = 0.f;
            } else {
                const float* cp = A + ((size_t)((bn<<2)+pp)<<20) + ((size_t)c<<14) + n;
                tap[dz*9+0] = (ym&&xm)? cp[-129]:0.f;
                tap[dz*9+1] =  ym?      cp[-128]:0.f;
                tap[dz*9+2] = (ym&&xpv)?cp[-127]:0.f;
                tap[dz*9+3] =  xm?      cp[-1]:0.f;
                tap[dz*9+4] =           cp[0];
                tap[dz*9+5] =  xpv?     cp[1]:0.f;
                tap[dz*9+6] = (yp&&xm)? cp[127]:0.f;
                tap[dz*9+7] =  yp?      cp[128]:0.f;
                tap[dz*9+8] = (yp&&xpv)?cp[129]:0.f;
            }
        }
        const float* w1c = w1 + c*108;
        #pragma unroll
        for(int j=0;j<4;j++){
            const float* wj = w1c + j*27;
            float cv = 0.f;
            #pragma unroll
            for(int k27=0;k27<27;k27++) cv += tap[k27]*wj[k27];
            float g = gelu_f(cv);
            const float4* wv = (const float4*)&w2l[(c*4+j)*64];
            #pragma unroll
            for(int o4=0;o4<16;o4++){
                float4 w4 = wv[o4];
                acc[o4*4+0] += w4.x*g; acc[o4*4+1] += w4.y*g;
                acc[o4*4+2] += w4.z*g; acc[o4*4+3] += w4.w*g;
            }
        }
    }
    size_t baseo = ((size_t)bp<<20) + n;
    #pragma unroll
    for(int o=0;o<64;o++) xp[baseo+((size_t)o<<14)] += acc[o];
}

// ---------------- fusion stage 1: T = relu(fw1 @ [xs;xp] + fb1) ----------------
__global__ __launch_bounds__(256) void fuse1_kernel(const float* __restrict__ xs,
        const float* __restrict__ xp, const float* __restrict__ fw1,
        const float* __restrict__ fb1, float* __restrict__ T){
    __shared__ float wl[8192];                   // wl[c*64+o] = fw1[o*128+c], c in 0..127
    int t = threadIdx.x;
    for(int i=t;i<8192;i+=256) wl[(i&127)*64 + (i>>7)] = fw1[i];
    __syncthreads();
    int idx = blockIdx.x*256 + t;
    int b = idx>>14, n = idx&16383;
    float acc[64];
    #pragma unroll
    for(int o=0;o<64;o++) acc[o] = fb1[o];
    const float* ip = xs + ((size_t)b<<20) + n;
    for(int c=0;c<64;c++){
        float v = ip[(size_t)c<<14];
        const float4* wv = (const float4*)&wl[c*64];
        #pragma unroll
        for(int o4=0;o4<16;o4++){
            float4 w4 = wv[o4];
            acc[o4*4+0] += w4.x*v; acc[o4*4+1] += w4.y*v;
            acc[o4*4+2] += w4.z*v; acc[o4*4+3] += w4.w*v;
        }
    }
    const float* ip2 = xp + ((size_t)b<<20) + n;
    for(int c=0;c<64;c++){
        float v = ip2[(size_t)c<<14];
        const float4* wv = (const float4*)&wl[(64+c)*64];
        #pragma unroll
        for(int o4=0;o4<16;o4++){
            float4 w4 = wv[o4];
            acc[o4*4+0] += w4.x*v; acc[o4*4+1] += w4.y*v;
            acc[o4*4+2] += w4.z*v; acc[o4*4+3] += w4.w*v;
        }
    }
    size_t baseo = ((size_t)b<<20) + n;
    #pragma unroll
    for(int o=0;o<64;o++) T[baseo+((size_t)o<<14)] = fmaxf(acc[o], 0.f);
}

// ---------------- fusion stage 2: out = sig(conv3x3(T)+fb2)*xs + (1-sig)*xp ----------------
__global__ __launch_bounds__(256) void fuse2_kernel(const float* __restrict__ T,
        const float* __restrict__ fw2, const float* __restrict__ fb2,
        const float* __restrict__ xs, const float* __restrict__ xp, float* __restrict__ out){
    int blk = blockIdx.x;                        // 8*64*64 = 32768
    int nt = blk&63, o = (blk>>6)&63, b = blk>>12;
    __shared__ float wl[576];
    for(int i=threadIdx.x;i<576;i+=256) wl[i] = fw2[o*576+i];
    __syncthreads();
    int n = nt*256 + threadIdx.x;
    int y = n>>7, x = n&127;
    bool ym=y>0, yp=y<127, xm=x>0, xpv=x<127;
    const float* tp = T + ((size_t)b<<20) + n;
    float acc = fb2[o];
    for(int c=0;c<64;c++){
        const float* cp = tp + ((size_t)c<<14);
        const float* wc = wl + c*9;
        float s = cp[0]*wc[4];
        if(ym){ s += cp[-128]*wc[1]; if(xm) s += cp[-129]*wc[0]; if(xpv) s += cp[-127]*wc[2]; }
        if(xm)  s += cp[-1]*wc[3];
        if(xpv) s += cp[1]*wc[5];
        if(yp){ s += cp[128]*wc[7]; if(xm) s += cp[127]*wc[6]; if(xpv) s += cp[129]*wc[8]; }
        acc += s;
    }
    float a = 1.f/(1.f+expf(-acc));
    size_t i0 = ((size_t)b<<20) + ((size_t)o<<14) + n;
    out[i0] = a*xs[i0] + (1.f-a)*xp[i0];
}

extern "C" void kernel_launch(void* const* d_in, const int* in_sizes, int n_in,
                              void* d_out, int out_size, void* d_ws, size_t ws_size,
                              hipStream_t stream) {
    // setup_inputs() dict order
    const float* x     = (const float*)d_in[0];
    const float* mask  = (const float*)d_in[1];
    const float* sl1w  = (const float*)d_in[2];
    const float* sl1b  = (const float*)d_in[3];
    const float* sl2w  = (const float*)d_in[4];
    const float* sl2b  = (const float*)d_in[5];
    const float* swq   = (const float*)d_in[6];
    const float* swk   = (const float*)d_in[7];
    const float* swv   = (const float*)d_in[8];
    const float* sproj = (const float*)d_in[9];
    const float* smp2  = (const float*)d_in[10];
    const float* sdq   = (const float*)d_in[11];
    const float* sdk   = (const float*)d_in[12];
    const float* sdv   = (const float*)d_in[13];
    const float* smp1  = (const float*)d_in[14];
    const float* sresc = (const float*)d_in[15];
    const float* sf1   = (const float*)d_in[16];
    const float* sf2   = (const float*)d_in[17];
    const float* pl1w  = (const float*)d_in[18];
    const float* pl1b  = (const float*)d_in[19];
    const float* pl2w  = (const float*)d_in[20];
    const float* pl2b  = (const float*)d_in[21];
    const float* pwq   = (const float*)d_in[22];
    const float* pwk   = (const float*)d_in[23];
    const float* pwv   = (const float*)d_in[24];
    const float* ppw   = (const float*)d_in[25];
    const float* pm2w  = (const float*)d_in[26];
    const float* ppb   = (const float*)d_in[27];
    const float* presc = (const float*)d_in[28];
    const float* pm1w  = (const float*)d_in[29];
    const float* pm1b  = (const float*)d_in[30];
    const float* pm2b  = (const float*)d_in[31];
    const float* pf1   = (const float*)d_in[32];
    const float* pf2   = (const float*)d_in[33];
    const float* fw1   = (const float*)d_in[34];
    const float* fb1   = (const float*)d_in[35];
    const float* fw2   = (const float*)d_in[36];
    const float* fb2   = (const float*)d_in[37];

    // workspace layout: 6 big buffers (202MB) + small scratch; d_out doubles as staging
    float* ws_f = (float*)d_ws;
    float* xs = ws_f;
    float* xp = ws_f + (size_t)SBUF;
    float* A  = ws_f + 2*(size_t)SBUF;
    float* Q  = ws_f + 3*(size_t)SBUF;
    float* K  = ws_f + 4*(size_t)SBUF;
    float* V  = ws_f + 5*(size_t)SBUF;
    float* small = ws_f + 6*(size_t)SBUF;
    float* mg   = small;                // 131072
    float* att  = mg + 131072;          // 4096
    float* svec = att + 4096;           // 512
    float* M    = svec + 512;           // 32768
    float* wbar = M + 32768;            // 65
    float* stage = (float*)d_out;       // scratch until fusion (written before read)
    float* Tf = Q;                      // fusion temp (Q is dead by then)

    hipMemcpyAsync(xs, x, (size_t)SBUF*4, hipMemcpyDeviceToDevice, stream);
    hipMemcpyAsync(xp, x, (size_t)SBUF*4, hipMemcpyDeviceToDevice, stream);

    // ---- spectral branch ----
    for(int i=0;i<2;i++){
        ln_kernel<<<512,256,0,stream>>>(xs, sl1w+i*64, sl1b+i*64, A);
        pw_kernel<<<512,256,0,stream>>>(A, swq+i*4096, nullptr, nullptr, stage, 0);
        dw3x3_kernel<<<32768,256,0,stream>>>(stage, sdq+i*576, Q);
        pw_kernel<<<512,256,0,stream>>>(A, swk+i*4096, nullptr, nullptr, stage, 0);
        dw3x3_kernel<<<32768,256,0,stream>>>(stage, sdk+i*576, K);
        pw_kernel<<<512,256,0,stream>>>(A, swv+i*4096, nullptr, nullptr, stage, 0);
        dw3x3_kernel<<<32768,256,0,stream>>>(stage, sdv+i*576, V);
        l2n_kernel<<<512,256,0,stream>>>(Q);
        l2n_kernel<<<512,256,0,stream>>>(K);
        qk_kernel<<<512,256,0,stream>>>(Q, K, att);
        zero512<<<2,256,0,stream>>>(svec);
        mbconv3_kernel<<<1024,256,0,stream>>>(mask, smp1+i*36864, svec);
        spec_softmax_kernel<<<8,64,0,stream>>>(att, svec, smp2+i*4096, sresc+i*8);
        mmat_kernel<<<8,256,0,stream>>>(att, sproj+i*4096, M);
        pw_kernel<<<512,256,0,stream>>>(V, M, nullptr, xs, xs, 1);
        ln_kernel<<<512,256,0,stream>>>(xs, sl2w+i*64, sl2b+i*64, A);
        ffn2d_kernel<<<512,256,0,stream>>>(A, sf1+i*2304, sf2+i*16384, xs);
    }
    // ---- polar branch ----
    for(int i=0;i<2;i++){
        ln_kernel<<<512,256,0,stream>>>(xp, pl1w+i*64, pl1b+i*64, A);
        pw_kernel<<<512,256,0,stream>>>(A, pwq+i*4096, nullptr, nullptr, Q, 0);
        pw_kernel<<<512,256,0,stream>>>(A, pwk+i*4096, nullptr, nullptr, K, 0);
        pw_kernel<<<512,256,0,stream>>>(A, pwv+i*4096, nullptr, nullptr, V, 0);
        wbar_kernel<<<1,64,0,stream>>>(pm2w+i*4096, pm2b+i*64, wbar);
        mg_kernel<<<512,256,0,stream>>>(mask, pm1w+i*576, pm1b+i*64, wbar, mg);
        att_pol_kernel<<<128,256,0,stream>>>(Q, K, V, mg, presc+i*8, stage);
        pw_kernel<<<512,256,0,stream>>>(stage, ppw+i*4096, ppb+i*64, xp, xp, 0);
        ln_kernel<<<512,256,0,stream>>>(xp, pl2w+i*64, pl2b+i*64, A);
        ffn3d_kernel<<<512,256,0,stream>>>(A, pf1+i*6912, pf2+i*16384, xp);
    }
    // ---- fusion ----
    fuse1_kernel<<<512,256,0,stream>>>(xs, xp, fw1, fb1, Tf);
    fuse2_kernel<<<32768,256,0,stream>>>(Tf, fw2, fb2, xs, xp, (float*)d_out);
}

// Round 4
// 4192.039 us; speedup vs baseline: 7.0496x; 7.0496x over previous
//
#include <hip/hip_runtime.h>
#include <math.h>

// Problem constants (B=8, C=64, H=W=128, HEADS=8, ch=8, L=2, P=4)
#define NPIX 16384               // 128*128
#define SBUF 8388608             // 8*64*16384 elements per full tensor

__device__ __forceinline__ float gelu_f(float x){
    return 0.5f*x*(1.0f+erff(x*0.70710678118654752440f));
}
__device__ __forceinline__ float waveReduceSum(float v){
    #pragma unroll
    for(int off=32;off>0;off>>=1) v += __shfl_down(v, off);
    return v;
}

// ---------------- LayerNorm over channel dim (64) ----------------
__global__ __launch_bounds__(256) void ln_kernel(const float* __restrict__ x,
        const float* __restrict__ w, const float* __restrict__ b, float* __restrict__ out){
    int idx = blockIdx.x*256 + threadIdx.x;      // over B*NPIX
    int bb = idx >> 14, n = idx & 16383;
    const float* ip = x + ((size_t)bb<<20) + n;
    float v[64]; float s = 0.f;
    #pragma unroll
    for(int c=0;c<64;c++){ v[c] = ip[(size_t)c<<14]; s += v[c]; }
    float mu = s*(1.f/64.f); float ss = 0.f;
    #pragma unroll
    for(int c=0;c<64;c++){ float d = v[c]-mu; ss += d*d; }
    float r = rsqrtf(ss*(1.f/64.f) + 1e-5f);
    float* op = out + ((size_t)bb<<20) + n;
    #pragma unroll
    for(int c=0;c<64;c++) op[(size_t)c<<14] = (v[c]-mu)*r*w[c] + b[c];
}

// ---------------- 1x1 conv: out[o] = sum_c w[o,c]*in[c] (+bias)(+res) ----------------
__global__ __launch_bounds__(256) void pw_kernel(const float* __restrict__ in,
        const float* __restrict__ w, const float* __restrict__ bias,
        const float* __restrict__ res, float* __restrict__ out, int wPerB){
    __shared__ float wl[4096];                   // transposed: wl[c*64+o]
    int t = threadIdx.x;
    int idx = blockIdx.x*256 + t;
    int b = idx >> 14, n = idx & 16383;
    const float* wp = w + (wPerB ? b*4096 : 0);
    for(int i=t;i<4096;i+=256) wl[(i&63)*64 + (i>>6)] = wp[i];
    __syncthreads();
    float acc[64];
    if(bias){
        #pragma unroll
        for(int o=0;o<64;o++) acc[o] = bias[o];
    } else {
        #pragma unroll
        for(int o=0;o<64;o++) acc[o] = 0.f;
    }
    const float* ip = in + ((size_t)b<<20) + n;
    for(int c=0;c<64;c++){
        float v = ip[(size_t)c<<14];
        const float4* wv = (const float4*)&wl[c*64];
        #pragma unroll
        for(int o4=0;o4<16;o4++){
            float4 w4 = wv[o4];
            acc[o4*4+0] += w4.x*v; acc[o4*4+1] += w4.y*v;
            acc[o4*4+2] += w4.z*v; acc[o4*4+3] += w4.w*v;
        }
    }
    size_t baseo = ((size_t)b<<20) + n;
    if(res){
        #pragma unroll
        for(int o=0;o<64;o++) out[baseo+((size_t)o<<14)] = acc[o] + res[baseo+((size_t)o<<14)];
    } else {
        #pragma unroll
        for(int o=0;o<64;o++) out[baseo+((size_t)o<<14)] = acc[o];
    }
}

// ---------------- depthwise 3x3, zero pad ----------------
__global__ __launch_bounds__(256) void dw3x3_kernel(const float* __restrict__ in,
        const float* __restrict__ wd, float* __restrict__ out){
    int idx = blockIdx.x*256 + threadIdx.x;      // over B*64*NPIX
    int n = idx & 16383; int bc = idx >> 14; int c = bc & 63;
    int y = n >> 7, x = n & 127;
    bool ym=y>0, yp=y<127, xm=x>0, xpv=x<127;
    const float* cp = in + ((size_t)bc<<14) + n;
    const float* wp = wd + c*9;
    float s = cp[0]*wp[4];
    if(ym){ s += cp[-128]*wp[1]; if(xm) s += cp[-129]*wp[0]; if(xpv) s += cp[-127]*wp[2]; }
    if(xm)  s += cp[-1]*wp[3];
    if(xpv) s += cp[1]*wp[5];
    if(yp){ s += cp[128]*wp[7]; if(xm) s += cp[127]*wp[6]; if(xpv) s += cp[129]*wp[8]; }
    out[idx] = s;
}

// ---------------- L2 normalize each (b,c) plane over NPIX ----------------
__global__ __launch_bounds__(256) void l2n_kernel(float* __restrict__ q){
    int bc = blockIdx.x;
    float* p = q + ((size_t)bc<<14);
    int t = threadIdx.x;
    float ss = 0.f;
    for(int n=t;n<NPIX;n+=256){ float v=p[n]; ss += v*v; }
    ss = waveReduceSum(ss);
    __shared__ float red[4];
    __shared__ float scale_s;
    if((t&63)==0) red[t>>6] = ss;
    __syncthreads();
    if(t==0) scale_s = 1.f/fmaxf(sqrtf(red[0]+red[1]+red[2]+red[3]), 1e-12f);
    __syncthreads();
    float sc = scale_s;
    for(int n=t;n<NPIX;n+=256) p[n] *= sc;
}

// ---------------- spectral attention: att[b,h,c,d] = sum_n q[c,n] k[d,n] ----------------
__global__ __launch_bounds__(256) void qk_kernel(const float* __restrict__ Q,
        const float* __restrict__ K, float* __restrict__ att){
    int blk = blockIdx.x;                        // B*HEADS*8 = 512
    int c = blk & 7, bh = blk >> 3;              // bh = b*8+head
    const float* qp = Q + (((size_t)bh*8 + c)<<14);
    const float* kp = K + (((size_t)bh*8)<<14);
    float p[8] = {0,0,0,0,0,0,0,0};
    for(int n=threadIdx.x;n<NPIX;n+=256){
        float qv = qp[n];
        #pragma unroll
        for(int d=0;d<8;d++) p[d] += qv*kp[((size_t)d<<14)+n];
    }
    #pragma unroll
    for(int off=32;off>0;off>>=1){
        #pragma unroll
        for(int d=0;d<8;d++) p[d] += __shfl_down(p[d], off);
    }
    __shared__ float red[4][8];
    int wave = threadIdx.x>>6, lane = threadIdx.x&63;
    if(lane==0){
        #pragma unroll
        for(int d=0;d<8;d++) red[wave][d] = p[d];
    }
    __syncthreads();
    if(threadIdx.x<8){
        float s = red[0][threadIdx.x]+red[1][threadIdx.x]+red[2][threadIdx.x]+red[3][threadIdx.x];
        att[blk*8+threadIdx.x] = s;
    }
}

// ---------------- zero helper ----------------
__global__ void zero512(float* __restrict__ p){
    p[blockIdx.x*256 + threadIdx.x] = 0.f;
}

// ---------------- mask bias v4: pw-kernel shape. One-time 36KB LDS fill (16 outputs),
// 2 pixels/thread, no mid-loop barriers. svec[b,m] += relu-sum over block's pixels. ----
__global__ __launch_bounds__(256) void mbconv4_kernel(const float* __restrict__ mask,
        const float* __restrict__ w, float* __restrict__ svec){
    __shared__ float wl[9216];                   // 36 KB: wl[ck*16+mo], ck in [0,576)
    __shared__ float red[4][16];
    int t = threadIdx.x;
    int og = blockIdx.x & 3;                     // output-channel group (16 each)
    int pb = (blockIdx.x >> 2) & 31;             // 512-pixel block
    int b  = blockIdx.x >> 7;
    const float* wp = w + (size_t)og*16*576;
    for(int i=t;i<9216;i+=256){
        int mo = i & 15, ck = i >> 4;
        wl[i] = wp[mo*576 + ck];
    }
    __syncthreads();
    int n0 = pb*512 + t;                         // pixel 0
    int n1 = n0 + 256;                           // pixel 1
    int y0 = n0>>7, x0 = n0&127;
    int y1 = n1>>7, x1 = n1&127;
    bool ym0=y0>0, yp0=y0<127, xm0=x0>0, xp0=x0<127;
    bool ym1=y1>0, yp1=y1<127, xm1=x1>0, xp1=x1<127;
    const float* mp = mask + ((size_t)b<<20);
    float acc0[16], acc1[16];
    #pragma unroll
    for(int o=0;o<16;o++){ acc0[o]=0.f; acc1[o]=0.f; }
    for(int c=0;c<64;c++){
        const float* cp0 = mp + ((size_t)c<<14) + n0;
        const float* cp1 = mp + ((size_t)c<<14) + n1;
        float ta[9], tb[9];
        ta[0] = (ym0&&xm0)? cp0[-129]:0.f;
        ta[1] =  ym0?       cp0[-128]:0.f;
        ta[2] = (ym0&&xp0)? cp0[-127]:0.f;
        ta[3] =  xm0?       cp0[-1]:0.f;
        ta[4] =             cp0[0];
        ta[5] =  xp0?       cp0[1]:0.f;
        ta[6] = (yp0&&xm0)? cp0[127]:0.f;
        ta[7] =  yp0?       cp0[128]:0.f;
        ta[8] = (yp0&&xp0)? cp0[129]:0.f;
        tb[0] = (ym1&&xm1)? cp1[-129]:0.f;
        tb[1] =  ym1?       cp1[-128]:0.f;
        tb[2] = (ym1&&xp1)? cp1[-127]:0.f;
        tb[3] =  xm1?       cp1[-1]:0.f;
        tb[4] =             cp1[0];
        tb[5] =  xp1?       cp1[1]:0.f;
        tb[6] = (yp1&&xm1)? cp1[127]:0.f;
        tb[7] =  yp1?       cp1[128]:0.f;
        tb[8] = (yp1&&xp1)? cp1[129]:0.f;
        #pragma unroll
        for(int k=0;k<9;k++){
            float va = ta[k], vb = tb[k];
            const float4* wv = (const float4*)&wl[(c*9+k)*16];
            #pragma unroll
            for(int o4=0;o4<4;o4++){
                float4 w4 = wv[o4];
                acc0[o4*4+0] += w4.x*va; acc0[o4*4+1] += w4.y*va;
                acc0[o4*4+2] += w4.z*va; acc0[o4*4+3] += w4.w*va;
                acc1[o4*4+0] += w4.x*vb; acc1[o4*4+1] += w4.y*vb;
                acc1[o4*4+2] += w4.z*vb; acc1[o4*4+3] += w4.w*vb;
            }
        }
    }
    // relu both pixels, reduce across block, atomic into svec
    int wave = t>>6, lane = t&63;
    #pragma unroll
    for(int m=0;m<16;m++){
        float v = waveReduceSum(fmaxf(acc0[m],0.f) + fmaxf(acc1[m],0.f));
        if(lane==0) red[wave][m] = v;
    }
    __syncthreads();
    if(t<16){
        float s = red[0][t]+red[1][t]+red[2][t]+red[3][t];
        atomicAdd(&svec[b*64 + og*16 + t], s);
    }
}

// ---------------- spectral: mb projection + scale + bias + softmax over d ----------------
__global__ void spec_softmax_kernel(float* __restrict__ att, const float* __restrict__ svec,
        const float* __restrict__ smp2, const float* __restrict__ resc){
    int b = blockIdx.x, t = threadIdx.x;         // 8 blocks, 64 threads
    __shared__ float mb[64];
    float a = 0.f;
    for(int m=0;m<64;m++) a += smp2[t*64+m]*svec[b*64+m];
    mb[t] = a*(1.f/16384.f);
    __syncthreads();
    int h = t>>3, c = t&7;
    float* ap = att + (size_t)(b*8+h)*64 + c*8;
    float rs = resc[h];
    float v[8]; float mx = -1e30f;
    #pragma unroll
    for(int d=0;d<8;d++){ v[d] = ap[d]*rs + mb[h*8+d] - mb[h*8+c]; mx = fmaxf(mx, v[d]); }
    float s = 0.f;
    #pragma unroll
    for(int d=0;d<8;d++){ v[d] = expf(v[d]-mx); s += v[d]; }
    float inv = 1.f/s;
    #pragma unroll
    for(int d=0;d<8;d++) ap[d] = v[d]*inv;
}

// ---------------- M[b] = sproj @ blockdiag(att[b]) (64x64 per batch) ----------------
__global__ void mmat_kernel(const float* __restrict__ att, const float* __restrict__ sproj,
        float* __restrict__ M){
    int b = blockIdx.x;
    for(int e=threadIdx.x;e<4096;e+=256){
        int o = e>>6, j = e&63;
        int h = j>>3, jj = j&7;
        float s = 0.f;
        #pragma unroll
        for(int cc=0;cc<8;cc++) s += sproj[o*64 + h*8+cc]*att[(size_t)(b*8+h)*64 + cc*8 + jj];
        M[b*4096 + e] = s;
    }
}

// ---------------- FFN2D fused: dw3x3(x4) -> GELU -> 256->64 proj, += residual ----------------
__global__ __launch_bounds__(256) void ffn2d_kernel(const float* __restrict__ A,
        const float* __restrict__ w1, const float* __restrict__ w2, float* __restrict__ xs){
    __shared__ float w2l[16384];                 // transposed: [m*64+o]
    int t = threadIdx.x;
    for(int i=t;i<16384;i+=256){ int o=i>>8, m=i&255; w2l[m*64+o] = w2[i]; }
    __syncthreads();
    int idx = blockIdx.x*256 + t;
    int b = idx>>14, n = idx&16383;
    int y = n>>7, x = n&127;
    bool ym=y>0, yp=y<127, xm=x>0, xpv=x<127;
    const float* ap = A + ((size_t)b<<20) + n;
    float acc[64];
    #pragma unroll
    for(int o=0;o<64;o++) acc[o] = 0.f;
    for(int c=0;c<64;c++){
        const float* cp = ap + ((size_t)c<<14);
        float t00 = (ym&&xm)? cp[-129]:0.f;
        float t01 =  ym?      cp[-128]:0.f;
        float t02 = (ym&&xpv)?cp[-127]:0.f;
        float t10 =  xm?      cp[-1]:0.f;
        float t11 =           cp[0];
        float t12 =  xpv?     cp[1]:0.f;
        float t20 = (yp&&xm)? cp[127]:0.f;
        float t21 =  yp?      cp[128]:0.f;
        float t22 = (yp&&xpv)?cp[129]:0.f;
        const float* w1c = w1 + c*36;
        #pragma unroll
        for(int j=0;j<4;j++){
            const float* wj = w1c + j*9;
            float cv = t00*wj[0]+t01*wj[1]+t02*wj[2]+t10*wj[3]+t11*wj[4]
                      +t12*wj[5]+t20*wj[6]+t21*wj[7]+t22*wj[8];
            float g = gelu_f(cv);
            const float4* wv = (const float4*)&w2l[(c*4+j)*64];
            #pragma unroll
            for(int o4=0;o4<16;o4++){
                float4 w4 = wv[o4];
                acc[o4*4+0] += w4.x*g; acc[o4*4+1] += w4.y*g;
                acc[o4*4+2] += w4.z*g; acc[o4*4+3] += w4.w*g;
            }
        }
    }
    size_t baseo = ((size_t)b<<20) + n;
    #pragma unroll
    for(int o=0;o<64;o++) xs[baseo+((size_t)o<<14)] += acc[o];
}

// ---------------- polar: wbar[c] = mean_o pm2w[o,c]; wbar[64] = mean(pm2b) ----------------
__global__ void wbar_kernel(const float* __restrict__ pm2w, const float* __restrict__ pm2b,
        float* __restrict__ wbar){
    int t = threadIdx.x;                         // 64
    float s = 0.f;
    for(int o=0;o<64;o++) s += pm2w[o*64+t];
    wbar[t] = s*(1.f/64.f);
    if(t==0){
        float sb = 0.f;
        for(int o=0;o<64;o++) sb += pm2b[o];
        wbar[64] = sb*(1.f/64.f);
    }
}

// ---------------- polar mask gate: mg[b,n] = sum_c wbar[c]*gelu(dw3x3(mask)[c]+pm1b[c]) + bbar ----------------
__global__ __launch_bounds__(256) void mg_kernel(const float* __restrict__ mask,
        const float* __restrict__ w1, const float* __restrict__ b1,
        const float* __restrict__ wbar, float* __restrict__ mg){
    int idx = blockIdx.x*256 + threadIdx.x;      // over B*NPIX
    int b = idx>>14, n = idx&16383;
    int y = n>>7, x = n&127;
    bool ym=y>0, yp=y<127, xm=x>0, xpv=x<127;
    const float* ap = mask + ((size_t)b<<20) + n;
    float acc = wbar[64];
    for(int c=0;c<64;c++){
        const float* cp = ap + ((size_t)c<<14);
        const float* wj = w1 + c*9;
        float cv = b1[c] + cp[0]*wj[4];
        if(ym){ cv += cp[-128]*wj[1]; if(xm) cv += cp[-129]*wj[0]; if(xpv) cv += cp[-127]*wj[2]; }
        if(xm)  cv += cp[-1]*wj[3];
        if(xpv) cv += cp[1]*wj[5];
        if(yp){ cv += cp[128]*wj[7]; if(xm) cv += cp[127]*wj[6]; if(xpv) cv += cp[129]*wj[8]; }
        acc += wbar[c]*gelu_f(cv);
    }
    mg[idx] = acc;
}

// ---------------- polar attention (P=4, ch=8 per head), writes O (pre-projection) ----------------
__global__ __launch_bounds__(256) void att_pol_kernel(const float* __restrict__ Q,
        const float* __restrict__ K, const float* __restrict__ V,
        const float* __restrict__ mg, const float* __restrict__ resc, float* __restrict__ O){
    int idx = blockIdx.x*256 + threadIdx.x;      // over BN*NPIX = 32768
    int bn = idx>>14, n = idx&16383;
    float mgv[4];
    #pragma unroll
    for(int p=0;p<4;p++) mgv[p] = mg[(((bn<<2)+p)<<14) + n];
    for(int h=0;h<8;h++){
        size_t base = ((size_t)bn<<22) + ((size_t)h<<17) + n;
        float q[4][8], k[4][8], v[4][8];
        #pragma unroll
        for(int p=0;p<4;p++){
            size_t pb = base + ((size_t)p<<20);
            #pragma unroll
            for(int j=0;j<8;j++){
                size_t o = pb + ((size_t)j<<14);
                q[p][j] = Q[o]; k[p][j] = K[o]; v[p][j] = V[o];
            }
        }
        #pragma unroll
        for(int p=0;p<4;p++){
            float sq=0.f, sk=0.f;
            #pragma unroll
            for(int j=0;j<8;j++){ sq += q[p][j]*q[p][j]; sk += k[p][j]*k[p][j]; }
            float iq = 1.f/fmaxf(sqrtf(sq),1e-12f), ik = 1.f/fmaxf(sqrtf(sk),1e-12f);
            #pragma unroll
            for(int j=0;j<8;j++){ q[p][j]*=iq; k[p][j]*=ik; }
        }
        float rs = resc[h];
        float att[4][4];
        #pragma unroll
        for(int p=0;p<4;p++){
            #pragma unroll
            for(int r=0;r<4;r++){
                float d = 0.f;
                #pragma unroll
                for(int j=0;j<8;j++) d += q[p][j]*k[r][j];
                att[p][r] = rs*d + mgv[r] - mgv[p];
            }
        }
        #pragma unroll
        for(int p=0;p<4;p++){
            float mx = fmaxf(fmaxf(att[p][0],att[p][1]),fmaxf(att[p][2],att[p][3]));
            float s = 0.f;
            #pragma unroll
            for(int r=0;r<4;r++){ att[p][r] = expf(att[p][r]-mx); s += att[p][r]; }
            float inv = 1.f/s;
            #pragma unroll
            for(int r=0;r<4;r++) att[p][r] *= inv;
        }
        #pragma unroll
        for(int p=0;p<4;p++){
            size_t pb = base + ((size_t)p<<20);
            #pragma unroll
            for(int j=0;j<8;j++){
                float o = att[p][0]*v[0][j]+att[p][1]*v[1][j]+att[p][2]*v[2][j]+att[p][3]*v[3][j];
                O[pb + ((size_t)j<<14)] = o;
            }
        }
    }
}

// ---------------- FFN3D fused: 3D dw conv 3x3x3 (x4) -> GELU -> 256->64 proj, += residual ----------------
__global__ __launch_bounds__(256) void ffn3d_kernel(const float* __restrict__ A,
        const float* __restrict__ w1, const float* __restrict__ w2, float* __restrict__ xp){
    __shared__ float w2l[16384];
    int t = threadIdx.x;
    for(int i=t;i<16384;i+=256){ int o=i>>8, m=i&255; w2l[m*64+o] = w2[i]; }
    __syncthreads();
    int idx = blockIdx.x*256 + t;                // over B*NPIX
    int bp = idx>>14, n = idx&16383;
    int bn = bp>>2, p = bp&3;
    int y = n>>7, x = n&127;
    bool ym=y>0, yp=y<127, xm=x>0, xpv=x<127;
    float acc[64];
    #pragma unroll
    for(int o=0;o<64;o++) acc[o] = 0.f;
    for(int c=0;c<64;c++){
        float tap[27];
        #pragma unroll
        for(int dz=0;dz<3;dz++){
            int pp = p + dz - 1;
            if(pp < 0 || pp > 3){
                #pragma unroll
                for(int k9=0;k9<9;k9++) tap[dz*9+k9] = 0.f;
            } else {
                const float* cp = A + ((size_t)((bn<<2)+pp)<<20) + ((size_t)c<<14) + n;
                tap[dz*9+0] = (ym&&xm)? cp[-129]:0.f;
                tap[dz*9+1] =  ym?      cp[-128]:0.f;
                tap[dz*9+2] = (ym&&xpv)?cp[-127]:0.f;
                tap[dz*9+3] =  xm?      cp[-1]:0.f;
                tap[dz*9+4] =           cp[0];
                tap[dz*9+5] =  xpv?     cp[1]:0.f;
                tap[dz*9+6] = (yp&&xm)? cp[127]:0.f;
                tap[dz*9+7] =  yp?      cp[128]:0.f;
                tap[dz*9+8] = (yp&&xpv)?cp[129]:0.f;
            }
        }
        const float* w1c = w1 + c*108;
        #pragma unroll
        for(int j=0;j<4;j++){
            const float* wj = w1c + j*27;
            float cv = 0.f;
            #pragma unroll
            for(int k27=0;k27<27;k27++) cv += tap[k27]*wj[k27];
            float g = gelu_f(cv);
            const float4* wv = (const float4*)&w2l[(c*4+j)*64];
            #pragma unroll
            for(int o4=0;o4<16;o4++){
                float4 w4 = wv[o4];
                acc[o4*4+0] += w4.x*g; acc[o4*4+1] += w4.y*g;
                acc[o4*4+2] += w4.z*g; acc[o4*4+3] += w4.w*g;
            }
        }
    }
    size_t baseo = ((size_t)bp<<20) + n;
    #pragma unroll
    for(int o=0;o<64;o++) xp[baseo+((size_t)o<<14)] += acc[o];
}

// ---------------- fusion stage 1: T = relu(fw1 @ [xs;xp] + fb1) ----------------
__global__ __launch_bounds__(256) void fuse1_kernel(const float* __restrict__ xs,
        const float* __restrict__ xp, const float* __restrict__ fw1,
        const float* __restrict__ fb1, float* __restrict__ T){
    __shared__ float wl[8192];                   // wl[c*64+o] = fw1[o*128+c], c in 0..127
    int t = threadIdx.x;
    for(int i=t;i<8192;i+=256) wl[(i&127)*64 + (i>>7)] = fw1[i];
    __syncthreads();
    int idx = blockIdx.x*256 + t;
    int b = idx>>14, n = idx&16383;
    float acc[64];
    #pragma unroll
    for(int o=0;o<64;o++) acc[o] = fb1[o];
    const float* ip = xs + ((size_t)b<<20) + n;
    for(int c=0;c<64;c++){
        float v = ip[(size_t)c<<14];
        const float4* wv = (const float4*)&wl[c*64];
        #pragma unroll
        for(int o4=0;o4<16;o4++){
            float4 w4 = wv[o4];
            acc[o4*4+0] += w4.x*v; acc[o4*4+1] += w4.y*v;
            acc[o4*4+2] += w4.z*v; acc[o4*4+3] += w4.w*v;
        }
    }
    const float* ip2 = xp + ((size_t)b<<20) + n;
    for(int c=0;c<64;c++){
        float v = ip2[(size_t)c<<14];
        const float4* wv = (const float4*)&wl[(64+c)*64];
        #pragma unroll
        for(int o4=0;o4<16;o4++){
            float4 w4 = wv[o4];
            acc[o4*4+0] += w4.x*v; acc[o4*4+1] += w4.y*v;
            acc[o4*4+2] += w4.z*v; acc[o4*4+3] += w4.w*v;
        }
    }
    size_t baseo = ((size_t)b<<20) + n;
    #pragma unroll
    for(int o=0;o<64;o++) T[baseo+((size_t)o<<14)] = fmaxf(acc[o], 0.f);
}

// ---------------- fusion stage 2: out = sig(conv3x3(T)+fb2)*xs + (1-sig)*xp ----------------
__global__ __launch_bounds__(256) void fuse2_kernel(const float* __restrict__ T,
        const float* __restrict__ fw2, const float* __restrict__ fb2,
        const float* __restrict__ xs, const float* __restrict__ xp, float* __restrict__ out){
    int blk = blockIdx.x;                        // 8*64*64 = 32768
    int nt = blk&63, o = (blk>>6)&63, b = blk>>12;
    __shared__ float wl[576];
    for(int i=threadIdx.x;i<576;i+=256) wl[i] = fw2[o*576+i];
    __syncthreads();
    int n = nt*256 + threadIdx.x;
    int y = n>>7, x = n&127;
    bool ym=y>0, yp=y<127, xm=x>0, xpv=x<127;
    const float* tp = T + ((size_t)b<<20) + n;
    float acc = fb2[o];
    for(int c=0;c<64;c++){
        const float* cp = tp + ((size_t)c<<14);
        const float* wc = wl + c*9;
        float s = cp[0]*wc[4];
        if(ym){ s += cp[-128]*wc[1]; if(xm) s += cp[-129]*wc[0]; if(xpv) s += cp[-127]*wc[2]; }
        if(xm)  s += cp[-1]*wc[3];
        if(xpv) s += cp[1]*wc[5];
        if(yp){ s += cp[128]*wc[7]; if(xm) s += cp[127]*wc[6]; if(xpv) s += cp[129]*wc[8]; }
        acc += s;
    }
    float a = 1.f/(1.f+expf(-acc));
    size_t i0 = ((size_t)b<<20) + ((size_t)o<<14) + n;
    out[i0] = a*xs[i0] + (1.f-a)*xp[i0];
}

extern "C" void kernel_launch(void* const* d_in, const int* in_sizes, int n_in,
                              void* d_out, int out_size, void* d_ws, size_t ws_size,
                              hipStream_t stream) {
    // setup_inputs() dict order
    const float* x     = (const float*)d_in[0];
    const float* mask  = (const float*)d_in[1];
    const float* sl1w  = (const float*)d_in[2];
    const float* sl1b  = (const float*)d_in[3];
    const float* sl2w  = (const float*)d_in[4];
    const float* sl2b  = (const float*)d_in[5];
    const float* swq   = (const float*)d_in[6];
    const float* swk   = (const float*)d_in[7];
    const float* swv   = (const float*)d_in[8];
    const float* sproj = (const float*)d_in[9];
    const float* smp2  = (const float*)d_in[10];
    const float* sdq   = (const float*)d_in[11];
    const float* sdk   = (const float*)d_in[12];
    const float* sdv   = (const float*)d_in[13];
    const float* smp1  = (const float*)d_in[14];
    const float* sresc = (const float*)d_in[15];
    const float* sf1   = (const float*)d_in[16];
    const float* sf2   = (const float*)d_in[17];
    const float* pl1w  = (const float*)d_in[18];
    const float* pl1b  = (const float*)d_in[19];
    const float* pl2w  = (const float*)d_in[20];
    const float* pl2b  = (const float*)d_in[21];
    const float* pwq   = (const float*)d_in[22];
    const float* pwk   = (const float*)d_in[23];
    const float* pwv   = (const float*)d_in[24];
    const float* ppw   = (const float*)d_in[25];
    const float* pm2w  = (const float*)d_in[26];
    const float* ppb   = (const float*)d_in[27];
    const float* presc = (const float*)d_in[28];
    const float* pm1w  = (const float*)d_in[29];
    const float* pm1b  = (const float*)d_in[30];
    const float* pm2b  = (const float*)d_in[31];
    const float* pf1   = (const float*)d_in[32];
    const float* pf2   = (const float*)d_in[33];
    const float* fw1   = (const float*)d_in[34];
    const float* fb1   = (const float*)d_in[35];
    const float* fw2   = (const float*)d_in[36];
    const float* fb2   = (const float*)d_in[37];

    // workspace layout: 6 big buffers (202MB) + small scratch; d_out doubles as staging
    float* ws_f = (float*)d_ws;
    float* xs = ws_f;
    float* xp = ws_f + (size_t)SBUF;
    float* A  = ws_f + 2*(size_t)SBUF;
    float* Q  = ws_f + 3*(size_t)SBUF;
    float* K  = ws_f + 4*(size_t)SBUF;
    float* V  = ws_f + 5*(size_t)SBUF;
    float* small = ws_f + 6*(size_t)SBUF;
    float* mg   = small;                // 131072
    float* att  = mg + 131072;          // 4096
    float* svec = att + 4096;           // 512
    float* M    = svec + 512;           // 32768
    float* wbar = M + 32768;            // 65
    float* stage = (float*)d_out;       // scratch until fusion (written before read)
    float* Tf = Q;                      // fusion temp (Q is dead by then)

    hipMemcpyAsync(xs, x, (size_t)SBUF*4, hipMemcpyDeviceToDevice, stream);
    hipMemcpyAsync(xp, x, (size_t)SBUF*4, hipMemcpyDeviceToDevice, stream);

    // ---- spectral branch ----
    for(int i=0;i<2;i++){
        ln_kernel<<<512,256,0,stream>>>(xs, sl1w+i*64, sl1b+i*64, A);
        pw_kernel<<<512,256,0,stream>>>(A, swq+i*4096, nullptr, nullptr, stage, 0);
        dw3x3_kernel<<<32768,256,0,stream>>>(stage, sdq+i*576, Q);
        pw_kernel<<<512,256,0,stream>>>(A, swk+i*4096, nullptr, nullptr, stage, 0);
        dw3x3_kernel<<<32768,256,0,stream>>>(stage, sdk+i*576, K);
        pw_kernel<<<512,256,0,stream>>>(A, swv+i*4096, nullptr, nullptr, stage, 0);
        dw3x3_kernel<<<32768,256,0,stream>>>(stage, sdv+i*576, V);
        l2n_kernel<<<512,256,0,stream>>>(Q);
        l2n_kernel<<<512,256,0,stream>>>(K);
        qk_kernel<<<512,256,0,stream>>>(Q, K, att);
        zero512<<<2,256,0,stream>>>(svec);
        mbconv4_kernel<<<1024,256,0,stream>>>(mask, smp1+i*36864, svec);
        spec_softmax_kernel<<<8,64,0,stream>>>(att, svec, smp2+i*4096, sresc+i*8);
        mmat_kernel<<<8,256,0,stream>>>(att, sproj+i*4096, M);
        pw_kernel<<<512,256,0,stream>>>(V, M, nullptr, xs, xs, 1);
        ln_kernel<<<512,256,0,stream>>>(xs, sl2w+i*64, sl2b+i*64, A);
        ffn2d_kernel<<<512,256,0,stream>>>(A, sf1+i*2304, sf2+i*16384, xs);
    }
    // ---- polar branch ----
    for(int i=0;i<2;i++){
        ln_kernel<<<512,256,0,stream>>>(xp, pl1w+i*64, pl1b+i*64, A);
        pw_kernel<<<512,256,0,stream>>>(A, pwq+i*4096, nullptr, nullptr, Q, 0);
        pw_kernel<<<512,256,0,stream>>>(A, pwk+i*4096, nullptr, nullptr, K, 0);
        pw_kernel<<<512,256,0,stream>>>(A, pwv+i*4096, nullptr, nullptr, V, 0);
        wbar_kernel<<<1,64,0,stream>>>(pm2w+i*4096, pm2b+i*64, wbar);
        mg_kernel<<<512,256,0,stream>>>(mask, pm1w+i*576, pm1b+i*64, wbar, mg);
        att_pol_kernel<<<128,256,0,stream>>>(Q, K, V, mg, presc+i*8, stage);
        pw_kernel<<<512,256,0,stream>>>(stage, ppw+i*4096, ppb+i*64, xp, xp, 0);
        ln_kernel<<<512,256,0,stream>>>(xp, pl2w+i*64, pl2b+i*64, A);
        ffn3d_kernel<<<512,256,0,stream>>>(A, pf1+i*6912, pf2+i*16384, xp);
    }
    // ---- fusion ----
    fuse1_kernel<<<512,256,0,stream>>>(xs, xp, fw1, fb1, Tf);
    fuse2_kernel<<<32768,256,0,stream>>>(Tf, fw2, fb2, xs, xp, (float*)d_out);
}

// Round 5
// 3199.339 us; speedup vs baseline: 9.2369x; 1.3103x over previous
//
#include <hip/hip_runtime.h>
#include <math.h>

// Problem constants (B=8, C=64, H=W=128, HEADS=8, ch=8, L=2, P=4)
#define NPIX 16384               // 128*128
#define SBUF 8388608             // 8*64*16384 elements per full tensor

__device__ __forceinline__ float gelu_f(float x){
    return 0.5f*x*(1.0f+erff(x*0.70710678118654752440f));
}
__device__ __forceinline__ float waveReduceSum(float v){
    #pragma unroll
    for(int off=32;off>0;off>>=1) v += __shfl_down(v, off);
    return v;
}

// ---------------- LayerNorm over channel dim (64) ----------------
__global__ __launch_bounds__(256) void ln_kernel(const float* __restrict__ x,
        const float* __restrict__ w, const float* __restrict__ b, float* __restrict__ out){
    int idx = blockIdx.x*256 + threadIdx.x;      // over B*NPIX
    int bb = idx >> 14, n = idx & 16383;
    const float* ip = x + ((size_t)bb<<20) + n;
    float v[64]; float s = 0.f;
    #pragma unroll
    for(int c=0;c<64;c++){ v[c] = ip[(size_t)c<<14]; s += v[c]; }
    float mu = s*(1.f/64.f); float ss = 0.f;
    #pragma unroll
    for(int c=0;c<64;c++){ float d = v[c]-mu; ss += d*d; }
    float r = rsqrtf(ss*(1.f/64.f) + 1e-5f);
    float* op = out + ((size_t)bb<<20) + n;
    #pragma unroll
    for(int c=0;c<64;c++) op[(size_t)c<<14] = (v[c]-mu)*r*w[c] + b[c];
}

// ---------------- 1x1 conv: out[o] = sum_c w[o,c]*in[c] (+bias)(+res) ----------------
__global__ __launch_bounds__(256) void pw_kernel(const float* __restrict__ in,
        const float* __restrict__ w, const float* __restrict__ bias,
        const float* __restrict__ res, float* __restrict__ out, int wPerB){
    __shared__ float wl[4096];                   // transposed: wl[c*64+o]
    int t = threadIdx.x;
    int idx = blockIdx.x*256 + t;
    int b = idx >> 14, n = idx & 16383;
    const float* wp = w + (wPerB ? b*4096 : 0);
    for(int i=t;i<4096;i+=256) wl[(i&63)*64 + (i>>6)] = wp[i];
    __syncthreads();
    float acc[64];
    if(bias){
        #pragma unroll
        for(int o=0;o<64;o++) acc[o] = bias[o];
    } else {
        #pragma unroll
        for(int o=0;o<64;o++) acc[o] = 0.f;
    }
    const float* ip = in + ((size_t)b<<20) + n;
    for(int c=0;c<64;c++){
        float v = ip[(size_t)c<<14];
        const float4* wv = (const float4*)&wl[c*64];
        #pragma unroll
        for(int o4=0;o4<16;o4++){
            float4 w4 = wv[o4];
            acc[o4*4+0] += w4.x*v; acc[o4*4+1] += w4.y*v;
            acc[o4*4+2] += w4.z*v; acc[o4*4+3] += w4.w*v;
        }
    }
    size_t baseo = ((size_t)b<<20) + n;
    if(res){
        #pragma unroll
        for(int o=0;o<64;o++) out[baseo+((size_t)o<<14)] = acc[o] + res[baseo+((size_t)o<<14)];
    } else {
        #pragma unroll
        for(int o=0;o<64;o++) out[baseo+((size_t)o<<14)] = acc[o];
    }
}

// ---------------- depthwise 3x3, zero pad ----------------
__global__ __launch_bounds__(256) void dw3x3_kernel(const float* __restrict__ in,
        const float* __restrict__ wd, float* __restrict__ out){
    int idx = blockIdx.x*256 + threadIdx.x;      // over B*64*NPIX
    int n = idx & 16383; int bc = idx >> 14; int c = bc & 63;
    int y = n >> 7, x = n & 127;
    bool ym=y>0, yp=y<127, xm=x>0, xpv=x<127;
    const float* cp = in + ((size_t)bc<<14) + n;
    const float* wp = wd + c*9;
    float s = cp[0]*wp[4];
    if(ym){ s += cp[-128]*wp[1]; if(xm) s += cp[-129]*wp[0]; if(xpv) s += cp[-127]*wp[2]; }
    if(xm)  s += cp[-1]*wp[3];
    if(xpv) s += cp[1]*wp[5];
    if(yp){ s += cp[128]*wp[7]; if(xm) s += cp[127]*wp[6]; if(xpv) s += cp[129]*wp[8]; }
    out[idx] = s;
}

// ---------------- L2 normalize each (b,c) plane over NPIX ----------------
__global__ __launch_bounds__(256) void l2n_kernel(float* __restrict__ q){
    int bc = blockIdx.x;
    float* p = q + ((size_t)bc<<14);
    int t = threadIdx.x;
    float ss = 0.f;
    for(int n=t;n<NPIX;n+=256){ float v=p[n]; ss += v*v; }
    ss = waveReduceSum(ss);
    __shared__ float red[4];
    __shared__ float scale_s;
    if((t&63)==0) red[t>>6] = ss;
    __syncthreads();
    if(t==0) scale_s = 1.f/fmaxf(sqrtf(red[0]+red[1]+red[2]+red[3]), 1e-12f);
    __syncthreads();
    float sc = scale_s;
    for(int n=t;n<NPIX;n+=256) p[n] *= sc;
}

// ---------------- spectral attention: att[b,h,c,d] = sum_n q[c,n] k[d,n] ----------------
__global__ __launch_bounds__(256) void qk_kernel(const float* __restrict__ Q,
        const float* __restrict__ K, float* __restrict__ att){
    int blk = blockIdx.x;                        // B*HEADS*8 = 512
    int c = blk & 7, bh = blk >> 3;              // bh = b*8+head
    const float* qp = Q + (((size_t)bh*8 + c)<<14);
    const float* kp = K + (((size_t)bh*8)<<14);
    float p[8] = {0,0,0,0,0,0,0,0};
    for(int n=threadIdx.x;n<NPIX;n+=256){
        float qv = qp[n];
        #pragma unroll
        for(int d=0;d<8;d++) p[d] += qv*kp[((size_t)d<<14)+n];
    }
    #pragma unroll
    for(int off=32;off>0;off>>=1){
        #pragma unroll
        for(int d=0;d<8;d++) p[d] += __shfl_down(p[d], off);
    }
    __shared__ float red[4][8];
    int wave = threadIdx.x>>6, lane = threadIdx.x&63;
    if(lane==0){
        #pragma unroll
        for(int d=0;d<8;d++) red[wave][d] = p[d];
    }
    __syncthreads();
    if(threadIdx.x<8){
        float s = red[0][threadIdx.x]+red[1][threadIdx.x]+red[2][threadIdx.x]+red[3][threadIdx.x];
        att[blk*8+threadIdx.x] = s;
    }
}

// ---------------- zero helper ----------------
__global__ void zero512(float* __restrict__ p){
    p[blockIdx.x*256 + threadIdx.x] = 0.f;
}

// ---------------- mask bias v4: pw-kernel shape. One-time 36KB LDS fill (16 outputs),
// 2 pixels/thread, no mid-loop barriers. svec[b,m] += relu-sum over block's pixels. ----
__global__ __launch_bounds__(256) void mbconv4_kernel(const float* __restrict__ mask,
        const float* __restrict__ w, float* __restrict__ svec){
    __shared__ float wl[9216];                   // 36 KB: wl[ck*16+mo], ck in [0,576)
    __shared__ float red[4][16];
    int t = threadIdx.x;
    int og = blockIdx.x & 3;                     // output-channel group (16 each)
    int pb = (blockIdx.x >> 2) & 31;             // 512-pixel block
    int b  = blockIdx.x >> 7;
    const float* wp = w + (size_t)og*16*576;
    for(int i=t;i<9216;i+=256){
        int mo = i & 15, ck = i >> 4;
        wl[i] = wp[mo*576 + ck];
    }
    __syncthreads();
    int n0 = pb*512 + t;                         // pixel 0
    int n1 = n0 + 256;                           // pixel 1
    int y0 = n0>>7, x0 = n0&127;
    int y1 = n1>>7, x1 = n1&127;
    bool ym0=y0>0, yp0=y0<127, xm0=x0>0, xp0=x0<127;
    bool ym1=y1>0, yp1=y1<127, xm1=x1>0, xp1=x1<127;
    const float* mp = mask + ((size_t)b<<20);
    float acc0[16], acc1[16];
    #pragma unroll
    for(int o=0;o<16;o++){ acc0[o]=0.f; acc1[o]=0.f; }
    for(int c=0;c<64;c++){
        const float* cp0 = mp + ((size_t)c<<14) + n0;
        const float* cp1 = mp + ((size_t)c<<14) + n1;
        float ta[9], tb[9];
        ta[0] = (ym0&&xm0)? cp0[-129]:0.f;
        ta[1] =  ym0?       cp0[-128]:0.f;
        ta[2] = (ym0&&xp0)? cp0[-127]:0.f;
        ta[3] =  xm0?       cp0[-1]:0.f;
        ta[4] =             cp0[0];
        ta[5] =  xp0?       cp0[1]:0.f;
        ta[6] = (yp0&&xm0)? cp0[127]:0.f;
        ta[7] =  yp0?       cp0[128]:0.f;
        ta[8] = (yp0&&xp0)? cp0[129]:0.f;
        tb[0] = (ym1&&xm1)? cp1[-129]:0.f;
        tb[1] =  ym1?       cp1[-128]:0.f;
        tb[2] = (ym1&&xp1)? cp1[-127]:0.f;
        tb[3] =  xm1?       cp1[-1]:0.f;
        tb[4] =             cp1[0];
        tb[5] =  xp1?       cp1[1]:0.f;
        tb[6] = (yp1&&xm1)? cp1[127]:0.f;
        tb[7] =  yp1?       cp1[128]:0.f;
        tb[8] = (yp1&&xp1)? cp1[129]:0.f;
        #pragma unroll
        for(int k=0;k<9;k++){
            float va = ta[k], vb = tb[k];
            const float4* wv = (const float4*)&wl[(c*9+k)*16];
            #pragma unroll
            for(int o4=0;o4<4;o4++){
                float4 w4 = wv[o4];
                acc0[o4*4+0] += w4.x*va; acc0[o4*4+1] += w4.y*va;
                acc0[o4*4+2] += w4.z*va; acc0[o4*4+3] += w4.w*va;
                acc1[o4*4+0] += w4.x*vb; acc1[o4*4+1] += w4.y*vb;
                acc1[o4*4+2] += w4.z*vb; acc1[o4*4+3] += w4.w*vb;
            }
        }
    }
    // relu both pixels, reduce across block, atomic into svec
    int wave = t>>6, lane = t&63;
    #pragma unroll
    for(int m=0;m<16;m++){
        float v = waveReduceSum(fmaxf(acc0[m],0.f) + fmaxf(acc1[m],0.f));
        if(lane==0) red[wave][m] = v;
    }
    __syncthreads();
    if(t<16){
        float s = red[0][t]+red[1][t]+red[2][t]+red[3][t];
        atomicAdd(&svec[b*64 + og*16 + t], s);
    }
}

// ---------------- spectral: mb projection + scale + bias + softmax over d ----------------
__global__ void spec_softmax_kernel(float* __restrict__ att, const float* __restrict__ svec,
        const float* __restrict__ smp2, const float* __restrict__ resc){
    int b = blockIdx.x, t = threadIdx.x;         // 8 blocks, 64 threads
    __shared__ float mb[64];
    float a = 0.f;
    for(int m=0;m<64;m++) a += smp2[t*64+m]*svec[b*64+m];
    mb[t] = a*(1.f/16384.f);
    __syncthreads();
    int h = t>>3, c = t&7;
    float* ap = att + (size_t)(b*8+h)*64 + c*8;
    float rs = resc[h];
    float v[8]; float mx = -1e30f;
    #pragma unroll
    for(int d=0;d<8;d++){ v[d] = ap[d]*rs + mb[h*8+d] - mb[h*8+c]; mx = fmaxf(mx, v[d]); }
    float s = 0.f;
    #pragma unroll
    for(int d=0;d<8;d++){ v[d] = expf(v[d]-mx); s += v[d]; }
    float inv = 1.f/s;
    #pragma unroll
    for(int d=0;d<8;d++) ap[d] = v[d]*inv;
}

// ---------------- M[b] = sproj @ blockdiag(att[b]) (64x64 per batch) ----------------
__global__ void mmat_kernel(const float* __restrict__ att, const float* __restrict__ sproj,
        float* __restrict__ M){
    int b = blockIdx.x;
    for(int e=threadIdx.x;e<4096;e+=256){
        int o = e>>6, j = e&63;
        int h = j>>3, jj = j&7;
        float s = 0.f;
        #pragma unroll
        for(int cc=0;cc<8;cc++) s += sproj[o*64 + h*8+cc]*att[(size_t)(b*8+h)*64 + cc*8 + jj];
        M[b*4096 + e] = s;
    }
}

// ---------------- FFN2D fused: dw3x3(x4) -> GELU -> 256->64 proj, += residual ----------------
__global__ __launch_bounds__(256) void ffn2d_kernel(const float* __restrict__ A,
        const float* __restrict__ w1, const float* __restrict__ w2, float* __restrict__ xs){
    __shared__ float w2l[16384];                 // transposed: [m*64+o]
    int t = threadIdx.x;
    for(int i=t;i<16384;i+=256){ int o=i>>8, m=i&255; w2l[m*64+o] = w2[i]; }
    __syncthreads();
    int idx = blockIdx.x*256 + t;
    int b = idx>>14, n = idx&16383;
    int y = n>>7, x = n&127;
    bool ym=y>0, yp=y<127, xm=x>0, xpv=x<127;
    const float* ap = A + ((size_t)b<<20) + n;
    float acc[64];
    #pragma unroll
    for(int o=0;o<64;o++) acc[o] = 0.f;
    for(int c=0;c<64;c++){
        const float* cp = ap + ((size_t)c<<14);
        float t00 = (ym&&xm)? cp[-129]:0.f;
        float t01 =  ym?      cp[-128]:0.f;
        float t02 = (ym&&xpv)?cp[-127]:0.f;
        float t10 =  xm?      cp[-1]:0.f;
        float t11 =           cp[0];
        float t12 =  xpv?     cp[1]:0.f;
        float t20 = (yp&&xm)? cp[127]:0.f;
        float t21 =  yp?      cp[128]:0.f;
        float t22 = (yp&&xpv)?cp[129]:0.f;
        const float* w1c = w1 + c*36;
        #pragma unroll
        for(int j=0;j<4;j++){
            const float* wj = w1c + j*9;
            float cv = t00*wj[0]+t01*wj[1]+t02*wj[2]+t10*wj[3]+t11*wj[4]
                      +t12*wj[5]+t20*wj[6]+t21*wj[7]+t22*wj[8];
            float g = gelu_f(cv);
            const float4* wv = (const float4*)&w2l[(c*4+j)*64];
            #pragma unroll
            for(int o4=0;o4<16;o4++){
                float4 w4 = wv[o4];
                acc[o4*4+0] += w4.x*g; acc[o4*4+1] += w4.y*g;
                acc[o4*4+2] += w4.z*g; acc[o4*4+3] += w4.w*g;
            }
        }
    }
    size_t baseo = ((size_t)b<<20) + n;
    #pragma unroll
    for(int o=0;o<64;o++) xs[baseo+((size_t)o<<14)] += acc[o];
}

// ---------------- polar: wbar[c] = mean_o pm2w[o,c]; wbar[64] = mean(pm2b) ----------------
__global__ void wbar_kernel(const float* __restrict__ pm2w, const float* __restrict__ pm2b,
        float* __restrict__ wbar){
    int t = threadIdx.x;                         // 64
    float s = 0.f;
    for(int o=0;o<64;o++) s += pm2w[o*64+t];
    wbar[t] = s*(1.f/64.f);
    if(t==0){
        float sb = 0.f;
        for(int o=0;o<64;o++) sb += pm2b[o];
        wbar[64] = sb*(1.f/64.f);
    }
}

// ---------------- polar mask gate: mg[b,n] = sum_c wbar[c]*gelu(dw3x3(mask)[c]+pm1b[c]) + bbar ----------------
__global__ __launch_bounds__(256) void mg_kernel(const float* __restrict__ mask,
        const float* __restrict__ w1, const float* __restrict__ b1,
        const float* __restrict__ wbar, float* __restrict__ mg){
    int idx = blockIdx.x*256 + threadIdx.x;      // over B*NPIX
    int b = idx>>14, n = idx&16383;
    int y = n>>7, x = n&127;
    bool ym=y>0, yp=y<127, xm=x>0, xpv=x<127;
    const float* ap = mask + ((size_t)b<<20) + n;
    float acc = wbar[64];
    for(int c=0;c<64;c++){
        const float* cp = ap + ((size_t)c<<14);
        const float* wj = w1 + c*9;
        float cv = b1[c] + cp[0]*wj[4];
        if(ym){ cv += cp[-128]*wj[1]; if(xm) cv += cp[-129]*wj[0]; if(xpv) cv += cp[-127]*wj[2]; }
        if(xm)  cv += cp[-1]*wj[3];
        if(xpv) cv += cp[1]*wj[5];
        if(yp){ cv += cp[128]*wj[7]; if(xm) cv += cp[127]*wj[6]; if(xpv) cv += cp[129]*wj[8]; }
        acc += wbar[c]*gelu_f(cv);
    }
    mg[idx] = acc;
}

// ---------------- polar attention (P=4, ch=8 per head), writes O (pre-projection) ----------------
__global__ __launch_bounds__(256) void att_pol_kernel(const float* __restrict__ Q,
        const float* __restrict__ K, const float* __restrict__ V,
        const float* __restrict__ mg, const float* __restrict__ resc, float* __restrict__ O){
    int idx = blockIdx.x*256 + threadIdx.x;      // over BN*NPIX = 32768
    int bn = idx>>14, n = idx&16383;
    float mgv[4];
    #pragma unroll
    for(int p=0;p<4;p++) mgv[p] = mg[(((bn<<2)+p)<<14) + n];
    for(int h=0;h<8;h++){
        size_t base = ((size_t)bn<<22) + ((size_t)h<<17) + n;
        float q[4][8], k[4][8], v[4][8];
        #pragma unroll
        for(int p=0;p<4;p++){
            size_t pb = base + ((size_t)p<<20);
            #pragma unroll
            for(int j=0;j<8;j++){
                size_t o = pb + ((size_t)j<<14);
                q[p][j] = Q[o]; k[p][j] = K[o]; v[p][j] = V[o];
            }
        }
        #pragma unroll
        for(int p=0;p<4;p++){
            float sq=0.f, sk=0.f;
            #pragma unroll
            for(int j=0;j<8;j++){ sq += q[p][j]*q[p][j]; sk += k[p][j]*k[p][j]; }
            float iq = 1.f/fmaxf(sqrtf(sq),1e-12f), ik = 1.f/fmaxf(sqrtf(sk),1e-12f);
            #pragma unroll
            for(int j=0;j<8;j++){ q[p][j]*=iq; k[p][j]*=ik; }
        }
        float rs = resc[h];
        float att[4][4];
        #pragma unroll
        for(int p=0;p<4;p++){
            #pragma unroll
            for(int r=0;r<4;r++){
                float d = 0.f;
                #pragma unroll
                for(int j=0;j<8;j++) d += q[p][j]*k[r][j];
                att[p][r] = rs*d + mgv[r] - mgv[p];
            }
        }
        #pragma unroll
        for(int p=0;p<4;p++){
            float mx = fmaxf(fmaxf(att[p][0],att[p][1]),fmaxf(att[p][2],att[p][3]));
            float s = 0.f;
            #pragma unroll
            for(int r=0;r<4;r++){ att[p][r] = expf(att[p][r]-mx); s += att[p][r]; }
            float inv = 1.f/s;
            #pragma unroll
            for(int r=0;r<4;r++) att[p][r] *= inv;
        }
        #pragma unroll
        for(int p=0;p<4;p++){
            size_t pb = base + ((size_t)p<<20);
            #pragma unroll
            for(int j=0;j<8;j++){
                float o = att[p][0]*v[0][j]+att[p][1]*v[1][j]+att[p][2]*v[2][j]+att[p][3]*v[3][j];
                O[pb + ((size_t)j<<14)] = o;
            }
        }
    }
}

// ---------------- FFN3D fused: 3D dw conv 3x3x3 (x4) -> GELU -> 256->64 proj, += residual ----------------
__global__ __launch_bounds__(256) void ffn3d_kernel(const float* __restrict__ A,
        const float* __restrict__ w1, const float* __restrict__ w2, float* __restrict__ xp){
    __shared__ float w2l[16384];
    int t = threadIdx.x;
    for(int i=t;i<16384;i+=256){ int o=i>>8, m=i&255; w2l[m*64+o] = w2[i]; }
    __syncthreads();
    int idx = blockIdx.x*256 + t;                // over B*NPIX
    int bp = idx>>14, n = idx&16383;
    int bn = bp>>2, p = bp&3;
    int y = n>>7, x = n&127;
    bool ym=y>0, yp=y<127, xm=x>0, xpv=x<127;
    float acc[64];
    #pragma unroll
    for(int o=0;o<64;o++) acc[o] = 0.f;
    for(int c=0;c<64;c++){
        float tap[27];
        #pragma unroll
        for(int dz=0;dz<3;dz++){
            int pp = p + dz - 1;
            if(pp < 0 || pp > 3){
                #pragma unroll
                for(int k9=0;k9<9;k9++) tap[dz*9+k9] = 0.f;
            } else {
                const float* cp = A + ((size_t)((bn<<2)+pp)<<20) + ((size_t)c<<14) + n;
                tap[dz*9+0] = (ym&&xm)? cp[-129]:0.f;
                tap[dz*9+1] =  ym?      cp[-128]:0.f;
                tap[dz*9+2] = (ym&&xpv)?cp[-127]:0.f;
                tap[dz*9+3] =  xm?      cp[-1]:0.f;
                tap[dz*9+4] =           cp[0];
                tap[dz*9+5] =  xpv?     cp[1]:0.f;
                tap[dz*9+6] = (yp&&xm)? cp[127]:0.f;
                tap[dz*9+7] =  yp?      cp[128]:0.f;
                tap[dz*9+8] = (yp&&xpv)?cp[129]:0.f;
            }
        }
        const float* w1c = w1 + c*108;
        #pragma unroll
        for(int j=0;j<4;j++){
            const float* wj = w1c + j*27;
            float cv = 0.f;
            #pragma unroll
            for(int k27=0;k27<27;k27++) cv += tap[k27]*wj[k27];
            float g = gelu_f(cv);
            const float4* wv = (const float4*)&w2l[(c*4+j)*64];
            #pragma unroll
            for(int o4=0;o4<16;o4++){
                float4 w4 = wv[o4];
                acc[o4*4+0] += w4.x*g; acc[o4*4+1] += w4.y*g;
                acc[o4*4+2] += w4.z*g; acc[o4*4+3] += w4.w*g;
            }
        }
    }
    size_t baseo = ((size_t)bp<<20) + n;
    #pragma unroll
    for(int o=0;o<64;o++) xp[baseo+((size_t)o<<14)] += acc[o];
}

// ---------------- fusion stage 1: T = relu(fw1 @ [xs;xp] + fb1) ----------------
__global__ __launch_bounds__(256) void fuse1_kernel(const float* __restrict__ xs,
        const float* __restrict__ xp, const float* __restrict__ fw1,
        const float* __restrict__ fb1, float* __restrict__ T){
    __shared__ float wl[8192];                   // wl[c*64+o] = fw1[o*128+c], c in 0..127
    int t = threadIdx.x;
    for(int i=t;i<8192;i+=256) wl[(i&127)*64 + (i>>7)] = fw1[i];
    __syncthreads();
    int idx = blockIdx.x*256 + t;
    int b = idx>>14, n = idx&16383;
    float acc[64];
    #pragma unroll
    for(int o=0;o<64;o++) acc[o] = fb1[o];
    const float* ip = xs + ((size_t)b<<20) + n;
    for(int c=0;c<64;c++){
        float v = ip[(size_t)c<<14];
        const float4* wv = (const float4*)&wl[c*64];
        #pragma unroll
        for(int o4=0;o4<16;o4++){
            float4 w4 = wv[o4];
            acc[o4*4+0] += w4.x*v; acc[o4*4+1] += w4.y*v;
            acc[o4*4+2] += w4.z*v; acc[o4*4+3] += w4.w*v;
        }
    }
    const float* ip2 = xp + ((size_t)b<<20) + n;
    for(int c=0;c<64;c++){
        float v = ip2[(size_t)c<<14];
        const float4* wv = (const float4*)&wl[(64+c)*64];
        #pragma unroll
        for(int o4=0;o4<16;o4++){
            float4 w4 = wv[o4];
            acc[o4*4+0] += w4.x*v; acc[o4*4+1] += w4.y*v;
            acc[o4*4+2] += w4.z*v; acc[o4*4+3] += w4.w*v;
        }
    }
    size_t baseo = ((size_t)b<<20) + n;
    #pragma unroll
    for(int o=0;o<64;o++) T[baseo+((size_t)o<<14)] = fmaxf(acc[o], 0.f);
}

// ---------------- fusion stage 2 v2 (mbconv4 shape): 16 outputs per block, 2 px/thread.
// out = sig(conv3x3(T)+fb2)*xs + (1-sig)*xp ----------------
__global__ __launch_bounds__(256) void fuse2v2_kernel(const float* __restrict__ T,
        const float* __restrict__ fw2, const float* __restrict__ fb2,
        const float* __restrict__ xs, const float* __restrict__ xp, float* __restrict__ out){
    __shared__ float wl[9216];                   // 36 KB: wl[ck*16+mo], ck = c*9+k
    int t = threadIdx.x;
    int og = blockIdx.x & 3;                     // output-channel group (16 each)
    int pb = (blockIdx.x >> 2) & 31;             // 512-pixel block
    int b  = blockIdx.x >> 7;
    const float* wp = fw2 + (size_t)og*16*576;
    for(int i=t;i<9216;i+=256){
        int mo = i & 15, ck = i >> 4;
        wl[i] = wp[mo*576 + ck];
    }
    __syncthreads();
    int n0 = pb*512 + t;
    int n1 = n0 + 256;
    int y0 = n0>>7, x0 = n0&127;
    int y1 = n1>>7, x1 = n1&127;
    bool ym0=y0>0, yp0=y0<127, xm0=x0>0, xp0=x0<127;
    bool ym1=y1>0, yp1=y1<127, xm1=x1>0, xp1=x1<127;
    const float* tp = T + ((size_t)b<<20);
    float acc0[16], acc1[16];
    #pragma unroll
    for(int o=0;o<16;o++){ acc0[o]=0.f; acc1[o]=0.f; }
    for(int c=0;c<64;c++){
        const float* cp0 = tp + ((size_t)c<<14) + n0;
        const float* cp1 = tp + ((size_t)c<<14) + n1;
        float ta[9], tb[9];
        ta[0] = (ym0&&xm0)? cp0[-129]:0.f;
        ta[1] =  ym0?       cp0[-128]:0.f;
        ta[2] = (ym0&&xp0)? cp0[-127]:0.f;
        ta[3] =  xm0?       cp0[-1]:0.f;
        ta[4] =             cp0[0];
        ta[5] =  xp0?       cp0[1]:0.f;
        ta[6] = (yp0&&xm0)? cp0[127]:0.f;
        ta[7] =  yp0?       cp0[128]:0.f;
        ta[8] = (yp0&&xp0)? cp0[129]:0.f;
        tb[0] = (ym1&&xm1)? cp1[-129]:0.f;
        tb[1] =  ym1?       cp1[-128]:0.f;
        tb[2] = (ym1&&xp1)? cp1[-127]:0.f;
        tb[3] =  xm1?       cp1[-1]:0.f;
        tb[4] =             cp1[0];
        tb[5] =  xp1?       cp1[1]:0.f;
        tb[6] = (yp1&&xm1)? cp1[127]:0.f;
        tb[7] =  yp1?       cp1[128]:0.f;
        tb[8] = (yp1&&xp1)? cp1[129]:0.f;
        #pragma unroll
        for(int k=0;k<9;k++){
            float va = ta[k], vb = tb[k];
            const float4* wv = (const float4*)&wl[(c*9+k)*16];
            #pragma unroll
            for(int o4=0;o4<4;o4++){
                float4 w4 = wv[o4];
                acc0[o4*4+0] += w4.x*va; acc0[o4*4+1] += w4.y*va;
                acc0[o4*4+2] += w4.z*va; acc0[o4*4+3] += w4.w*va;
                acc1[o4*4+0] += w4.x*vb; acc1[o4*4+1] += w4.y*vb;
                acc1[o4*4+2] += w4.z*vb; acc1[o4*4+3] += w4.w*vb;
            }
        }
    }
    // epilogue: sigmoid gate + mix, write 16 outputs x 2 pixels
    #pragma unroll
    for(int m=0;m<16;m++){
        int o = og*16 + m;
        float bias = fb2[o];
        size_t i0 = ((size_t)b<<20) + ((size_t)o<<14) + n0;
        size_t i1 = ((size_t)b<<20) + ((size_t)o<<14) + n1;
        float a0 = 1.f/(1.f+expf(-(acc0[m]+bias)));
        float a1 = 1.f/(1.f+expf(-(acc1[m]+bias)));
        out[i0] = a0*xs[i0] + (1.f-a0)*xp[i0];
        out[i1] = a1*xs[i1] + (1.f-a1)*xp[i1];
    }
}

extern "C" void kernel_launch(void* const* d_in, const int* in_sizes, int n_in,
                              void* d_out, int out_size, void* d_ws, size_t ws_size,
                              hipStream_t stream) {
    // setup_inputs() dict order
    const float* x     = (const float*)d_in[0];
    const float* mask  = (const float*)d_in[1];
    const float* sl1w  = (const float*)d_in[2];
    const float* sl1b  = (const float*)d_in[3];
    const float* sl2w  = (const float*)d_in[4];
    const float* sl2b  = (const float*)d_in[5];
    const float* swq   = (const float*)d_in[6];
    const float* swk   = (const float*)d_in[7];
    const float* swv   = (const float*)d_in[8];
    const float* sproj = (const float*)d_in[9];
    const float* smp2  = (const float*)d_in[10];
    const float* sdq   = (const float*)d_in[11];
    const float* sdk   = (const float*)d_in[12];
    const float* sdv   = (const float*)d_in[13];
    const float* smp1  = (const float*)d_in[14];
    const float* sresc = (const float*)d_in[15];
    const float* sf1   = (const float*)d_in[16];
    const float* sf2   = (const float*)d_in[17];
    const float* pl1w  = (const float*)d_in[18];
    const float* pl1b  = (const float*)d_in[19];
    const float* pl2w  = (const float*)d_in[20];
    const float* pl2b  = (const float*)d_in[21];
    const float* pwq   = (const float*)d_in[22];
    const float* pwk   = (const float*)d_in[23];
    const float* pwv   = (const float*)d_in[24];
    const float* ppw   = (const float*)d_in[25];
    const float* pm2w  = (const float*)d_in[26];
    const float* ppb   = (const float*)d_in[27];
    const float* presc = (const float*)d_in[28];
    const float* pm1w  = (const float*)d_in[29];
    const float* pm1b  = (const float*)d_in[30];
    const float* pm2b  = (const float*)d_in[31];
    const float* pf1   = (const float*)d_in[32];
    const float* pf2   = (const float*)d_in[33];
    const float* fw1   = (const float*)d_in[34];
    const float* fb1   = (const float*)d_in[35];
    const float* fw2   = (const float*)d_in[36];
    const float* fb2   = (const float*)d_in[37];

    // workspace layout: 6 big buffers (202MB) + small scratch; d_out doubles as staging
    float* ws_f = (float*)d_ws;
    float* xs = ws_f;
    float* xp = ws_f + (size_t)SBUF;
    float* A  = ws_f + 2*(size_t)SBUF;
    float* Q  = ws_f + 3*(size_t)SBUF;
    float* K  = ws_f + 4*(size_t)SBUF;
    float* V  = ws_f + 5*(size_t)SBUF;
    float* small = ws_f + 6*(size_t)SBUF;
    float* mg   = small;                // 131072
    float* att  = mg + 131072;          // 4096
    float* svec = att + 4096;           // 512
    float* M    = svec + 512;           // 32768
    float* wbar = M + 32768;            // 65
    float* stage = (float*)d_out;       // scratch until fusion (written before read)
    float* Tf = Q;                      // fusion temp (Q is dead by then)

    hipMemcpyAsync(xs, x, (size_t)SBUF*4, hipMemcpyDeviceToDevice, stream);
    hipMemcpyAsync(xp, x, (size_t)SBUF*4, hipMemcpyDeviceToDevice, stream);

    // ---- spectral branch ----
    for(int i=0;i<2;i++){
        ln_kernel<<<512,256,0,stream>>>(xs, sl1w+i*64, sl1b+i*64, A);
        pw_kernel<<<512,256,0,stream>>>(A, swq+i*4096, nullptr, nullptr, stage, 0);
        dw3x3_kernel<<<32768,256,0,stream>>>(stage, sdq+i*576, Q);
        pw_kernel<<<512,256,0,stream>>>(A, swk+i*4096, nullptr, nullptr, stage, 0);
        dw3x3_kernel<<<32768,256,0,stream>>>(stage, sdk+i*576, K);
        pw_kernel<<<512,256,0,stream>>>(A, swv+i*4096, nullptr, nullptr, stage, 0);
        dw3x3_kernel<<<32768,256,0,stream>>>(stage, sdv+i*576, V);
        l2n_kernel<<<512,256,0,stream>>>(Q);
        l2n_kernel<<<512,256,0,stream>>>(K);
        qk_kernel<<<512,256,0,stream>>>(Q, K, att);
        zero512<<<2,256,0,stream>>>(svec);
        mbconv4_kernel<<<1024,256,0,stream>>>(mask, smp1+i*36864, svec);
        spec_softmax_kernel<<<8,64,0,stream>>>(att, svec, smp2+i*4096, sresc+i*8);
        mmat_kernel<<<8,256,0,stream>>>(att, sproj+i*4096, M);
        pw_kernel<<<512,256,0,stream>>>(V, M, nullptr, xs, xs, 1);
        ln_kernel<<<512,256,0,stream>>>(xs, sl2w+i*64, sl2b+i*64, A);
        ffn2d_kernel<<<512,256,0,stream>>>(A, sf1+i*2304, sf2+i*16384, xs);
    }
    // ---- polar branch ----
    for(int i=0;i<2;i++){
        ln_kernel<<<512,256,0,stream>>>(xp, pl1w+i*64, pl1b+i*64, A);
        pw_kernel<<<512,256,0,stream>>>(A, pwq+i*4096, nullptr, nullptr, Q, 0);
        pw_kernel<<<512,256,0,stream>>>(A, pwk+i*4096, nullptr, nullptr, K, 0);
        pw_kernel<<<512,256,0,stream>>>(A, pwv+i*4096, nullptr, nullptr, V, 0);
        wbar_kernel<<<1,64,0,stream>>>(pm2w+i*4096, pm2b+i*64, wbar);
        mg_kernel<<<512,256,0,stream>>>(mask, pm1w+i*576, pm1b+i*64, wbar, mg);
        att_pol_kernel<<<128,256,0,stream>>>(Q, K, V, mg, presc+i*8, stage);
        pw_kernel<<<512,256,0,stream>>>(stage, ppw+i*4096, ppb+i*64, xp, xp, 0);
        ln_kernel<<<512,256,0,stream>>>(xp, pl2w+i*64, pl2b+i*64, A);
        ffn3d_kernel<<<512,256,0,stream>>>(A, pf1+i*6912, pf2+i*16384, xp);
    }
    // ---- fusion ----
    fuse1_kernel<<<512,256,0,stream>>>(xs, xp, fw1, fb1, Tf);
    fuse2v2_kernel<<<1024,256,0,stream>>>(Tf, fw2, fb2, xs, xp, (float*)d_out);
}

// Round 6
// 2993.498 us; speedup vs baseline: 9.8721x; 1.0688x over previous
//
#include <hip/hip_runtime.h>
#include <math.h>

// Problem constants (B=8, C=64, H=W=128, HEADS=8, ch=8, L=2, P=4)
#define NPIX 16384               // 128*128
#define SBUF 8388608             // 8*64*16384 elements per full tensor

__device__ __forceinline__ float gelu_f(float x){
    return 0.5f*x*(1.0f+erff(x*0.70710678118654752440f));
}
__device__ __forceinline__ float waveReduceSum(float v){
    #pragma unroll
    for(int off=32;off>0;off>>=1) v += __shfl_down(v, off);
    return v;
}

// ---------------- LayerNorm over channel dim (64) ----------------
__global__ __launch_bounds__(256) void ln_kernel(const float* __restrict__ x,
        const float* __restrict__ w, const float* __restrict__ b, float* __restrict__ out){
    int idx = blockIdx.x*256 + threadIdx.x;      // over B*NPIX
    int bb = idx >> 14, n = idx & 16383;
    const float* ip = x + ((size_t)bb<<20) + n;
    float v[64]; float s = 0.f;
    #pragma unroll
    for(int c=0;c<64;c++){ v[c] = ip[(size_t)c<<14]; s += v[c]; }
    float mu = s*(1.f/64.f); float ss = 0.f;
    #pragma unroll
    for(int c=0;c<64;c++){ float d = v[c]-mu; ss += d*d; }
    float r = rsqrtf(ss*(1.f/64.f) + 1e-5f);
    float* op = out + ((size_t)bb<<20) + n;
    #pragma unroll
    for(int c=0;c<64;c++) op[(size_t)c<<14] = (v[c]-mu)*r*w[c] + b[c];
}

// ---------------- 1x1 conv: out[o] = sum_c w[o,c]*in[c] (+bias)(+res) ----------------
__global__ __launch_bounds__(256) void pw_kernel(const float* __restrict__ in,
        const float* __restrict__ w, const float* __restrict__ bias,
        const float* __restrict__ res, float* __restrict__ out, int wPerB){
    __shared__ float wl[4096];                   // transposed: wl[c*64+o]
    int t = threadIdx.x;
    int idx = blockIdx.x*256 + t;
    int b = idx >> 14, n = idx & 16383;
    const float* wp = w + (wPerB ? b*4096 : 0);
    for(int i=t;i<4096;i+=256) wl[(i&63)*64 + (i>>6)] = wp[i];
    __syncthreads();
    float acc[64];
    if(bias){
        #pragma unroll
        for(int o=0;o<64;o++) acc[o] = bias[o];
    } else {
        #pragma unroll
        for(int o=0;o<64;o++) acc[o] = 0.f;
    }
    const float* ip = in + ((size_t)b<<20) + n;
    for(int c=0;c<64;c++){
        float v = ip[(size_t)c<<14];
        const float4* wv = (const float4*)&wl[c*64];
        #pragma unroll
        for(int o4=0;o4<16;o4++){
            float4 w4 = wv[o4];
            acc[o4*4+0] += w4.x*v; acc[o4*4+1] += w4.y*v;
            acc[o4*4+2] += w4.z*v; acc[o4*4+3] += w4.w*v;
        }
    }
    size_t baseo = ((size_t)b<<20) + n;
    if(res){
        #pragma unroll
        for(int o=0;o<64;o++) out[baseo+((size_t)o<<14)] = acc[o] + res[baseo+((size_t)o<<14)];
    } else {
        #pragma unroll
        for(int o=0;o<64;o++) out[baseo+((size_t)o<<14)] = acc[o];
    }
}

// ---------------- depthwise 3x3, zero pad ----------------
__global__ __launch_bounds__(256) void dw3x3_kernel(const float* __restrict__ in,
        const float* __restrict__ wd, float* __restrict__ out){
    int idx = blockIdx.x*256 + threadIdx.x;      // over B*64*NPIX
    int n = idx & 16383; int bc = idx >> 14; int c = bc & 63;
    int y = n >> 7, x = n & 127;
    bool ym=y>0, yp=y<127, xm=x>0, xpv=x<127;
    const float* cp = in + ((size_t)bc<<14) + n;
    const float* wp = wd + c*9;
    float s = cp[0]*wp[4];
    if(ym){ s += cp[-128]*wp[1]; if(xm) s += cp[-129]*wp[0]; if(xpv) s += cp[-127]*wp[2]; }
    if(xm)  s += cp[-1]*wp[3];
    if(xpv) s += cp[1]*wp[5];
    if(yp){ s += cp[128]*wp[7]; if(xm) s += cp[127]*wp[6]; if(xpv) s += cp[129]*wp[8]; }
    out[idx] = s;
}

// ---------------- L2 normalize each (b,c) plane over NPIX ----------------
__global__ __launch_bounds__(256) void l2n_kernel(float* __restrict__ q){
    int bc = blockIdx.x;
    float* p = q + ((size_t)bc<<14);
    int t = threadIdx.x;
    float ss = 0.f;
    for(int n=t;n<NPIX;n+=256){ float v=p[n]; ss += v*v; }
    ss = waveReduceSum(ss);
    __shared__ float red[4];
    __shared__ float scale_s;
    if((t&63)==0) red[t>>6] = ss;
    __syncthreads();
    if(t==0) scale_s = 1.f/fmaxf(sqrtf(red[0]+red[1]+red[2]+red[3]), 1e-12f);
    __syncthreads();
    float sc = scale_s;
    for(int n=t;n<NPIX;n+=256) p[n] *= sc;
}

// ---------------- spectral attention: att[b,h,c,d] = sum_n q[c,n] k[d,n] ----------------
__global__ __launch_bounds__(256) void qk_kernel(const float* __restrict__ Q,
        const float* __restrict__ K, float* __restrict__ att){
    int blk = blockIdx.x;                        // B*HEADS*8 = 512
    int c = blk & 7, bh = blk >> 3;              // bh = b*8+head
    const float* qp = Q + (((size_t)bh*8 + c)<<14);
    const float* kp = K + (((size_t)bh*8)<<14);
    float p[8] = {0,0,0,0,0,0,0,0};
    for(int n=threadIdx.x;n<NPIX;n+=256){
        float qv = qp[n];
        #pragma unroll
        for(int d=0;d<8;d++) p[d] += qv*kp[((size_t)d<<14)+n];
    }
    #pragma unroll
    for(int off=32;off>0;off>>=1){
        #pragma unroll
        for(int d=0;d<8;d++) p[d] += __shfl_down(p[d], off);
    }
    __shared__ float red[4][8];
    int wave = threadIdx.x>>6, lane = threadIdx.x&63;
    if(lane==0){
        #pragma unroll
        for(int d=0;d<8;d++) red[wave][d] = p[d];
    }
    __syncthreads();
    if(threadIdx.x<8){
        float s = red[0][threadIdx.x]+red[1][threadIdx.x]+red[2][threadIdx.x]+red[3][threadIdx.x];
        att[blk*8+threadIdx.x] = s;
    }
}

// ---------------- zero helper ----------------
__global__ void zero512(float* __restrict__ p){
    p[blockIdx.x*256 + threadIdx.x] = 0.f;
}

// ---------------- mask bias v4: pw-kernel shape. One-time 36KB LDS fill (16 outputs),
// 2 pixels/thread, no mid-loop barriers. svec[b,m] += relu-sum over block's pixels. ----
__global__ __launch_bounds__(256) void mbconv4_kernel(const float* __restrict__ mask,
        const float* __restrict__ w, float* __restrict__ svec){
    __shared__ float wl[9216];                   // 36 KB: wl[ck*16+mo], ck in [0,576)
    __shared__ float red[4][16];
    int t = threadIdx.x;
    int og = blockIdx.x & 3;                     // output-channel group (16 each)
    int pb = (blockIdx.x >> 2) & 31;             // 512-pixel block
    int b  = blockIdx.x >> 7;
    const float* wp = w + (size_t)og*16*576;
    for(int i=t;i<9216;i+=256){
        int mo = i & 15, ck = i >> 4;
        wl[i] = wp[mo*576 + ck];
    }
    __syncthreads();
    int n0 = pb*512 + t;                         // pixel 0
    int n1 = n0 + 256;                           // pixel 1
    int y0 = n0>>7, x0 = n0&127;
    int y1 = n1>>7, x1 = n1&127;
    bool ym0=y0>0, yp0=y0<127, xm0=x0>0, xp0=x0<127;
    bool ym1=y1>0, yp1=y1<127, xm1=x1>0, xp1=x1<127;
    const float* mp = mask + ((size_t)b<<20);
    float acc0[16], acc1[16];
    #pragma unroll
    for(int o=0;o<16;o++){ acc0[o]=0.f; acc1[o]=0.f; }
    for(int c=0;c<64;c++){
        const float* cp0 = mp + ((size_t)c<<14) + n0;
        const float* cp1 = mp + ((size_t)c<<14) + n1;
        float ta[9], tb[9];
        ta[0] = (ym0&&xm0)? cp0[-129]:0.f;
        ta[1] =  ym0?       cp0[-128]:0.f;
        ta[2] = (ym0&&xp0)? cp0[-127]:0.f;
        ta[3] =  xm0?       cp0[-1]:0.f;
        ta[4] =             cp0[0];
        ta[5] =  xp0?       cp0[1]:0.f;
        ta[6] = (yp0&&xm0)? cp0[127]:0.f;
        ta[7] =  yp0?       cp0[128]:0.f;
        ta[8] = (yp0&&xp0)? cp0[129]:0.f;
        tb[0] = (ym1&&xm1)? cp1[-129]:0.f;
        tb[1] =  ym1?       cp1[-128]:0.f;
        tb[2] = (ym1&&xp1)? cp1[-127]:0.f;
        tb[3] =  xm1?       cp1[-1]:0.f;
        tb[4] =             cp1[0];
        tb[5] =  xp1?       cp1[1]:0.f;
        tb[6] = (yp1&&xm1)? cp1[127]:0.f;
        tb[7] =  yp1?       cp1[128]:0.f;
        tb[8] = (yp1&&xp1)? cp1[129]:0.f;
        #pragma unroll
        for(int k=0;k<9;k++){
            float va = ta[k], vb = tb[k];
            const float4* wv = (const float4*)&wl[(c*9+k)*16];
            #pragma unroll
            for(int o4=0;o4<4;o4++){
                float4 w4 = wv[o4];
                acc0[o4*4+0] += w4.x*va; acc0[o4*4+1] += w4.y*va;
                acc0[o4*4+2] += w4.z*va; acc0[o4*4+3] += w4.w*va;
                acc1[o4*4+0] += w4.x*vb; acc1[o4*4+1] += w4.y*vb;
                acc1[o4*4+2] += w4.z*vb; acc1[o4*4+3] += w4.w*vb;
            }
        }
    }
    // relu both pixels, reduce across block, atomic into svec
    int wave = t>>6, lane = t&63;
    #pragma unroll
    for(int m=0;m<16;m++){
        float v = waveReduceSum(fmaxf(acc0[m],0.f) + fmaxf(acc1[m],0.f));
        if(lane==0) red[wave][m] = v;
    }
    __syncthreads();
    if(t<16){
        float s = red[0][t]+red[1][t]+red[2][t]+red[3][t];
        atomicAdd(&svec[b*64 + og*16 + t], s);
    }
}

// ---------------- spectral: mb projection + scale + bias + softmax over d ----------------
__global__ void spec_softmax_kernel(float* __restrict__ att, const float* __restrict__ svec,
        const float* __restrict__ smp2, const float* __restrict__ resc){
    int b = blockIdx.x, t = threadIdx.x;         // 8 blocks, 64 threads
    __shared__ float mb[64];
    float a = 0.f;
    for(int m=0;m<64;m++) a += smp2[t*64+m]*svec[b*64+m];
    mb[t] = a*(1.f/16384.f);
    __syncthreads();
    int h = t>>3, c = t&7;
    float* ap = att + (size_t)(b*8+h)*64 + c*8;
    float rs = resc[h];
    float v[8]; float mx = -1e30f;
    #pragma unroll
    for(int d=0;d<8;d++){ v[d] = ap[d]*rs + mb[h*8+d] - mb[h*8+c]; mx = fmaxf(mx, v[d]); }
    float s = 0.f;
    #pragma unroll
    for(int d=0;d<8;d++){ v[d] = expf(v[d]-mx); s += v[d]; }
    float inv = 1.f/s;
    #pragma unroll
    for(int d=0;d<8;d++) ap[d] = v[d]*inv;
}

// ---------------- M[b] = sproj @ blockdiag(att[b]) (64x64 per batch) ----------------
__global__ void mmat_kernel(const float* __restrict__ att, const float* __restrict__ sproj,
        float* __restrict__ M){
    int b = blockIdx.x;
    for(int e=threadIdx.x;e<4096;e+=256){
        int o = e>>6, j = e&63;
        int h = j>>3, jj = j&7;
        float s = 0.f;
        #pragma unroll
        for(int cc=0;cc<8;cc++) s += sproj[o*64 + h*8+cc]*att[(size_t)(b*8+h)*64 + cc*8 + jj];
        M[b*4096 + e] = s;
    }
}

// ---------------- FFN2D fused v2 (og-split): dw3x3(x4)->GELU->proj to 32 of 64 outputs ----
__global__ __launch_bounds__(256) void ffn2d_v2_kernel(const float* __restrict__ A,
        const float* __restrict__ w1, const float* __restrict__ w2, float* __restrict__ xs){
    __shared__ float w2l[8192];                  // 32 KB: w2l[m*32+oo], m in [0,256)
    int t = threadIdx.x;
    int og = blockIdx.x & 1;                     // 2 groups x 32 outputs
    int pb = (blockIdx.x >> 1) & 63;             // 256-pixel block
    int b  = blockIdx.x >> 7;
    // conflict-free fill: consecutive lanes -> consecutive LDS addresses
    for(int i=t;i<8192;i+=256){
        int oo = i & 31, m = i >> 5;
        w2l[i] = w2[(og*32+oo)*256 + m];
    }
    __syncthreads();
    int n = pb*256 + t;
    int y = n>>7, x = n&127;
    bool ym=y>0, yp=y<127, xm=x>0, xpv=x<127;
    const float* ap = A + ((size_t)b<<20) + n;
    float acc[32];
    #pragma unroll
    for(int o=0;o<32;o++) acc[o] = 0.f;
    for(int c=0;c<64;c++){
        const float* cp = ap + ((size_t)c<<14);
        float t00 = (ym&&xm)? cp[-129]:0.f;
        float t01 =  ym?      cp[-128]:0.f;
        float t02 = (ym&&xpv)?cp[-127]:0.f;
        float t10 =  xm?      cp[-1]:0.f;
        float t11 =           cp[0];
        float t12 =  xpv?     cp[1]:0.f;
        float t20 = (yp&&xm)? cp[127]:0.f;
        float t21 =  yp?      cp[128]:0.f;
        float t22 = (yp&&xpv)?cp[129]:0.f;
        const float* w1c = w1 + c*36;
        #pragma unroll
        for(int j=0;j<4;j++){
            const float* wj = w1c + j*9;
            float cv = t00*wj[0]+t01*wj[1]+t02*wj[2]+t10*wj[3]+t11*wj[4]
                      +t12*wj[5]+t20*wj[6]+t21*wj[7]+t22*wj[8];
            float g = gelu_f(cv);
            const float4* wv = (const float4*)&w2l[(c*4+j)*32];
            #pragma unroll
            for(int o4=0;o4<8;o4++){
                float4 w4 = wv[o4];
                acc[o4*4+0] += w4.x*g; acc[o4*4+1] += w4.y*g;
                acc[o4*4+2] += w4.z*g; acc[o4*4+3] += w4.w*g;
            }
        }
    }
    size_t baseo = ((size_t)b<<20) + ((size_t)(og*32)<<14) + n;
    #pragma unroll
    for(int o=0;o<32;o++) xs[baseo+((size_t)o<<14)] += acc[o];
}

// ---------------- polar: wbar[c] = mean_o pm2w[o,c]; wbar[64] = mean(pm2b) ----------------
__global__ void wbar_kernel(const float* __restrict__ pm2w, const float* __restrict__ pm2b,
        float* __restrict__ wbar){
    int t = threadIdx.x;                         // 64
    float s = 0.f;
    for(int o=0;o<64;o++) s += pm2w[o*64+t];
    wbar[t] = s*(1.f/64.f);
    if(t==0){
        float sb = 0.f;
        for(int o=0;o<64;o++) sb += pm2b[o];
        wbar[64] = sb*(1.f/64.f);
    }
}

// ---------------- polar mask gate: mg[b,n] = sum_c wbar[c]*gelu(dw3x3(mask)[c]+pm1b[c]) + bbar ----------------
__global__ __launch_bounds__(256) void mg_kernel(const float* __restrict__ mask,
        const float* __restrict__ w1, const float* __restrict__ b1,
        const float* __restrict__ wbar, float* __restrict__ mg){
    int idx = blockIdx.x*256 + threadIdx.x;      // over B*NPIX
    int b = idx>>14, n = idx&16383;
    int y = n>>7, x = n&127;
    bool ym=y>0, yp=y<127, xm=x>0, xpv=x<127;
    const float* ap = mask + ((size_t)b<<20) + n;
    float acc = wbar[64];
    for(int c=0;c<64;c++){
        const float* cp = ap + ((size_t)c<<14);
        const float* wj = w1 + c*9;
        float cv = b1[c] + cp[0]*wj[4];
        if(ym){ cv += cp[-128]*wj[1]; if(xm) cv += cp[-129]*wj[0]; if(xpv) cv += cp[-127]*wj[2]; }
        if(xm)  cv += cp[-1]*wj[3];
        if(xpv) cv += cp[1]*wj[5];
        if(yp){ cv += cp[128]*wj[7]; if(xm) cv += cp[127]*wj[6]; if(xpv) cv += cp[129]*wj[8]; }
        acc += wbar[c]*gelu_f(cv);
    }
    mg[idx] = acc;
}

// ---------------- polar attention (P=4, ch=8 per head), writes O (pre-projection) ----------------
__global__ __launch_bounds__(256) void att_pol_kernel(const float* __restrict__ Q,
        const float* __restrict__ K, const float* __restrict__ V,
        const float* __restrict__ mg, const float* __restrict__ resc, float* __restrict__ O){
    int idx = blockIdx.x*256 + threadIdx.x;      // over BN*NPIX = 32768
    int bn = idx>>14, n = idx&16383;
    float mgv[4];
    #pragma unroll
    for(int p=0;p<4;p++) mgv[p] = mg[(((bn<<2)+p)<<14) + n];
    for(int h=0;h<8;h++){
        size_t base = ((size_t)bn<<22) + ((size_t)h<<17) + n;
        float q[4][8], k[4][8], v[4][8];
        #pragma unroll
        for(int p=0;p<4;p++){
            size_t pb = base + ((size_t)p<<20);
            #pragma unroll
            for(int j=0;j<8;j++){
                size_t o = pb + ((size_t)j<<14);
                q[p][j] = Q[o]; k[p][j] = K[o]; v[p][j] = V[o];
            }
        }
        #pragma unroll
        for(int p=0;p<4;p++){
            float sq=0.f, sk=0.f;
            #pragma unroll
            for(int j=0;j<8;j++){ sq += q[p][j]*q[p][j]; sk += k[p][j]*k[p][j]; }
            float iq = 1.f/fmaxf(sqrtf(sq),1e-12f), ik = 1.f/fmaxf(sqrtf(sk),1e-12f);
            #pragma unroll
            for(int j=0;j<8;j++){ q[p][j]*=iq; k[p][j]*=ik; }
        }
        float rs = resc[h];
        float att[4][4];
        #pragma unroll
        for(int p=0;p<4;p++){
            #pragma unroll
            for(int r=0;r<4;r++){
                float d = 0.f;
                #pragma unroll
                for(int j=0;j<8;j++) d += q[p][j]*k[r][j];
                att[p][r] = rs*d + mgv[r] - mgv[p];
            }
        }
        #pragma unroll
        for(int p=0;p<4;p++){
            float mx = fmaxf(fmaxf(att[p][0],att[p][1]),fmaxf(att[p][2],att[p][3]));
            float s = 0.f;
            #pragma unroll
            for(int r=0;r<4;r++){ att[p][r] = expf(att[p][r]-mx); s += att[p][r]; }
            float inv = 1.f/s;
            #pragma unroll
            for(int r=0;r<4;r++) att[p][r] *= inv;
        }
        #pragma unroll
        for(int p=0;p<4;p++){
            size_t pb = base + ((size_t)p<<20);
            #pragma unroll
            for(int j=0;j<8;j++){
                float o = att[p][0]*v[0][j]+att[p][1]*v[1][j]+att[p][2]*v[2][j]+att[p][3]*v[3][j];
                O[pb + ((size_t)j<<14)] = o;
            }
        }
    }
}

// ---------------- FFN3D fused v2 (og-split): 3D dw conv 3x3x3(x4)->GELU->proj to 32 outputs ----
__global__ __launch_bounds__(256) void ffn3d_v2_kernel(const float* __restrict__ A,
        const float* __restrict__ w1, const float* __restrict__ w2, float* __restrict__ xp){
    __shared__ float w2l[8192];                  // 32 KB: w2l[m*32+oo]
    int t = threadIdx.x;
    int og = blockIdx.x & 1;
    int pbk = (blockIdx.x >> 1) & 63;            // 256-pixel block
    int bp = blockIdx.x >> 7;                    // 0..7 (= bn*4+p)
    for(int i=t;i<8192;i+=256){
        int oo = i & 31, m = i >> 5;
        w2l[i] = w2[(og*32+oo)*256 + m];
    }
    __syncthreads();
    int bn = bp>>2, p = bp&3;
    int n = pbk*256 + t;
    int y = n>>7, x = n&127;
    bool ym=y>0, yp=y<127, xm=x>0, xpv=x<127;
    float acc[32];
    #pragma unroll
    for(int o=0;o<32;o++) acc[o] = 0.f;
    for(int c=0;c<64;c++){
        float tap[27];
        #pragma unroll
        for(int dz=0;dz<3;dz++){
            int pp = p + dz - 1;
            if(pp < 0 || pp > 3){
                #pragma unroll
                for(int k9=0;k9<9;k9++) tap[dz*9+k9] = 0.f;
            } else {
                const float* cp = A + ((size_t)((bn<<2)+pp)<<20) + ((size_t)c<<14) + n;
                tap[dz*9+0] = (ym&&xm)? cp[-129]:0.f;
                tap[dz*9+1] =  ym?      cp[-128]:0.f;
                tap[dz*9+2] = (ym&&xpv)?cp[-127]:0.f;
                tap[dz*9+3] =  xm?      cp[-1]:0.f;
                tap[dz*9+4] =           cp[0];
                tap[dz*9+5] =  xpv?     cp[1]:0.f;
                tap[dz*9+6] = (yp&&xm)? cp[127]:0.f;
                tap[dz*9+7] =  yp?      cp[128]:0.f;
                tap[dz*9+8] = (yp&&xpv)?cp[129]:0.f;
            }
        }
        const float* w1c = w1 + c*108;
        #pragma unroll
        for(int j=0;j<4;j++){
            const float* wj = w1c + j*27;
            float cv = 0.f;
            #pragma unroll
            for(int k27=0;k27<27;k27++) cv += tap[k27]*wj[k27];
            float g = gelu_f(cv);
            const float4* wv = (const float4*)&w2l[(c*4+j)*32];
            #pragma unroll
            for(int o4=0;o4<8;o4++){
                float4 w4 = wv[o4];
                acc[o4*4+0] += w4.x*g; acc[o4*4+1] += w4.y*g;
                acc[o4*4+2] += w4.z*g; acc[o4*4+3] += w4.w*g;
            }
        }
    }
    size_t baseo = ((size_t)bp<<20) + ((size_t)(og*32)<<14) + n;
    #pragma unroll
    for(int o=0;o<32;o++) xp[baseo+((size_t)o<<14)] += acc[o];
}

// ---------------- fusion stage 1: T = relu(fw1 @ [xs;xp] + fb1) ----------------
__global__ __launch_bounds__(256) void fuse1_kernel(const float* __restrict__ xs,
        const float* __restrict__ xp, const float* __restrict__ fw1,
        const float* __restrict__ fb1, float* __restrict__ T){
    __shared__ float wl[8192];                   // wl[c*64+o] = fw1[o*128+c], c in 0..127
    int t = threadIdx.x;
    for(int i=t;i<8192;i+=256) wl[(i&127)*64 + (i>>7)] = fw1[i];
    __syncthreads();
    int idx = blockIdx.x*256 + t;
    int b = idx>>14, n = idx&16383;
    float acc[64];
    #pragma unroll
    for(int o=0;o<64;o++) acc[o] = fb1[o];
    const float* ip = xs + ((size_t)b<<20) + n;
    for(int c=0;c<64;c++){
        float v = ip[(size_t)c<<14];
        const float4* wv = (const float4*)&wl[c*64];
        #pragma unroll
        for(int o4=0;o4<16;o4++){
            float4 w4 = wv[o4];
            acc[o4*4+0] += w4.x*v; acc[o4*4+1] += w4.y*v;
            acc[o4*4+2] += w4.z*v; acc[o4*4+3] += w4.w*v;
        }
    }
    const float* ip2 = xp + ((size_t)b<<20) + n;
    for(int c=0;c<64;c++){
        float v = ip2[(size_t)c<<14];
        const float4* wv = (const float4*)&wl[(64+c)*64];
        #pragma unroll
        for(int o4=0;o4<16;o4++){
            float4 w4 = wv[o4];
            acc[o4*4+0] += w4.x*v; acc[o4*4+1] += w4.y*v;
            acc[o4*4+2] += w4.z*v; acc[o4*4+3] += w4.w*v;
        }
    }
    size_t baseo = ((size_t)b<<20) + n;
    #pragma unroll
    for(int o=0;o<64;o++) T[baseo+((size_t)o<<14)] = fmaxf(acc[o], 0.f);
}

// ---------------- fusion stage 2 v2 (mbconv4 shape): 16 outputs per block, 2 px/thread.
// out = sig(conv3x3(T)+fb2)*xs + (1-sig)*xp ----------------
__global__ __launch_bounds__(256) void fuse2v2_kernel(const float* __restrict__ T,
        const float* __restrict__ fw2, const float* __restrict__ fb2,
        const float* __restrict__ xs, const float* __restrict__ xp, float* __restrict__ out){
    __shared__ float wl[9216];                   // 36 KB: wl[ck*16+mo], ck = c*9+k
    int t = threadIdx.x;
    int og = blockIdx.x & 3;                     // output-channel group (16 each)
    int pb = (blockIdx.x >> 2) & 31;             // 512-pixel block
    int b  = blockIdx.x >> 7;
    const float* wp = fw2 + (size_t)og*16*576;
    for(int i=t;i<9216;i+=256){
        int mo = i & 15, ck = i >> 4;
        wl[i] = wp[mo*576 + ck];
    }
    __syncthreads();
    int n0 = pb*512 + t;
    int n1 = n0 + 256;
    int y0 = n0>>7, x0 = n0&127;
    int y1 = n1>>7, x1 = n1&127;
    bool ym0=y0>0, yp0=y0<127, xm0=x0>0, xp0=x0<127;
    bool ym1=y1>0, yp1=y1<127, xm1=x1>0, xp1=x1<127;
    const float* tp = T + ((size_t)b<<20);
    float acc0[16], acc1[16];
    #pragma unroll
    for(int o=0;o<16;o++){ acc0[o]=0.f; acc1[o]=0.f; }
    for(int c=0;c<64;c++){
        const float* cp0 = tp + ((size_t)c<<14) + n0;
        const float* cp1 = tp + ((size_t)c<<14) + n1;
        float ta[9], tb[9];
        ta[0] = (ym0&&xm0)? cp0[-129]:0.f;
        ta[1] =  ym0?       cp0[-128]:0.f;
        ta[2] = (ym0&&xp0)? cp0[-127]:0.f;
        ta[3] =  xm0?       cp0[-1]:0.f;
        ta[4] =             cp0[0];
        ta[5] =  xp0?       cp0[1]:0.f;
        ta[6] = (yp0&&xm0)? cp0[127]:0.f;
        ta[7] =  yp0?       cp0[128]:0.f;
        ta[8] = (yp0&&xp0)? cp0[129]:0.f;
        tb[0] = (ym1&&xm1)? cp1[-129]:0.f;
        tb[1] =  ym1?       cp1[-128]:0.f;
        tb[2] = (ym1&&xp1)? cp1[-127]:0.f;
        tb[3] =  xm1?       cp1[-1]:0.f;
        tb[4] =             cp1[0];
        tb[5] =  xp1?       cp1[1]:0.f;
        tb[6] = (yp1&&xm1)? cp1[127]:0.f;
        tb[7] =  yp1?       cp1[128]:0.f;
        tb[8] = (yp1&&xp1)? cp1[129]:0.f;
        #pragma unroll
        for(int k=0;k<9;k++){
            float va = ta[k], vb = tb[k];
            const float4* wv = (const float4*)&wl[(c*9+k)*16];
            #pragma unroll
            for(int o4=0;o4<4;o4++){
                float4 w4 = wv[o4];
                acc0[o4*4+0] += w4.x*va; acc0[o4*4+1] += w4.y*va;
                acc0[o4*4+2] += w4.z*va; acc0[o4*4+3] += w4.w*va;
                acc1[o4*4+0] += w4.x*vb; acc1[o4*4+1] += w4.y*vb;
                acc1[o4*4+2] += w4.z*vb; acc1[o4*4+3] += w4.w*vb;
            }
        }
    }
    // epilogue: sigmoid gate + mix, write 16 outputs x 2 pixels
    #pragma unroll
    for(int m=0;m<16;m++){
        int o = og*16 + m;
        float bias = fb2[o];
        size_t i0 = ((size_t)b<<20) + ((size_t)o<<14) + n0;
        size_t i1 = ((size_t)b<<20) + ((size_t)o<<14) + n1;
        float a0 = 1.f/(1.f+expf(-(acc0[m]+bias)));
        float a1 = 1.f/(1.f+expf(-(acc1[m]+bias)));
        out[i0] = a0*xs[i0] + (1.f-a0)*xp[i0];
        out[i1] = a1*xs[i1] + (1.f-a1)*xp[i1];
    }
}

extern "C" void kernel_launch(void* const* d_in, const int* in_sizes, int n_in,
                              void* d_out, int out_size, void* d_ws, size_t ws_size,
                              hipStream_t stream) {
    // setup_inputs() dict order
    const float* x     = (const float*)d_in[0];
    const float* mask  = (const float*)d_in[1];
    const float* sl1w  = (const float*)d_in[2];
    const float* sl1b  = (const float*)d_in[3];
    const float* sl2w  = (const float*)d_in[4];
    const float* sl2b  = (const float*)d_in[5];
    const float* swq   = (const float*)d_in[6];
    const float* swk   = (const float*)d_in[7];
    const float* swv   = (const float*)d_in[8];
    const float* sproj = (const float*)d_in[9];
    const float* smp2  = (const float*)d_in[10];
    const float* sdq   = (const float*)d_in[11];
    const float* sdk   = (const float*)d_in[12];
    const float* sdv   = (const float*)d_in[13];
    const float* smp1  = (const float*)d_in[14];
    const float* sresc = (const float*)d_in[15];
    const float* sf1   = (const float*)d_in[16];
    const float* sf2   = (const float*)d_in[17];
    const float* pl1w  = (const float*)d_in[18];
    const float* pl1b  = (const float*)d_in[19];
    const float* pl2w  = (const float*)d_in[20];
    const float* pl2b  = (const float*)d_in[21];
    const float* pwq   = (const float*)d_in[22];
    const float* pwk   = (const float*)d_in[23];
    const float* pwv   = (const float*)d_in[24];
    const float* ppw   = (const float*)d_in[25];
    const float* pm2w  = (const float*)d_in[26];
    const float* ppb   = (const float*)d_in[27];
    const float* presc = (const float*)d_in[28];
    const float* pm1w  = (const float*)d_in[29];
    const float* pm1b  = (const float*)d_in[30];
    const float* pm2b  = (const float*)d_in[31];
    const float* pf1   = (const float*)d_in[32];
    const float* pf2   = (const float*)d_in[33];
    const float* fw1   = (const float*)d_in[34];
    const float* fb1   = (const float*)d_in[35];
    const float* fw2   = (const float*)d_in[36];
    const float* fb2   = (const float*)d_in[37];

    // workspace layout: 6 big buffers (202MB) + small scratch; d_out doubles as staging
    float* ws_f = (float*)d_ws;
    float* xs = ws_f;
    float* xp = ws_f + (size_t)SBUF;
    float* A  = ws_f + 2*(size_t)SBUF;
    float* Q  = ws_f + 3*(size_t)SBUF;
    float* K  = ws_f + 4*(size_t)SBUF;
    float* V  = ws_f + 5*(size_t)SBUF;
    float* small = ws_f + 6*(size_t)SBUF;
    float* mg   = small;                // 131072
    float* att  = mg + 131072;          // 4096
    float* svec = att + 4096;           // 512
    float* M    = svec + 512;           // 32768
    float* wbar = M + 32768;            // 65
    float* stage = (float*)d_out;       // scratch until fusion (written before read)
    float* Tf = Q;                      // fusion temp (Q is dead by then)

    hipMemcpyAsync(xs, x, (size_t)SBUF*4, hipMemcpyDeviceToDevice, stream);
    hipMemcpyAsync(xp, x, (size_t)SBUF*4, hipMemcpyDeviceToDevice, stream);

    // ---- spectral branch ----
    for(int i=0;i<2;i++){
        ln_kernel<<<512,256,0,stream>>>(xs, sl1w+i*64, sl1b+i*64, A);
        pw_kernel<<<512,256,0,stream>>>(A, swq+i*4096, nullptr, nullptr, stage, 0);
        dw3x3_kernel<<<32768,256,0,stream>>>(stage, sdq+i*576, Q);
        pw_kernel<<<512,256,0,stream>>>(A, swk+i*4096, nullptr, nullptr, stage, 0);
        dw3x3_kernel<<<32768,256,0,stream>>>(stage, sdk+i*576, K);
        pw_kernel<<<512,256,0,stream>>>(A, swv+i*4096, nullptr, nullptr, stage, 0);
        dw3x3_kernel<<<32768,256,0,stream>>>(stage, sdv+i*576, V);
        l2n_kernel<<<512,256,0,stream>>>(Q);
        l2n_kernel<<<512,256,0,stream>>>(K);
        qk_kernel<<<512,256,0,stream>>>(Q, K, att);
        zero512<<<2,256,0,stream>>>(svec);
        mbconv4_kernel<<<1024,256,0,stream>>>(mask, smp1+i*36864, svec);
        spec_softmax_kernel<<<8,64,0,stream>>>(att, svec, smp2+i*4096, sresc+i*8);
        mmat_kernel<<<8,256,0,stream>>>(att, sproj+i*4096, M);
        pw_kernel<<<512,256,0,stream>>>(V, M, nullptr, xs, xs, 1);
        ln_kernel<<<512,256,0,stream>>>(xs, sl2w+i*64, sl2b+i*64, A);
        ffn2d_v2_kernel<<<1024,256,0,stream>>>(A, sf1+i*2304, sf2+i*16384, xs);
    }
    // ---- polar branch ----
    for(int i=0;i<2;i++){
        ln_kernel<<<512,256,0,stream>>>(xp, pl1w+i*64, pl1b+i*64, A);
        pw_kernel<<<512,256,0,stream>>>(A, pwq+i*4096, nullptr, nullptr, Q, 0);
        pw_kernel<<<512,256,0,stream>>>(A, pwk+i*4096, nullptr, nullptr, K, 0);
        pw_kernel<<<512,256,0,stream>>>(A, pwv+i*4096, nullptr, nullptr, V, 0);
        wbar_kernel<<<1,64,0,stream>>>(pm2w+i*4096, pm2b+i*64, wbar);
        mg_kernel<<<512,256,0,stream>>>(mask, pm1w+i*576, pm1b+i*64, wbar, mg);
        att_pol_kernel<<<128,256,0,stream>>>(Q, K, V, mg, presc+i*8, stage);
        pw_kernel<<<512,256,0,stream>>>(stage, ppw+i*4096, ppb+i*64, xp, xp, 0);
        ln_kernel<<<512,256,0,stream>>>(xp, pl2w+i*64, pl2b+i*64, A);
        ffn3d_v2_kernel<<<1024,256,0,stream>>>(A, pf1+i*6912, pf2+i*16384, xp);
    }
    // ---- fusion ----
    fuse1_kernel<<<512,256,0,stream>>>(xs, xp, fw1, fb1, Tf);
    fuse2v2_kernel<<<1024,256,0,stream>>>(Tf, fw2, fb2, xs, xp, (float*)d_out);
}

// Round 7
// 2933.252 us; speedup vs baseline: 10.0749x; 1.0205x over previous
//
#include <hip/hip_runtime.h>
#include <math.h>

// Problem constants (B=8, C=64, H=W=128, HEADS=8, ch=8, L=2, P=4)
#define NPIX 16384               // 128*128
#define SBUF 8388608             // 8*64*16384 elements per full tensor

__device__ __forceinline__ float gelu_f(float x){
    return 0.5f*x*(1.0f+erff(x*0.70710678118654752440f));
}
__device__ __forceinline__ float waveReduceSum(float v){
    #pragma unroll
    for(int off=32;off>0;off>>=1) v += __shfl_down(v, off);
    return v;
}

// ---------------- LayerNorm over channel dim (64) ----------------
__global__ __launch_bounds__(256) void ln_kernel(const float* __restrict__ x,
        const float* __restrict__ w, const float* __restrict__ b, float* __restrict__ out){
    int idx = blockIdx.x*256 + threadIdx.x;      // over B*NPIX
    int bb = idx >> 14, n = idx & 16383;
    const float* ip = x + ((size_t)bb<<20) + n;
    float v[64]; float s = 0.f;
    #pragma unroll
    for(int c=0;c<64;c++){ v[c] = ip[(size_t)c<<14]; s += v[c]; }
    float mu = s*(1.f/64.f); float ss = 0.f;
    #pragma unroll
    for(int c=0;c<64;c++){ float d = v[c]-mu; ss += d*d; }
    float r = rsqrtf(ss*(1.f/64.f) + 1e-5f);
    float* op = out + ((size_t)bb<<20) + n;
    #pragma unroll
    for(int c=0;c<64;c++) op[(size_t)c<<14] = (v[c]-mu)*r*w[c] + b[c];
}

// ---------------- 1x1 conv: out[o] = sum_c w[o,c]*in[c] (+bias)(+res) ----------------
__global__ __launch_bounds__(256) void pw_kernel(const float* __restrict__ in,
        const float* __restrict__ w, const float* __restrict__ bias,
        const float* __restrict__ res, float* __restrict__ out, int wPerB){
    __shared__ float wl[4096];                   // transposed: wl[c*64+o]
    int t = threadIdx.x;
    int idx = blockIdx.x*256 + t;
    int b = idx >> 14, n = idx & 16383;
    const float* wp = w + (wPerB ? b*4096 : 0);
    for(int i=t;i<4096;i+=256) wl[(i&63)*64 + (i>>6)] = wp[i];
    __syncthreads();
    float acc[64];
    if(bias){
        #pragma unroll
        for(int o=0;o<64;o++) acc[o] = bias[o];
    } else {
        #pragma unroll
        for(int o=0;o<64;o++) acc[o] = 0.f;
    }
    const float* ip = in + ((size_t)b<<20) + n;
    for(int c=0;c<64;c++){
        float v = ip[(size_t)c<<14];
        const float4* wv = (const float4*)&wl[c*64];
        #pragma unroll
        for(int o4=0;o4<16;o4++){
            float4 w4 = wv[o4];
            acc[o4*4+0] += w4.x*v; acc[o4*4+1] += w4.y*v;
            acc[o4*4+2] += w4.z*v; acc[o4*4+3] += w4.w*v;
        }
    }
    size_t baseo = ((size_t)b<<20) + n;
    if(res){
        #pragma unroll
        for(int o=0;o<64;o++) out[baseo+((size_t)o<<14)] = acc[o] + res[baseo+((size_t)o<<14)];
    } else {
        #pragma unroll
        for(int o=0;o<64;o++) out[baseo+((size_t)o<<14)] = acc[o];
    }
}

// ---------------- depthwise 3x3, zero pad ----------------
__global__ __launch_bounds__(256) void dw3x3_kernel(const float* __restrict__ in,
        const float* __restrict__ wd, float* __restrict__ out){
    int idx = blockIdx.x*256 + threadIdx.x;      // over B*64*NPIX
    int n = idx & 16383; int bc = idx >> 14; int c = bc & 63;
    int y = n >> 7, x = n & 127;
    bool ym=y>0, yp=y<127, xm=x>0, xpv=x<127;
    const float* cp = in + ((size_t)bc<<14) + n;
    const float* wp = wd + c*9;
    float s = cp[0]*wp[4];
    if(ym){ s += cp[-128]*wp[1]; if(xm) s += cp[-129]*wp[0]; if(xpv) s += cp[-127]*wp[2]; }
    if(xm)  s += cp[-1]*wp[3];
    if(xpv) s += cp[1]*wp[5];
    if(yp){ s += cp[128]*wp[7]; if(xm) s += cp[127]*wp[6]; if(xpv) s += cp[129]*wp[8]; }
    out[idx] = s;
}

// ---------------- L2 normalize each (b,c) plane over NPIX ----------------
__global__ __launch_bounds__(256) void l2n_kernel(float* __restrict__ q){
    int bc = blockIdx.x;
    float* p = q + ((size_t)bc<<14);
    int t = threadIdx.x;
    float ss = 0.f;
    for(int n=t;n<NPIX;n+=256){ float v=p[n]; ss += v*v; }
    ss = waveReduceSum(ss);
    __shared__ float red[4];
    __shared__ float scale_s;
    if((t&63)==0) red[t>>6] = ss;
    __syncthreads();
    if(t==0) scale_s = 1.f/fmaxf(sqrtf(red[0]+red[1]+red[2]+red[3]), 1e-12f);
    __syncthreads();
    float sc = scale_s;
    for(int n=t;n<NPIX;n+=256) p[n] *= sc;
}

// ---------------- spectral attention: att[b,h,c,d] = sum_n q[c,n] k[d,n] ----------------
__global__ __launch_bounds__(256) void qk_kernel(const float* __restrict__ Q,
        const float* __restrict__ K, float* __restrict__ att){
    int blk = blockIdx.x;                        // B*HEADS*8 = 512
    int c = blk & 7, bh = blk >> 3;              // bh = b*8+head
    const float* qp = Q + (((size_t)bh*8 + c)<<14);
    const float* kp = K + (((size_t)bh*8)<<14);
    float p[8] = {0,0,0,0,0,0,0,0};
    for(int n=threadIdx.x;n<NPIX;n+=256){
        float qv = qp[n];
        #pragma unroll
        for(int d=0;d<8;d++) p[d] += qv*kp[((size_t)d<<14)+n];
    }
    #pragma unroll
    for(int off=32;off>0;off>>=1){
        #pragma unroll
        for(int d=0;d<8;d++) p[d] += __shfl_down(p[d], off);
    }
    __shared__ float red[4][8];
    int wave = threadIdx.x>>6, lane = threadIdx.x&63;
    if(lane==0){
        #pragma unroll
        for(int d=0;d<8;d++) red[wave][d] = p[d];
    }
    __syncthreads();
    if(threadIdx.x<8){
        float s = red[0][threadIdx.x]+red[1][threadIdx.x]+red[2][threadIdx.x]+red[3][threadIdx.x];
        att[blk*8+threadIdx.x] = s;
    }
}

// ---------------- zero helper ----------------
__global__ void zero512(float* __restrict__ p){
    p[blockIdx.x*256 + threadIdx.x] = 0.f;
}

// ---------------- mask bias v4: pw-kernel shape. One-time 36KB LDS fill (16 outputs),
// 2 pixels/thread, no mid-loop barriers. svec[b,m] += relu-sum over block's pixels. ----
__global__ __launch_bounds__(256) void mbconv4_kernel(const float* __restrict__ mask,
        const float* __restrict__ w, float* __restrict__ svec){
    __shared__ float wl[9216];                   // 36 KB: wl[ck*16+mo], ck in [0,576)
    __shared__ float red[4][16];
    int t = threadIdx.x;
    int og = blockIdx.x & 3;                     // output-channel group (16 each)
    int pb = (blockIdx.x >> 2) & 31;             // 512-pixel block
    int b  = blockIdx.x >> 7;
    const float* wp = w + (size_t)og*16*576;
    for(int i=t;i<9216;i+=256){
        int mo = i & 15, ck = i >> 4;
        wl[i] = wp[mo*576 + ck];
    }
    __syncthreads();
    int n0 = pb*512 + t;                         // pixel 0
    int n1 = n0 + 256;                           // pixel 1
    int y0 = n0>>7, x0 = n0&127;
    int y1 = n1>>7, x1 = n1&127;
    bool ym0=y0>0, yp0=y0<127, xm0=x0>0, xp0=x0<127;
    bool ym1=y1>0, yp1=y1<127, xm1=x1>0, xp1=x1<127;
    const float* mp = mask + ((size_t)b<<20);
    float acc0[16], acc1[16];
    #pragma unroll
    for(int o=0;o<16;o++){ acc0[o]=0.f; acc1[o]=0.f; }
    for(int c=0;c<64;c++){
        const float* cp0 = mp + ((size_t)c<<14) + n0;
        const float* cp1 = mp + ((size_t)c<<14) + n1;
        float ta[9], tb[9];
        ta[0] = (ym0&&xm0)? cp0[-129]:0.f;
        ta[1] =  ym0?       cp0[-128]:0.f;
        ta[2] = (ym0&&xp0)? cp0[-127]:0.f;
        ta[3] =  xm0?       cp0[-1]:0.f;
        ta[4] =             cp0[0];
        ta[5] =  xp0?       cp0[1]:0.f;
        ta[6] = (yp0&&xm0)? cp0[127]:0.f;
        ta[7] =  yp0?       cp0[128]:0.f;
        ta[8] = (yp0&&xp0)? cp0[129]:0.f;
        tb[0] = (ym1&&xm1)? cp1[-129]:0.f;
        tb[1] =  ym1?       cp1[-128]:0.f;
        tb[2] = (ym1&&xp1)? cp1[-127]:0.f;
        tb[3] =  xm1?       cp1[-1]:0.f;
        tb[4] =             cp1[0];
        tb[5] =  xp1?       cp1[1]:0.f;
        tb[6] = (yp1&&xm1)? cp1[127]:0.f;
        tb[7] =  yp1?       cp1[128]:0.f;
        tb[8] = (yp1&&xp1)? cp1[129]:0.f;
        #pragma unroll
        for(int k=0;k<9;k++){
            float va = ta[k], vb = tb[k];
            const float4* wv = (const float4*)&wl[(c*9+k)*16];
            #pragma unroll
            for(int o4=0;o4<4;o4++){
                float4 w4 = wv[o4];
                acc0[o4*4+0] += w4.x*va; acc0[o4*4+1] += w4.y*va;
                acc0[o4*4+2] += w4.z*va; acc0[o4*4+3] += w4.w*va;
                acc1[o4*4+0] += w4.x*vb; acc1[o4*4+1] += w4.y*vb;
                acc1[o4*4+2] += w4.z*vb; acc1[o4*4+3] += w4.w*vb;
            }
        }
    }
    // relu both pixels, reduce across block, atomic into svec
    int wave = t>>6, lane = t&63;
    #pragma unroll
    for(int m=0;m<16;m++){
        float v = waveReduceSum(fmaxf(acc0[m],0.f) + fmaxf(acc1[m],0.f));
        if(lane==0) red[wave][m] = v;
    }
    __syncthreads();
    if(t<16){
        float s = red[0][t]+red[1][t]+red[2][t]+red[3][t];
        atomicAdd(&svec[b*64 + og*16 + t], s);
    }
}

// ---------------- spectral: mb projection + scale + bias + softmax over d ----------------
__global__ void spec_softmax_kernel(float* __restrict__ att, const float* __restrict__ svec,
        const float* __restrict__ smp2, const float* __restrict__ resc){
    int b = blockIdx.x, t = threadIdx.x;         // 8 blocks, 64 threads
    __shared__ float mb[64];
    float a = 0.f;
    for(int m=0;m<64;m++) a += smp2[t*64+m]*svec[b*64+m];
    mb[t] = a*(1.f/16384.f);
    __syncthreads();
    int h = t>>3, c = t&7;
    float* ap = att + (size_t)(b*8+h)*64 + c*8;
    float rs = resc[h];
    float v[8]; float mx = -1e30f;
    #pragma unroll
    for(int d=0;d<8;d++){ v[d] = ap[d]*rs + mb[h*8+d] - mb[h*8+c]; mx = fmaxf(mx, v[d]); }
    float s = 0.f;
    #pragma unroll
    for(int d=0;d<8;d++){ v[d] = expf(v[d]-mx); s += v[d]; }
    float inv = 1.f/s;
    #pragma unroll
    for(int d=0;d<8;d++) ap[d] = v[d]*inv;
}

// ---------------- M[b] = sproj @ blockdiag(att[b]) (64x64 per batch) ----------------
__global__ void mmat_kernel(const float* __restrict__ att, const float* __restrict__ sproj,
        float* __restrict__ M){
    int b = blockIdx.x;
    for(int e=threadIdx.x;e<4096;e+=256){
        int o = e>>6, j = e&63;
        int h = j>>3, jj = j&7;
        float s = 0.f;
        #pragma unroll
        for(int cc=0;cc<8;cc++) s += sproj[o*64 + h*8+cc]*att[(size_t)(b*8+h)*64 + cc*8 + jj];
        M[b*4096 + e] = s;
    }
}

// ---------------- FFN2D fused v3 (og=4): dw3x3(x4)->GELU->proj to 16 of 64 outputs ----
__global__ __launch_bounds__(256) void ffn2d_v3_kernel(const float* __restrict__ A,
        const float* __restrict__ w1, const float* __restrict__ w2, float* __restrict__ xs){
    __shared__ float w2l[4096];                  // 16 KB: w2l[m*16+oo], m in [0,256)
    int t = threadIdx.x;
    int og = blockIdx.x & 3;                     // 4 groups x 16 outputs
    int pb = (blockIdx.x >> 2) & 63;             // 256-pixel block
    int b  = blockIdx.x >> 8;
    for(int i=t;i<4096;i+=256){
        int oo = i & 15, m = i >> 4;
        w2l[i] = w2[(og*16+oo)*256 + m];
    }
    __syncthreads();
    int n = pb*256 + t;
    int y = n>>7, x = n&127;
    bool ym=y>0, yp=y<127, xm=x>0, xpv=x<127;
    const float* ap = A + ((size_t)b<<20) + n;
    float acc[16];
    #pragma unroll
    for(int o=0;o<16;o++) acc[o] = 0.f;
    for(int c=0;c<64;c++){
        const float* cp = ap + ((size_t)c<<14);
        float t00 = (ym&&xm)? cp[-129]:0.f;
        float t01 =  ym?      cp[-128]:0.f;
        float t02 = (ym&&xpv)?cp[-127]:0.f;
        float t10 =  xm?      cp[-1]:0.f;
        float t11 =           cp[0];
        float t12 =  xpv?     cp[1]:0.f;
        float t20 = (yp&&xm)? cp[127]:0.f;
        float t21 =  yp?      cp[128]:0.f;
        float t22 = (yp&&xpv)?cp[129]:0.f;
        const float* w1c = w1 + c*36;
        #pragma unroll
        for(int j=0;j<4;j++){
            const float* wj = w1c + j*9;
            float cv = t00*wj[0]+t01*wj[1]+t02*wj[2]+t10*wj[3]+t11*wj[4]
                      +t12*wj[5]+t20*wj[6]+t21*wj[7]+t22*wj[8];
            float g = gelu_f(cv);
            const float4* wv = (const float4*)&w2l[(c*4+j)*16];
            #pragma unroll
            for(int o4=0;o4<4;o4++){
                float4 w4 = wv[o4];
                acc[o4*4+0] += w4.x*g; acc[o4*4+1] += w4.y*g;
                acc[o4*4+2] += w4.z*g; acc[o4*4+3] += w4.w*g;
            }
        }
    }
    size_t baseo = ((size_t)b<<20) + ((size_t)(og*16)<<14) + n;
    #pragma unroll
    for(int o=0;o<16;o++) xs[baseo+((size_t)o<<14)] += acc[o];
}

// ---------------- polar: wbar[c] = mean_o pm2w[o,c]; wbar[64] = mean(pm2b) ----------------
__global__ void wbar_kernel(const float* __restrict__ pm2w, const float* __restrict__ pm2b,
        float* __restrict__ wbar){
    int t = threadIdx.x;                         // 64
    float s = 0.f;
    for(int o=0;o<64;o++) s += pm2w[o*64+t];
    wbar[t] = s*(1.f/64.f);
    if(t==0){
        float sb = 0.f;
        for(int o=0;o<64;o++) sb += pm2b[o];
        wbar[64] = sb*(1.f/64.f);
    }
}

// ---------------- polar mask gate: mg[b,n] = sum_c wbar[c]*gelu(dw3x3(mask)[c]+pm1b[c]) + bbar ----------------
__global__ __launch_bounds__(256) void mg_kernel(const float* __restrict__ mask,
        const float* __restrict__ w1, const float* __restrict__ b1,
        const float* __restrict__ wbar, float* __restrict__ mg){
    int idx = blockIdx.x*256 + threadIdx.x;      // over B*NPIX
    int b = idx>>14, n = idx&16383;
    int y = n>>7, x = n&127;
    bool ym=y>0, yp=y<127, xm=x>0, xpv=x<127;
    const float* ap = mask + ((size_t)b<<20) + n;
    float acc = wbar[64];
    for(int c=0;c<64;c++){
        const float* cp = ap + ((size_t)c<<14);
        const float* wj = w1 + c*9;
        float cv = b1[c] + cp[0]*wj[4];
        if(ym){ cv += cp[-128]*wj[1]; if(xm) cv += cp[-129]*wj[0]; if(xpv) cv += cp[-127]*wj[2]; }
        if(xm)  cv += cp[-1]*wj[3];
        if(xpv) cv += cp[1]*wj[5];
        if(yp){ cv += cp[128]*wj[7]; if(xm) cv += cp[127]*wj[6]; if(xpv) cv += cp[129]*wj[8]; }
        acc += wbar[c]*gelu_f(cv);
    }
    mg[idx] = acc;
}

// ---------------- polar attention (P=4, ch=8 per head), writes O (pre-projection) ----------------
__global__ __launch_bounds__(256) void att_pol_kernel(const float* __restrict__ Q,
        const float* __restrict__ K, const float* __restrict__ V,
        const float* __restrict__ mg, const float* __restrict__ resc, float* __restrict__ O){
    int idx = blockIdx.x*256 + threadIdx.x;      // over BN*NPIX = 32768
    int bn = idx>>14, n = idx&16383;
    float mgv[4];
    #pragma unroll
    for(int p=0;p<4;p++) mgv[p] = mg[(((bn<<2)+p)<<14) + n];
    for(int h=0;h<8;h++){
        size_t base = ((size_t)bn<<22) + ((size_t)h<<17) + n;
        float q[4][8], k[4][8], v[4][8];
        #pragma unroll
        for(int p=0;p<4;p++){
            size_t pb = base + ((size_t)p<<20);
            #pragma unroll
            for(int j=0;j<8;j++){
                size_t o = pb + ((size_t)j<<14);
                q[p][j] = Q[o]; k[p][j] = K[o]; v[p][j] = V[o];
            }
        }
        #pragma unroll
        for(int p=0;p<4;p++){
            float sq=0.f, sk=0.f;
            #pragma unroll
            for(int j=0;j<8;j++){ sq += q[p][j]*q[p][j]; sk += k[p][j]*k[p][j]; }
            float iq = 1.f/fmaxf(sqrtf(sq),1e-12f), ik = 1.f/fmaxf(sqrtf(sk),1e-12f);
            #pragma unroll
            for(int j=0;j<8;j++){ q[p][j]*=iq; k[p][j]*=ik; }
        }
        float rs = resc[h];
        float att[4][4];
        #pragma unroll
        for(int p=0;p<4;p++){
            #pragma unroll
            for(int r=0;r<4;r++){
                float d = 0.f;
                #pragma unroll
                for(int j=0;j<8;j++) d += q[p][j]*k[r][j];
                att[p][r] = rs*d + mgv[r] - mgv[p];
            }
        }
        #pragma unroll
        for(int p=0;p<4;p++){
            float mx = fmaxf(fmaxf(att[p][0],att[p][1]),fmaxf(att[p][2],att[p][3]));
            float s = 0.f;
            #pragma unroll
            for(int r=0;r<4;r++){ att[p][r] = expf(att[p][r]-mx); s += att[p][r]; }
            float inv = 1.f/s;
            #pragma unroll
            for(int r=0;r<4;r++) att[p][r] *= inv;
        }
        #pragma unroll
        for(int p=0;p<4;p++){
            size_t pb = base + ((size_t)p<<20);
            #pragma unroll
            for(int j=0;j<8;j++){
                float o = att[p][0]*v[0][j]+att[p][1]*v[1][j]+att[p][2]*v[2][j]+att[p][3]*v[3][j];
                O[pb + ((size_t)j<<14)] = o;
            }
        }
    }
}

// ---------------- FFN3D fused v3 (og=4): 3D dw conv 3x3x3(x4)->GELU->proj to 16 outputs ----
__global__ __launch_bounds__(256) void ffn3d_v3_kernel(const float* __restrict__ A,
        const float* __restrict__ w1, const float* __restrict__ w2, float* __restrict__ xp){
    __shared__ float w2l[4096];                  // 16 KB: w2l[m*16+oo]
    int t = threadIdx.x;
    int og = blockIdx.x & 3;
    int pbk = (blockIdx.x >> 2) & 63;            // 256-pixel block
    int bp = blockIdx.x >> 8;                    // 0..7 (= bn*4+p)
    for(int i=t;i<4096;i+=256){
        int oo = i & 15, m = i >> 4;
        w2l[i] = w2[(og*16+oo)*256 + m];
    }
    __syncthreads();
    int bn = bp>>2, p = bp&3;
    int n = pbk*256 + t;
    int y = n>>7, x = n&127;
    bool ym=y>0, yp=y<127, xm=x>0, xpv=x<127;
    float acc[16];
    #pragma unroll
    for(int o=0;o<16;o++) acc[o] = 0.f;
    for(int c=0;c<64;c++){
        float tap[27];
        #pragma unroll
        for(int dz=0;dz<3;dz++){
            int pp = p + dz - 1;
            if(pp < 0 || pp > 3){
                #pragma unroll
                for(int k9=0;k9<9;k9++) tap[dz*9+k9] = 0.f;
            } else {
                const float* cp = A + ((size_t)((bn<<2)+pp)<<20) + ((size_t)c<<14) + n;
                tap[dz*9+0] = (ym&&xm)? cp[-129]:0.f;
                tap[dz*9+1] =  ym?      cp[-128]:0.f;
                tap[dz*9+2] = (ym&&xpv)?cp[-127]:0.f;
                tap[dz*9+3] =  xm?      cp[-1]:0.f;
                tap[dz*9+4] =           cp[0];
                tap[dz*9+5] =  xpv?     cp[1]:0.f;
                tap[dz*9+6] = (yp&&xm)? cp[127]:0.f;
                tap[dz*9+7] =  yp?      cp[128]:0.f;
                tap[dz*9+8] = (yp&&xpv)?cp[129]:0.f;
            }
        }
        const float* w1c = w1 + c*108;
        #pragma unroll
        for(int j=0;j<4;j++){
            const float* wj = w1c + j*27;
            float cv = 0.f;
            #pragma unroll
            for(int k27=0;k27<27;k27++) cv += tap[k27]*wj[k27];
            float g = gelu_f(cv);
            const float4* wv = (const float4*)&w2l[(c*4+j)*16];
            #pragma unroll
            for(int o4=0;o4<4;o4++){
                float4 w4 = wv[o4];
                acc[o4*4+0] += w4.x*g; acc[o4*4+1] += w4.y*g;
                acc[o4*4+2] += w4.z*g; acc[o4*4+3] += w4.w*g;
            }
        }
    }
    size_t baseo = ((size_t)bp<<20) + ((size_t)(og*16)<<14) + n;
    #pragma unroll
    for(int o=0;o<16;o++) xp[baseo+((size_t)o<<14)] += acc[o];
}

// ---------------- fusion stage 1: T = relu(fw1 @ [xs;xp] + fb1) ----------------
__global__ __launch_bounds__(256) void fuse1_kernel(const float* __restrict__ xs,
        const float* __restrict__ xp, const float* __restrict__ fw1,
        const float* __restrict__ fb1, float* __restrict__ T){
    __shared__ float wl[8192];                   // wl[c*64+o] = fw1[o*128+c], c in 0..127
    int t = threadIdx.x;
    for(int i=t;i<8192;i+=256) wl[(i&127)*64 + (i>>7)] = fw1[i];
    __syncthreads();
    int idx = blockIdx.x*256 + t;
    int b = idx>>14, n = idx&16383;
    float acc[64];
    #pragma unroll
    for(int o=0;o<64;o++) acc[o] = fb1[o];
    const float* ip = xs + ((size_t)b<<20) + n;
    for(int c=0;c<64;c++){
        float v = ip[(size_t)c<<14];
        const float4* wv = (const float4*)&wl[c*64];
        #pragma unroll
        for(int o4=0;o4<16;o4++){
            float4 w4 = wv[o4];
            acc[o4*4+0] += w4.x*v; acc[o4*4+1] += w4.y*v;
            acc[o4*4+2] += w4.z*v; acc[o4*4+3] += w4.w*v;
        }
    }
    const float* ip2 = xp + ((size_t)b<<20) + n;
    for(int c=0;c<64;c++){
        float v = ip2[(size_t)c<<14];
        const float4* wv = (const float4*)&wl[(64+c)*64];
        #pragma unroll
        for(int o4=0;o4<16;o4++){
            float4 w4 = wv[o4];
            acc[o4*4+0] += w4.x*v; acc[o4*4+1] += w4.y*v;
            acc[o4*4+2] += w4.z*v; acc[o4*4+3] += w4.w*v;
        }
    }
    size_t baseo = ((size_t)b<<20) + n;
    #pragma unroll
    for(int o=0;o<64;o++) T[baseo+((size_t)o<<14)] = fmaxf(acc[o], 0.f);
}

// ---------------- fusion stage 2 v2 (mbconv4 shape): 16 outputs per block, 2 px/thread.
// out = sig(conv3x3(T)+fb2)*xs + (1-sig)*xp ----------------
__global__ __launch_bounds__(256) void fuse2v2_kernel(const float* __restrict__ T,
        const float* __restrict__ fw2, const float* __restrict__ fb2,
        const float* __restrict__ xs, const float* __restrict__ xp, float* __restrict__ out){
    __shared__ float wl[9216];                   // 36 KB: wl[ck*16+mo], ck = c*9+k
    int t = threadIdx.x;
    int og = blockIdx.x & 3;                     // output-channel group (16 each)
    int pb = (blockIdx.x >> 2) & 31;             // 512-pixel block
    int b  = blockIdx.x >> 7;
    const float* wp = fw2 + (size_t)og*16*576;
    for(int i=t;i<9216;i+=256){
        int mo = i & 15, ck = i >> 4;
        wl[i] = wp[mo*576 + ck];
    }
    __syncthreads();
    int n0 = pb*512 + t;
    int n1 = n0 + 256;
    int y0 = n0>>7, x0 = n0&127;
    int y1 = n1>>7, x1 = n1&127;
    bool ym0=y0>0, yp0=y0<127, xm0=x0>0, xp0=x0<127;
    bool ym1=y1>0, yp1=y1<127, xm1=x1>0, xp1=x1<127;
    const float* tp = T + ((size_t)b<<20);
    float acc0[16], acc1[16];
    #pragma unroll
    for(int o=0;o<16;o++){ acc0[o]=0.f; acc1[o]=0.f; }
    for(int c=0;c<64;c++){
        const float* cp0 = tp + ((size_t)c<<14) + n0;
        const float* cp1 = tp + ((size_t)c<<14) + n1;
        float ta[9], tb[9];
        ta[0] = (ym0&&xm0)? cp0[-129]:0.f;
        ta[1] =  ym0?       cp0[-128]:0.f;
        ta[2] = (ym0&&xp0)? cp0[-127]:0.f;
        ta[3] =  xm0?       cp0[-1]:0.f;
        ta[4] =             cp0[0];
        ta[5] =  xp0?       cp0[1]:0.f;
        ta[6] = (yp0&&xm0)? cp0[127]:0.f;
        ta[7] =  yp0?       cp0[128]:0.f;
        ta[8] = (yp0&&xp0)? cp0[129]:0.f;
        tb[0] = (ym1&&xm1)? cp1[-129]:0.f;
        tb[1] =  ym1?       cp1[-128]:0.f;
        tb[2] = (ym1&&xp1)? cp1[-127]:0.f;
        tb[3] =  xm1?       cp1[-1]:0.f;
        tb[4] =             cp1[0];
        tb[5] =  xp1?       cp1[1]:0.f;
        tb[6] = (yp1&&xm1)? cp1[127]:0.f;
        tb[7] =  yp1?       cp1[128]:0.f;
        tb[8] = (yp1&&xp1)? cp1[129]:0.f;
        #pragma unroll
        for(int k=0;k<9;k++){
            float va = ta[k], vb = tb[k];
            const float4* wv = (const float4*)&wl[(c*9+k)*16];
            #pragma unroll
            for(int o4=0;o4<4;o4++){
                float4 w4 = wv[o4];
                acc0[o4*4+0] += w4.x*va; acc0[o4*4+1] += w4.y*va;
                acc0[o4*4+2] += w4.z*va; acc0[o4*4+3] += w4.w*va;
                acc1[o4*4+0] += w4.x*vb; acc1[o4*4+1] += w4.y*vb;
                acc1[o4*4+2] += w4.z*vb; acc1[o4*4+3] += w4.w*vb;
            }
        }
    }
    // epilogue: sigmoid gate + mix, write 16 outputs x 2 pixels
    #pragma unroll
    for(int m=0;m<16;m++){
        int o = og*16 + m;
        float bias = fb2[o];
        size_t i0 = ((size_t)b<<20) + ((size_t)o<<14) + n0;
        size_t i1 = ((size_t)b<<20) + ((size_t)o<<14) + n1;
        float a0 = 1.f/(1.f+expf(-(acc0[m]+bias)));
        float a1 = 1.f/(1.f+expf(-(acc1[m]+bias)));
        out[i0] = a0*xs[i0] + (1.f-a0)*xp[i0];
        out[i1] = a1*xs[i1] + (1.f-a1)*xp[i1];
    }
}

extern "C" void kernel_launch(void* const* d_in, const int* in_sizes, int n_in,
                              void* d_out, int out_size, void* d_ws, size_t ws_size,
                              hipStream_t stream) {
    // setup_inputs() dict order
    const float* x     = (const float*)d_in[0];
    const float* mask  = (const float*)d_in[1];
    const float* sl1w  = (const float*)d_in[2];
    const float* sl1b  = (const float*)d_in[3];
    const float* sl2w  = (const float*)d_in[4];
    const float* sl2b  = (const float*)d_in[5];
    const float* swq   = (const float*)d_in[6];
    const float* swk   = (const float*)d_in[7];
    const float* swv   = (const float*)d_in[8];
    const float* sproj = (const float*)d_in[9];
    const float* smp2  = (const float*)d_in[10];
    const float* sdq   = (const float*)d_in[11];
    const float* sdk   = (const float*)d_in[12];
    const float* sdv   = (const float*)d_in[13];
    const float* smp1  = (const float*)d_in[14];
    const float* sresc = (const float*)d_in[15];
    const float* sf1   = (const float*)d_in[16];
    const float* sf2   = (const float*)d_in[17];
    const float* pl1w  = (const float*)d_in[18];
    const float* pl1b  = (const float*)d_in[19];
    const float* pl2w  = (const float*)d_in[20];
    const float* pl2b  = (const float*)d_in[21];
    const float* pwq   = (const float*)d_in[22];
    const float* pwk   = (const float*)d_in[23];
    const float* pwv   = (const float*)d_in[24];
    const float* ppw   = (const float*)d_in[25];
    const float* pm2w  = (const float*)d_in[26];
    const float* ppb   = (const float*)d_in[27];
    const float* presc = (const float*)d_in[28];
    const float* pm1w  = (const float*)d_in[29];
    const float* pm1b  = (const float*)d_in[30];
    const float* pm2b  = (const float*)d_in[31];
    const float* pf1   = (const float*)d_in[32];
    const float* pf2   = (const float*)d_in[33];
    const float* fw1   = (const float*)d_in[34];
    const float* fb1   = (const float*)d_in[35];
    const float* fw2   = (const float*)d_in[36];
    const float* fb2   = (const float*)d_in[37];

    // workspace layout: 6 big buffers (202MB) + small scratch; d_out doubles as staging
    float* ws_f = (float*)d_ws;
    float* xs = ws_f;
    float* xp = ws_f + (size_t)SBUF;
    float* A  = ws_f + 2*(size_t)SBUF;
    float* Q  = ws_f + 3*(size_t)SBUF;
    float* K  = ws_f + 4*(size_t)SBUF;
    float* V  = ws_f + 5*(size_t)SBUF;
    float* small = ws_f + 6*(size_t)SBUF;
    float* mg   = small;                // 131072
    float* att  = mg + 131072;          // 4096
    float* svec = att + 4096;           // 512
    float* M    = svec + 512;           // 32768
    float* wbar = M + 32768;            // 65
    float* stage = (float*)d_out;       // scratch until fusion (written before read)
    float* Tf = Q;                      // fusion temp (Q is dead by then)

    hipMemcpyAsync(xs, x, (size_t)SBUF*4, hipMemcpyDeviceToDevice, stream);
    hipMemcpyAsync(xp, x, (size_t)SBUF*4, hipMemcpyDeviceToDevice, stream);

    // ---- spectral branch ----
    for(int i=0;i<2;i++){
        ln_kernel<<<512,256,0,stream>>>(xs, sl1w+i*64, sl1b+i*64, A);
        pw_kernel<<<512,256,0,stream>>>(A, swq+i*4096, nullptr, nullptr, stage, 0);
        dw3x3_kernel<<<32768,256,0,stream>>>(stage, sdq+i*576, Q);
        pw_kernel<<<512,256,0,stream>>>(A, swk+i*4096, nullptr, nullptr, stage, 0);
        dw3x3_kernel<<<32768,256,0,stream>>>(stage, sdk+i*576, K);
        pw_kernel<<<512,256,0,stream>>>(A, swv+i*4096, nullptr, nullptr, stage, 0);
        dw3x3_kernel<<<32768,256,0,stream>>>(stage, sdv+i*576, V);
        l2n_kernel<<<512,256,0,stream>>>(Q);
        l2n_kernel<<<512,256,0,stream>>>(K);
        qk_kernel<<<512,256,0,stream>>>(Q, K, att);
        zero512<<<2,256,0,stream>>>(svec);
        mbconv4_kernel<<<1024,256,0,stream>>>(mask, smp1+i*36864, svec);
        spec_softmax_kernel<<<8,64,0,stream>>>(att, svec, smp2+i*4096, sresc+i*8);
        mmat_kernel<<<8,256,0,stream>>>(att, sproj+i*4096, M);
        pw_kernel<<<512,256,0,stream>>>(V, M, nullptr, xs, xs, 1);
        ln_kernel<<<512,256,0,stream>>>(xs, sl2w+i*64, sl2b+i*64, A);
        ffn2d_v3_kernel<<<2048,256,0,stream>>>(A, sf1+i*2304, sf2+i*16384, xs);
    }
    // ---- polar branch ----
    for(int i=0;i<2;i++){
        ln_kernel<<<512,256,0,stream>>>(xp, pl1w+i*64, pl1b+i*64, A);
        pw_kernel<<<512,256,0,stream>>>(A, pwq+i*4096, nullptr, nullptr, Q, 0);
        pw_kernel<<<512,256,0,stream>>>(A, pwk+i*4096, nullptr, nullptr, K, 0);
        pw_kernel<<<512,256,0,stream>>>(A, pwv+i*4096, nullptr, nullptr, V, 0);
        wbar_kernel<<<1,64,0,stream>>>(pm2w+i*4096, pm2b+i*64, wbar);
        mg_kernel<<<512,256,0,stream>>>(mask, pm1w+i*576, pm1b+i*64, wbar, mg);
        att_pol_kernel<<<128,256,0,stream>>>(Q, K, V, mg, presc+i*8, stage);
        pw_kernel<<<512,256,0,stream>>>(stage, ppw+i*4096, ppb+i*64, xp, xp, 0);
        ln_kernel<<<512,256,0,stream>>>(xp, pl2w+i*64, pl2b+i*64, A);
        ffn3d_v3_kernel<<<2048,256,0,stream>>>(A, pf1+i*6912, pf2+i*16384, xp);
    }
    // ---- fusion ----
    fuse1_kernel<<<512,256,0,stream>>>(xs, xp, fw1, fb1, Tf);
    fuse2v2_kernel<<<1024,256,0,stream>>>(Tf, fw2, fb2, xs, xp, (float*)d_out);
}

// Round 8
// 2799.783 us; speedup vs baseline: 10.5551x; 1.0477x over previous
//
#include <hip/hip_runtime.h>
#include <math.h>

// Problem constants (B=8, C=64, H=W=128, HEADS=8, ch=8, L=2, P=4)
#define NPIX 16384               // 128*128
#define SBUF 8388608             // 8*64*16384 elements per full tensor

__device__ __forceinline__ float gelu_f(float x){
    return 0.5f*x*(1.0f+erff(x*0.70710678118654752440f));
}
__device__ __forceinline__ float waveReduceSum(float v){
    #pragma unroll
    for(int off=32;off>0;off>>=1) v += __shfl_down(v, off);
    return v;
}

// ---------------- LayerNorm over channel dim (64) ----------------
__global__ __launch_bounds__(256) void ln_kernel(const float* __restrict__ x,
        const float* __restrict__ w, const float* __restrict__ b, float* __restrict__ out){
    int idx = blockIdx.x*256 + threadIdx.x;      // over B*NPIX
    int bb = idx >> 14, n = idx & 16383;
    const float* ip = x + ((size_t)bb<<20) + n;
    float v[64]; float s = 0.f;
    #pragma unroll
    for(int c=0;c<64;c++){ v[c] = ip[(size_t)c<<14]; s += v[c]; }
    float mu = s*(1.f/64.f); float ss = 0.f;
    #pragma unroll
    for(int c=0;c<64;c++){ float d = v[c]-mu; ss += d*d; }
    float r = rsqrtf(ss*(1.f/64.f) + 1e-5f);
    float* op = out + ((size_t)bb<<20) + n;
    #pragma unroll
    for(int c=0;c<64;c++) op[(size_t)c<<14] = (v[c]-mu)*r*w[c] + b[c];
}

// ---------------- 1x1 conv: out[o] = sum_c w[o,c]*in[c] (+bias)(+res) ----------------
__global__ __launch_bounds__(256) void pw_kernel(const float* __restrict__ in,
        const float* __restrict__ w, const float* __restrict__ bias,
        const float* __restrict__ res, float* __restrict__ out, int wPerB){
    __shared__ float wl[4096];                   // transposed: wl[c*64+o]
    int t = threadIdx.x;
    int idx = blockIdx.x*256 + t;
    int b = idx >> 14, n = idx & 16383;
    const float* wp = w + (wPerB ? b*4096 : 0);
    for(int i=t;i<4096;i+=256) wl[(i&63)*64 + (i>>6)] = wp[i];
    __syncthreads();
    float acc[64];
    if(bias){
        #pragma unroll
        for(int o=0;o<64;o++) acc[o] = bias[o];
    } else {
        #pragma unroll
        for(int o=0;o<64;o++) acc[o] = 0.f;
    }
    const float* ip = in + ((size_t)b<<20) + n;
    for(int c=0;c<64;c++){
        float v = ip[(size_t)c<<14];
        const float4* wv = (const float4*)&wl[c*64];
        #pragma unroll
        for(int o4=0;o4<16;o4++){
            float4 w4 = wv[o4];
            acc[o4*4+0] += w4.x*v; acc[o4*4+1] += w4.y*v;
            acc[o4*4+2] += w4.z*v; acc[o4*4+3] += w4.w*v;
        }
    }
    size_t baseo = ((size_t)b<<20) + n;
    if(res){
        #pragma unroll
        for(int o=0;o<64;o++) out[baseo+((size_t)o<<14)] = acc[o] + res[baseo+((size_t)o<<14)];
    } else {
        #pragma unroll
        for(int o=0;o<64;o++) out[baseo+((size_t)o<<14)] = acc[o];
    }
}

// ---------------- depthwise 3x3, zero pad ----------------
__global__ __launch_bounds__(256) void dw3x3_kernel(const float* __restrict__ in,
        const float* __restrict__ wd, float* __restrict__ out){
    int idx = blockIdx.x*256 + threadIdx.x;      // over B*64*NPIX
    int n = idx & 16383; int bc = idx >> 14; int c = bc & 63;
    int y = n >> 7, x = n & 127;
    bool ym=y>0, yp=y<127, xm=x>0, xpv=x<127;
    const float* cp = in + ((size_t)bc<<14) + n;
    const float* wp = wd + c*9;
    float s = cp[0]*wp[4];
    if(ym){ s += cp[-128]*wp[1]; if(xm) s += cp[-129]*wp[0]; if(xpv) s += cp[-127]*wp[2]; }
    if(xm)  s += cp[-1]*wp[3];
    if(xpv) s += cp[1]*wp[5];
    if(yp){ s += cp[128]*wp[7]; if(xm) s += cp[127]*wp[6]; if(xpv) s += cp[129]*wp[8]; }
    out[idx] = s;
}

// ---------------- zero helper (5632 floats: att+svec+qn+kn) ----------------
__global__ void zero5632(float* __restrict__ p){
    p[blockIdx.x*256 + threadIdx.x] = 0.f;
}

// ---------------- spectral QK^T + row norms, fused (replaces l2n+qk) ----------------
// att_raw[(bh*8+c)*8+d] += sum_n q[c,n] k[d,n];  qn[bh*8+c] += |q_c|^2;  kn[bh*8+c] += |k_c|^2
__global__ __launch_bounds__(256) void qk2_kernel(const float* __restrict__ Q,
        const float* __restrict__ K, float* __restrict__ att,
        float* __restrict__ qn, float* __restrict__ kn){
    int blk = blockIdx.x;                        // 2048 = 4 nchunks x 64 bh x 8 c
    int c = blk & 7, bh = (blk>>3) & 63, chunk = blk >> 9;
    const float* qp = Q + (((size_t)bh*8 + c)<<14);
    const float* kp = K + (((size_t)bh*8)<<14);
    float p[8] = {0,0,0,0,0,0,0,0};
    float qsq = 0.f, ksq = 0.f;
    int n0 = chunk*4096;
    for(int n = n0 + threadIdx.x; n < n0+4096; n += 256){
        float qv = qp[n]; qsq += qv*qv;
        float kc = kp[((size_t)c<<14)+n]; ksq += kc*kc;
        #pragma unroll
        for(int d=0;d<8;d++) p[d] += qv*kp[((size_t)d<<14)+n];
    }
    #pragma unroll
    for(int off=32;off>0;off>>=1){
        #pragma unroll
        for(int d=0;d<8;d++) p[d] += __shfl_down(p[d], off);
        qsq += __shfl_down(qsq, off);
        ksq += __shfl_down(ksq, off);
    }
    __shared__ float red[4][10];
    int wave = threadIdx.x>>6, lane = threadIdx.x&63;
    if(lane==0){
        #pragma unroll
        for(int d=0;d<8;d++) red[wave][d] = p[d];
        red[wave][8] = qsq; red[wave][9] = ksq;
    }
    __syncthreads();
    if(threadIdx.x<10){
        float s = red[0][threadIdx.x]+red[1][threadIdx.x]+red[2][threadIdx.x]+red[3][threadIdx.x];
        if(threadIdx.x<8)       atomicAdd(&att[(size_t)(bh*8+c)*8 + threadIdx.x], s);
        else if(threadIdx.x==8) atomicAdd(&qn[bh*8+c], s);
        else                    atomicAdd(&kn[bh*8+c], s);
    }
}

// ---------------- mask bias v4: pw-kernel shape. One-time 36KB LDS fill (16 outputs),
// 2 pixels/thread, no mid-loop barriers. svec[b,m] += relu-sum over block's pixels. ----
__global__ __launch_bounds__(256) void mbconv4_kernel(const float* __restrict__ mask,
        const float* __restrict__ w, float* __restrict__ svec){
    __shared__ float wl[9216];                   // 36 KB: wl[ck*16+mo], ck in [0,576)
    __shared__ float red[4][16];
    int t = threadIdx.x;
    int og = blockIdx.x & 3;                     // output-channel group (16 each)
    int pb = (blockIdx.x >> 2) & 31;             // 512-pixel block
    int b  = blockIdx.x >> 7;
    const float* wp = w + (size_t)og*16*576;
    for(int i=t;i<9216;i+=256){
        int mo = i & 15, ck = i >> 4;
        wl[i] = wp[mo*576 + ck];
    }
    __syncthreads();
    int n0 = pb*512 + t;                         // pixel 0
    int n1 = n0 + 256;                           // pixel 1
    int y0 = n0>>7, x0 = n0&127;
    int y1 = n1>>7, x1 = n1&127;
    bool ym0=y0>0, yp0=y0<127, xm0=x0>0, xp0=x0<127;
    bool ym1=y1>0, yp1=y1<127, xm1=x1>0, xp1=x1<127;
    const float* mp = mask + ((size_t)b<<20);
    float acc0[16], acc1[16];
    #pragma unroll
    for(int o=0;o<16;o++){ acc0[o]=0.f; acc1[o]=0.f; }
    for(int c=0;c<64;c++){
        const float* cp0 = mp + ((size_t)c<<14) + n0;
        const float* cp1 = mp + ((size_t)c<<14) + n1;
        float ta[9], tb[9];
        ta[0] = (ym0&&xm0)? cp0[-129]:0.f;
        ta[1] =  ym0?       cp0[-128]:0.f;
        ta[2] = (ym0&&xp0)? cp0[-127]:0.f;
        ta[3] =  xm0?       cp0[-1]:0.f;
        ta[4] =             cp0[0];
        ta[5] =  xp0?       cp0[1]:0.f;
        ta[6] = (yp0&&xm0)? cp0[127]:0.f;
        ta[7] =  yp0?       cp0[128]:0.f;
        ta[8] = (yp0&&xp0)? cp0[129]:0.f;
        tb[0] = (ym1&&xm1)? cp1[-129]:0.f;
        tb[1] =  ym1?       cp1[-128]:0.f;
        tb[2] = (ym1&&xp1)? cp1[-127]:0.f;
        tb[3] =  xm1?       cp1[-1]:0.f;
        tb[4] =             cp1[0];
        tb[5] =  xp1?       cp1[1]:0.f;
        tb[6] = (yp1&&xm1)? cp1[127]:0.f;
        tb[7] =  yp1?       cp1[128]:0.f;
        tb[8] = (yp1&&xp1)? cp1[129]:0.f;
        #pragma unroll
        for(int k=0;k<9;k++){
            float va = ta[k], vb = tb[k];
            const float4* wv = (const float4*)&wl[(c*9+k)*16];
            #pragma unroll
            for(int o4=0;o4<4;o4++){
                float4 w4 = wv[o4];
                acc0[o4*4+0] += w4.x*va; acc0[o4*4+1] += w4.y*va;
                acc0[o4*4+2] += w4.z*va; acc0[o4*4+3] += w4.w*va;
                acc1[o4*4+0] += w4.x*vb; acc1[o4*4+1] += w4.y*vb;
                acc1[o4*4+2] += w4.z*vb; acc1[o4*4+3] += w4.w*vb;
            }
        }
    }
    // relu both pixels, reduce across block, atomic into svec
    int wave = t>>6, lane = t&63;
    #pragma unroll
    for(int m=0;m<16;m++){
        float v = waveReduceSum(fmaxf(acc0[m],0.f) + fmaxf(acc1[m],0.f));
        if(lane==0) red[wave][m] = v;
    }
    __syncthreads();
    if(t<16){
        float s = red[0][t]+red[1][t]+red[2][t]+red[3][t];
        atomicAdd(&svec[b*64 + og*16 + t], s);
    }
}

// ---------------- spectral: norms + mb projection + scale + bias + softmax over d ----------------
__global__ void spec_softmax2_kernel(float* __restrict__ att, const float* __restrict__ svec,
        const float* __restrict__ smp2, const float* __restrict__ resc,
        const float* __restrict__ qn, const float* __restrict__ kn){
    int b = blockIdx.x, t = threadIdx.x;         // 8 blocks, 64 threads
    __shared__ float mb[64];
    float a = 0.f;
    for(int m=0;m<64;m++) a += smp2[t*64+m]*svec[b*64+m];
    mb[t] = a*(1.f/16384.f);
    __syncthreads();
    int h = t>>3, c = t&7;
    float* ap = att + (size_t)(b*8+h)*64 + c*8;
    float rs = resc[h];
    float iqc = 1.f/fmaxf(sqrtf(qn[(b*8+h)*8+c]), 1e-12f);
    float ik[8];
    #pragma unroll
    for(int d=0;d<8;d++) ik[d] = 1.f/fmaxf(sqrtf(kn[(b*8+h)*8+d]), 1e-12f);
    float v[8]; float mx = -1e30f;
    #pragma unroll
    for(int d=0;d<8;d++){ v[d] = ap[d]*rs*iqc*ik[d] + mb[h*8+d] - mb[h*8+c]; mx = fmaxf(mx, v[d]); }
    float s = 0.f;
    #pragma unroll
    for(int d=0;d<8;d++){ v[d] = expf(v[d]-mx); s += v[d]; }
    float inv = 1.f/s;
    #pragma unroll
    for(int d=0;d<8;d++) ap[d] = v[d]*inv;
}

// ---------------- M[b] = sproj @ blockdiag(att[b]) (64x64 per batch) ----------------
__global__ void mmat_kernel(const float* __restrict__ att, const float* __restrict__ sproj,
        float* __restrict__ M){
    int b = blockIdx.x;
    for(int e=threadIdx.x;e<4096;e+=256){
        int o = e>>6, j = e&63;
        int h = j>>3, jj = j&7;
        float s = 0.f;
        #pragma unroll
        for(int cc=0;cc<8;cc++) s += sproj[o*64 + h*8+cc]*att[(size_t)(b*8+h)*64 + cc*8 + jj];
        M[b*4096 + e] = s;
    }
}

// ---------------- FFN2D fused v3 (og=4): dw3x3(x4)->GELU->proj to 16 of 64 outputs ----
__global__ __launch_bounds__(256) void ffn2d_v3_kernel(const float* __restrict__ A,
        const float* __restrict__ w1, const float* __restrict__ w2, float* __restrict__ xs){
    __shared__ float w2l[4096];                  // 16 KB: w2l[m*16+oo], m in [0,256)
    int t = threadIdx.x;
    int og = blockIdx.x & 3;                     // 4 groups x 16 outputs
    int pb = (blockIdx.x >> 2) & 63;             // 256-pixel block
    int b  = blockIdx.x >> 8;
    for(int i=t;i<4096;i+=256){
        int oo = i & 15, m = i >> 4;
        w2l[i] = w2[(og*16+oo)*256 + m];
    }
    __syncthreads();
    int n = pb*256 + t;
    int y = n>>7, x = n&127;
    bool ym=y>0, yp=y<127, xm=x>0, xpv=x<127;
    const float* ap = A + ((size_t)b<<20) + n;
    float acc[16];
    #pragma unroll
    for(int o=0;o<16;o++) acc[o] = 0.f;
    for(int c=0;c<64;c++){
        const float* cp = ap + ((size_t)c<<14);
        float t00 = (ym&&xm)? cp[-129]:0.f;
        float t01 =  ym?      cp[-128]:0.f;
        float t02 = (ym&&xpv)?cp[-127]:0.f;
        float t10 =  xm?      cp[-1]:0.f;
        float t11 =           cp[0];
        float t12 =  xpv?     cp[1]:0.f;
        float t20 = (yp&&xm)? cp[127]:0.f;
        float t21 =  yp?      cp[128]:0.f;
        float t22 = (yp&&xpv)?cp[129]:0.f;
        const float* w1c = w1 + c*36;
        #pragma unroll
        for(int j=0;j<4;j++){
            const float* wj = w1c + j*9;
            float cv = t00*wj[0]+t01*wj[1]+t02*wj[2]+t10*wj[3]+t11*wj[4]
                      +t12*wj[5]+t20*wj[6]+t21*wj[7]+t22*wj[8];
            float g = gelu_f(cv);
            const float4* wv = (const float4*)&w2l[(c*4+j)*16];
            #pragma unroll
            for(int o4=0;o4<4;o4++){
                float4 w4 = wv[o4];
                acc[o4*4+0] += w4.x*g; acc[o4*4+1] += w4.y*g;
                acc[o4*4+2] += w4.z*g; acc[o4*4+3] += w4.w*g;
            }
        }
    }
    size_t baseo = ((size_t)b<<20) + ((size_t)(og*16)<<14) + n;
    #pragma unroll
    for(int o=0;o<16;o++) xs[baseo+((size_t)o<<14)] += acc[o];
}

// ---------------- polar: wbar[c] = mean_o pm2w[o,c]; wbar[64] = mean(pm2b) ----------------
__global__ void wbar_kernel(const float* __restrict__ pm2w, const float* __restrict__ pm2b,
        float* __restrict__ wbar){
    int t = threadIdx.x;                         // 64
    float s = 0.f;
    for(int o=0;o<64;o++) s += pm2w[o*64+t];
    wbar[t] = s*(1.f/64.f);
    if(t==0){
        float sb = 0.f;
        for(int o=0;o<64;o++) sb += pm2b[o];
        wbar[64] = sb*(1.f/64.f);
    }
}

// ---------------- polar mask gate: mg[b,n] = sum_c wbar[c]*gelu(dw3x3(mask)[c]+pm1b[c]) + bbar ----------------
__global__ __launch_bounds__(256) void mg_kernel(const float* __restrict__ mask,
        const float* __restrict__ w1, const float* __restrict__ b1,
        const float* __restrict__ wbar, float* __restrict__ mg){
    int idx = blockIdx.x*256 + threadIdx.x;      // over B*NPIX
    int b = idx>>14, n = idx&16383;
    int y = n>>7, x = n&127;
    bool ym=y>0, yp=y<127, xm=x>0, xpv=x<127;
    const float* ap = mask + ((size_t)b<<20) + n;
    float acc = wbar[64];
    for(int c=0;c<64;c++){
        const float* cp = ap + ((size_t)c<<14);
        const float* wj = w1 + c*9;
        float cv = b1[c] + cp[0]*wj[4];
        if(ym){ cv += cp[-128]*wj[1]; if(xm) cv += cp[-129]*wj[0]; if(xpv) cv += cp[-127]*wj[2]; }
        if(xm)  cv += cp[-1]*wj[3];
        if(xpv) cv += cp[1]*wj[5];
        if(yp){ cv += cp[128]*wj[7]; if(xm) cv += cp[127]*wj[6]; if(xpv) cv += cp[129]*wj[8]; }
        acc += wbar[c]*gelu_f(cv);
    }
    mg[idx] = acc;
}

// ---------------- polar attention v2: one head per block (grid 1024) ----------------
__global__ __launch_bounds__(256) void att_pol2_kernel(const float* __restrict__ Q,
        const float* __restrict__ K, const float* __restrict__ V,
        const float* __restrict__ mg, const float* __restrict__ resc, float* __restrict__ O){
    int h = blockIdx.x & 7;
    int idx = (blockIdx.x>>3)*256 + threadIdx.x; // over BN*NPIX = 32768
    int bn = idx>>14, n = idx&16383;
    float mgv[4];
    #pragma unroll
    for(int p=0;p<4;p++) mgv[p] = mg[(((bn<<2)+p)<<14) + n];
    size_t base = ((size_t)bn<<22) + ((size_t)h<<17) + n;
    float q[4][8], k[4][8], v[4][8];
    #pragma unroll
    for(int p=0;p<4;p++){
        size_t pb = base + ((size_t)p<<20);
        #pragma unroll
        for(int j=0;j<8;j++){
            size_t o = pb + ((size_t)j<<14);
            q[p][j] = Q[o]; k[p][j] = K[o]; v[p][j] = V[o];
        }
    }
    #pragma unroll
    for(int p=0;p<4;p++){
        float sq=0.f, sk=0.f;
        #pragma unroll
        for(int j=0;j<8;j++){ sq += q[p][j]*q[p][j]; sk += k[p][j]*k[p][j]; }
        float iq = 1.f/fmaxf(sqrtf(sq),1e-12f), ik = 1.f/fmaxf(sqrtf(sk),1e-12f);
        #pragma unroll
        for(int j=0;j<8;j++){ q[p][j]*=iq; k[p][j]*=ik; }
    }
    float rs = resc[h];
    float att[4][4];
    #pragma unroll
    for(int p=0;p<4;p++){
        #pragma unroll
        for(int r=0;r<4;r++){
            float d = 0.f;
            #pragma unroll
            for(int j=0;j<8;j++) d += q[p][j]*k[r][j];
            att[p][r] = rs*d + mgv[r] - mgv[p];
        }
    }
    #pragma unroll
    for(int p=0;p<4;p++){
        float mx = fmaxf(fmaxf(att[p][0],att[p][1]),fmaxf(att[p][2],att[p][3]));
        float s = 0.f;
        #pragma unroll
        for(int r=0;r<4;r++){ att[p][r] = expf(att[p][r]-mx); s += att[p][r]; }
        float inv = 1.f/s;
        #pragma unroll
        for(int r=0;r<4;r++) att[p][r] *= inv;
    }
    #pragma unroll
    for(int p=0;p<4;p++){
        size_t pb = base + ((size_t)p<<20);
        #pragma unroll
        for(int j=0;j<8;j++){
            float o = att[p][0]*v[0][j]+att[p][1]*v[1][j]+att[p][2]*v[2][j]+att[p][3]*v[3][j];
            O[pb + ((size_t)j<<14)] = o;
        }
    }
}

// ---------------- FFN3D fused v3 (og=4): 3D dw conv 3x3x3(x4)->GELU->proj to 16 outputs ----
__global__ __launch_bounds__(256) void ffn3d_v3_kernel(const float* __restrict__ A,
        const float* __restrict__ w1, const float* __restrict__ w2, float* __restrict__ xp){
    __shared__ float w2l[4096];                  // 16 KB: w2l[m*16+oo]
    int t = threadIdx.x;
    int og = blockIdx.x & 3;
    int pbk = (blockIdx.x >> 2) & 63;            // 256-pixel block
    int bp = blockIdx.x >> 8;                    // 0..7 (= bn*4+p)
    for(int i=t;i<4096;i+=256){
        int oo = i & 15, m = i >> 4;
        w2l[i] = w2[(og*16+oo)*256 + m];
    }
    __syncthreads();
    int bn = bp>>2, p = bp&3;
    int n = pbk*256 + t;
    int y = n>>7, x = n&127;
    bool ym=y>0, yp=y<127, xm=x>0, xpv=x<127;
    float acc[16];
    #pragma unroll
    for(int o=0;o<16;o++) acc[o] = 0.f;
    for(int c=0;c<64;c++){
        float tap[27];
        #pragma unroll
        for(int dz=0;dz<3;dz++){
            int pp = p + dz - 1;
            if(pp < 0 || pp > 3){
                #pragma unroll
                for(int k9=0;k9<9;k9++) tap[dz*9+k9] = 0.f;
            } else {
                const float* cp = A + ((size_t)((bn<<2)+pp)<<20) + ((size_t)c<<14) + n;
                tap[dz*9+0] = (ym&&xm)? cp[-129]:0.f;
                tap[dz*9+1] =  ym?      cp[-128]:0.f;
                tap[dz*9+2] = (ym&&xpv)?cp[-127]:0.f;
                tap[dz*9+3] =  xm?      cp[-1]:0.f;
                tap[dz*9+4] =           cp[0];
                tap[dz*9+5] =  xpv?     cp[1]:0.f;
                tap[dz*9+6] = (yp&&xm)? cp[127]:0.f;
                tap[dz*9+7] =  yp?      cp[128]:0.f;
                tap[dz*9+8] = (yp&&xpv)?cp[129]:0.f;
            }
        }
        const float* w1c = w1 + c*108;
        #pragma unroll
        for(int j=0;j<4;j++){
            const float* wj = w1c + j*27;
            float cv = 0.f;
            #pragma unroll
            for(int k27=0;k27<27;k27++) cv += tap[k27]*wj[k27];
            float g = gelu_f(cv);
            const float4* wv = (const float4*)&w2l[(c*4+j)*16];
            #pragma unroll
            for(int o4=0;o4<4;o4++){
                float4 w4 = wv[o4];
                acc[o4*4+0] += w4.x*g; acc[o4*4+1] += w4.y*g;
                acc[o4*4+2] += w4.z*g; acc[o4*4+3] += w4.w*g;
            }
        }
    }
    size_t baseo = ((size_t)bp<<20) + ((size_t)(og*16)<<14) + n;
    #pragma unroll
    for(int o=0;o<16;o++) xp[baseo+((size_t)o<<14)] += acc[o];
}

// ---------------- fusion stage 1: T = relu(fw1 @ [xs;xp] + fb1) ----------------
__global__ __launch_bounds__(256) void fuse1_kernel(const float* __restrict__ xs,
        const float* __restrict__ xp, const float* __restrict__ fw1,
        const float* __restrict__ fb1, float* __restrict__ T){
    __shared__ float wl[8192];                   // wl[c*64+o] = fw1[o*128+c], c in 0..127
    int t = threadIdx.x;
    for(int i=t;i<8192;i+=256) wl[(i&127)*64 + (i>>7)] = fw1[i];
    __syncthreads();
    int idx = blockIdx.x*256 + t;
    int b = idx>>14, n = idx&16383;
    float acc[64];
    #pragma unroll
    for(int o=0;o<64;o++) acc[o] = fb1[o];
    const float* ip = xs + ((size_t)b<<20) + n;
    for(int c=0;c<64;c++){
        float v = ip[(size_t)c<<14];
        const float4* wv = (const float4*)&wl[c*64];
        #pragma unroll
        for(int o4=0;o4<16;o4++){
            float4 w4 = wv[o4];
            acc[o4*4+0] += w4.x*v; acc[o4*4+1] += w4.y*v;
            acc[o4*4+2] += w4.z*v; acc[o4*4+3] += w4.w*v;
        }
    }
    const float* ip2 = xp + ((size_t)b<<20) + n;
    for(int c=0;c<64;c++){
        float v = ip2[(size_t)c<<14];
        const float4* wv = (const float4*)&wl[(64+c)*64];
        #pragma unroll
        for(int o4=0;o4<16;o4++){
            float4 w4 = wv[o4];
            acc[o4*4+0] += w4.x*v; acc[o4*4+1] += w4.y*v;
            acc[o4*4+2] += w4.z*v; acc[o4*4+3] += w4.w*v;
        }
    }
    size_t baseo = ((size_t)b<<20) + n;
    #pragma unroll
    for(int o=0;o<64;o++) T[baseo+((size_t)o<<14)] = fmaxf(acc[o], 0.f);
}

// ---------------- fusion stage 2 v2 (mbconv4 shape): 16 outputs per block, 2 px/thread.
// out = sig(conv3x3(T)+fb2)*xs + (1-sig)*xp ----------------
__global__ __launch_bounds__(256) void fuse2v2_kernel(const float* __restrict__ T,
        const float* __restrict__ fw2, const float* __restrict__ fb2,
        const float* __restrict__ xs, const float* __restrict__ xp, float* __restrict__ out){
    __shared__ float wl[9216];                   // 36 KB: wl[ck*16+mo], ck = c*9+k
    int t = threadIdx.x;
    int og = blockIdx.x & 3;                     // output-channel group (16 each)
    int pb = (blockIdx.x >> 2) & 31;             // 512-pixel block
    int b  = blockIdx.x >> 7;
    const float* wp = fw2 + (size_t)og*16*576;
    for(int i=t;i<9216;i+=256){
        int mo = i & 15, ck = i >> 4;
        wl[i] = wp[mo*576 + ck];
    }
    __syncthreads();
    int n0 = pb*512 + t;
    int n1 = n0 + 256;
    int y0 = n0>>7, x0 = n0&127;
    int y1 = n1>>7, x1 = n1&127;
    bool ym0=y0>0, yp0=y0<127, xm0=x0>0, xp0=x0<127;
    bool ym1=y1>0, yp1=y1<127, xm1=x1>0, xp1=x1<127;
    const float* tp = T + ((size_t)b<<20);
    float acc0[16], acc1[16];
    #pragma unroll
    for(int o=0;o<16;o++){ acc0[o]=0.f; acc1[o]=0.f; }
    for(int c=0;c<64;c++){
        const float* cp0 = tp + ((size_t)c<<14) + n0;
        const float* cp1 = tp + ((size_t)c<<14) + n1;
        float ta[9], tb[9];
        ta[0] = (ym0&&xm0)? cp0[-129]:0.f;
        ta[1] =  ym0?       cp0[-128]:0.f;
        ta[2] = (ym0&&xp0)? cp0[-127]:0.f;
        ta[3] =  xm0?       cp0[-1]:0.f;
        ta[4] =             cp0[0];
        ta[5] =  xp0?       cp0[1]:0.f;
        ta[6] = (yp0&&xm0)? cp0[127]:0.f;
        ta[7] =  yp0?       cp0[128]:0.f;
        ta[8] = (yp0&&xp0)? cp0[129]:0.f;
        tb[0] = (ym1&&xm1)? cp1[-129]:0.f;
        tb[1] =  ym1?       cp1[-128]:0.f;
        tb[2] = (ym1&&xp1)? cp1[-127]:0.f;
        tb[3] =  xm1?       cp1[-1]:0.f;
        tb[4] =             cp1[0];
        tb[5] =  xp1?       cp1[1]:0.f;
        tb[6] = (yp1&&xm1)? cp1[127]:0.f;
        tb[7] =  yp1?       cp1[128]:0.f;
        tb[8] = (yp1&&xp1)? cp1[129]:0.f;
        #pragma unroll
        for(int k=0;k<9;k++){
            float va = ta[k], vb = tb[k];
            const float4* wv = (const float4*)&wl[(c*9+k)*16];
            #pragma unroll
            for(int o4=0;o4<4;o4++){
                float4 w4 = wv[o4];
                acc0[o4*4+0] += w4.x*va; acc0[o4*4+1] += w4.y*va;
                acc0[o4*4+2] += w4.z*va; acc0[o4*4+3] += w4.w*va;
                acc1[o4*4+0] += w4.x*vb; acc1[o4*4+1] += w4.y*vb;
                acc1[o4*4+2] += w4.z*vb; acc1[o4*4+3] += w4.w*vb;
            }
        }
    }
    // epilogue: sigmoid gate + mix, write 16 outputs x 2 pixels
    #pragma unroll
    for(int m=0;m<16;m++){
        int o = og*16 + m;
        float bias = fb2[o];
        size_t i0 = ((size_t)b<<20) + ((size_t)o<<14) + n0;
        size_t i1 = ((size_t)b<<20) + ((size_t)o<<14) + n1;
        float a0 = 1.f/(1.f+expf(-(acc0[m]+bias)));
        float a1 = 1.f/(1.f+expf(-(acc1[m]+bias)));
        out[i0] = a0*xs[i0] + (1.f-a0)*xp[i0];
        out[i1] = a1*xs[i1] + (1.f-a1)*xp[i1];
    }
}

extern "C" void kernel_launch(void* const* d_in, const int* in_sizes, int n_in,
                              void* d_out, int out_size, void* d_ws, size_t ws_size,
                              hipStream_t stream) {
    // setup_inputs() dict order
    const float* x     = (const float*)d_in[0];
    const float* mask  = (const float*)d_in[1];
    const float* sl1w  = (const float*)d_in[2];
    const float* sl1b  = (const float*)d_in[3];
    const float* sl2w  = (const float*)d_in[4];
    const float* sl2b  = (const float*)d_in[5];
    const float* swq   = (const float*)d_in[6];
    const float* swk   = (const float*)d_in[7];
    const float* swv   = (const float*)d_in[8];
    const float* sproj = (const float*)d_in[9];
    const float* smp2  = (const float*)d_in[10];
    const float* sdq   = (const float*)d_in[11];
    const float* sdk   = (const float*)d_in[12];
    const float* sdv   = (const float*)d_in[13];
    const float* smp1  = (const float*)d_in[14];
    const float* sresc = (const float*)d_in[15];
    const float* sf1   = (const float*)d_in[16];
    const float* sf2   = (const float*)d_in[17];
    const float* pl1w  = (const float*)d_in[18];
    const float* pl1b  = (const float*)d_in[19];
    const float* pl2w  = (const float*)d_in[20];
    const float* pl2b  = (const float*)d_in[21];
    const float* pwq   = (const float*)d_in[22];
    const float* pwk   = (const float*)d_in[23];
    const float* pwv   = (const float*)d_in[24];
    const float* ppw   = (const float*)d_in[25];
    const float* pm2w  = (const float*)d_in[26];
    const float* ppb   = (const float*)d_in[27];
    const float* presc = (const float*)d_in[28];
    const float* pm1w  = (const float*)d_in[29];
    const float* pm1b  = (const float*)d_in[30];
    const float* pm2b  = (const float*)d_in[31];
    const float* pf1   = (const float*)d_in[32];
    const float* pf2   = (const float*)d_in[33];
    const float* fw1   = (const float*)d_in[34];
    const float* fb1   = (const float*)d_in[35];
    const float* fw2   = (const float*)d_in[36];
    const float* fb2   = (const float*)d_in[37];

    // workspace layout: 6 big buffers (202MB) + small scratch; d_out doubles as staging
    float* ws_f = (float*)d_ws;
    float* xs = ws_f;
    float* xp = ws_f + (size_t)SBUF;
    float* A  = ws_f + 2*(size_t)SBUF;
    float* Q  = ws_f + 3*(size_t)SBUF;
    float* K  = ws_f + 4*(size_t)SBUF;
    float* V  = ws_f + 5*(size_t)SBUF;
    float* small = ws_f + 6*(size_t)SBUF;
    float* mg   = small;                // 131072
    float* att  = mg + 131072;          // 4096   (zero region starts here)
    float* svec = att + 4096;           // 512
    float* qn   = svec + 512;           // 512
    float* kn   = qn + 512;             // 512    (zero region = 5632 floats)
    float* M    = kn + 512;             // 32768
    float* wbar = M + 32768;            // 65
    float* stage = (float*)d_out;       // scratch until fusion (written before read)
    float* Tf = Q;                      // fusion temp (Q is dead by then)

    hipMemcpyAsync(xs, x, (size_t)SBUF*4, hipMemcpyDeviceToDevice, stream);
    hipMemcpyAsync(xp, x, (size_t)SBUF*4, hipMemcpyDeviceToDevice, stream);

    // ---- spectral branch ----
    for(int i=0;i<2;i++){
        ln_kernel<<<512,256,0,stream>>>(xs, sl1w+i*64, sl1b+i*64, A);
        pw_kernel<<<512,256,0,stream>>>(A, swq+i*4096, nullptr, nullptr, stage, 0);
        dw3x3_kernel<<<32768,256,0,stream>>>(stage, sdq+i*576, Q);
        pw_kernel<<<512,256,0,stream>>>(A, swk+i*4096, nullptr, nullptr, stage, 0);
        dw3x3_kernel<<<32768,256,0,stream>>>(stage, sdk+i*576, K);
        pw_kernel<<<512,256,0,stream>>>(A, swv+i*4096, nullptr, nullptr, stage, 0);
        dw3x3_kernel<<<32768,256,0,stream>>>(stage, sdv+i*576, V);
        zero5632<<<22,256,0,stream>>>(att);
        qk2_kernel<<<2048,256,0,stream>>>(Q, K, att, qn, kn);
        mbconv4_kernel<<<1024,256,0,stream>>>(mask, smp1+i*36864, svec);
        spec_softmax2_kernel<<<8,64,0,stream>>>(att, svec, smp2+i*4096, sresc+i*8, qn, kn);
        mmat_kernel<<<8,256,0,stream>>>(att, sproj+i*4096, M);
        pw_kernel<<<512,256,0,stream>>>(V, M, nullptr, xs, xs, 1);
        ln_kernel<<<512,256,0,stream>>>(xs, sl2w+i*64, sl2b+i*64, A);
        ffn2d_v3_kernel<<<2048,256,0,stream>>>(A, sf1+i*2304, sf2+i*16384, xs);
    }
    // ---- polar branch ----
    for(int i=0;i<2;i++){
        ln_kernel<<<512,256,0,stream>>>(xp, pl1w+i*64, pl1b+i*64, A);
        pw_kernel<<<512,256,0,stream>>>(A, pwq+i*4096, nullptr, nullptr, Q, 0);
        pw_kernel<<<512,256,0,stream>>>(A, pwk+i*4096, nullptr, nullptr, K, 0);
        pw_kernel<<<512,256,0,stream>>>(A, pwv+i*4096, nullptr, nullptr, V, 0);
        wbar_kernel<<<1,64,0,stream>>>(pm2w+i*4096, pm2b+i*64, wbar);
        mg_kernel<<<512,256,0,stream>>>(mask, pm1w+i*576, pm1b+i*64, wbar, mg);
        att_pol2_kernel<<<1024,256,0,stream>>>(Q, K, V, mg, presc+i*8, stage);
        pw_kernel<<<512,256,0,stream>>>(stage, ppw+i*4096, ppb+i*64, xp, xp, 0);
        ln_kernel<<<512,256,0,stream>>>(xp, pl2w+i*64, pl2b+i*64, A);
        ffn3d_v3_kernel<<<2048,256,0,stream>>>(A, pf1+i*6912, pf2+i*16384, xp);
    }
    // ---- fusion ----
    fuse1_kernel<<<512,256,0,stream>>>(xs, xp, fw1, fb1, Tf);
    fuse2v2_kernel<<<1024,256,0,stream>>>(Tf, fw2, fb2, xs, xp, (float*)d_out);
}